// Round 1
// baseline (2873.919 us; speedup 1.0000x reference)
//
#include <hip/hip_runtime.h>

// MultiHeadCrossAttention: B=4, C=512, HEADS=4, HD=128, L=100
// f1: [4,5,512,10,10] -> 500 support tokens/batch
// f2: [4,75,512,10,10] -> 7500 query tokens/batch
// out1: [4,5,512,100], out2: [4,75,512,100] concatenated in d_out.

#define SCALE_ 0.08838834764831845f   // 128^-0.5

// ---------------------------------------------------------------------------
// proj: Y[b][t][o] = sum_c X[b][t/100][c][t%100] * W[o][c] + bias[o]
// X channel-major [B,n,512,100]; Y token-major [B,ntok,512].
// grid: (ceil(ntok/64), 8, B), block 256. 64 tok x 64 out tile, K-chunk 32.
// ---------------------------------------------------------------------------
__global__ __launch_bounds__(256) void proj_kernel(
    const float* __restrict__ X, const float* __restrict__ W,
    const float* __restrict__ bias, float* __restrict__ Y, int ntok)
{
    __shared__ float Xs[32][68];   // [kk][token]
    __shared__ float Ws[32][68];   // [kk][o_local]
    const int t  = threadIdx.x;
    const int t0 = blockIdx.x * 64;
    const int o0 = blockIdx.y * 64;
    const int b  = blockIdx.z;
    const int nN = ntok / 100;
    const int tr = (t >> 4) * 4;   // token sub-tile
    const int oc = (t & 15) * 4;   // out sub-tile
    float acc[4][4] = {};

    const int tokA = t & 63;
    const int kkA  = t >> 6;       // 0..3
    const int tgA  = t0 + tokA;
    int nA = 0, lA = 0;
    if (tgA < ntok) { nA = tgA / 100; lA = tgA % 100; }
    const int kkB = t & 31;
    const int obB = t >> 5;        // 0..7

    for (int c0 = 0; c0 < 512; c0 += 32) {
        __syncthreads();
        if (tgA < ntok) {
            const float* xp = X + ((size_t)(b * nN + nA) * 512 + c0) * 100 + lA;
            #pragma unroll
            for (int it = 0; it < 8; ++it)
                Xs[kkA + it * 4][tokA] = xp[(size_t)(kkA + it * 4) * 100];
        } else {
            #pragma unroll
            for (int it = 0; it < 8; ++it) Xs[kkA + it * 4][tokA] = 0.f;
        }
        const float* wp = W + (size_t)o0 * 512 + c0 + kkB;
        #pragma unroll
        for (int it = 0; it < 8; ++it)
            Ws[kkB][obB + it * 8] = wp[(size_t)(obB + it * 8) * 512];
        __syncthreads();
        #pragma unroll
        for (int kk = 0; kk < 32; ++kk) {
            const float4 xv = *(const float4*)&Xs[kk][tr];
            const float4 wv = *(const float4*)&Ws[kk][oc];
            const float xa[4] = {xv.x, xv.y, xv.z, xv.w};
            const float wa[4] = {wv.x, wv.y, wv.z, wv.w};
            #pragma unroll
            for (int i = 0; i < 4; ++i)
                #pragma unroll
                for (int j = 0; j < 4; ++j)
                    acc[i][j] = fmaf(xa[i], wa[j], acc[i][j]);
        }
    }
    #pragma unroll
    for (int i = 0; i < 4; ++i) {
        const int tg = t0 + tr + i;
        if (tg < ntok) {
            float* yp = Y + ((size_t)b * ntok + tg) * 512 + o0 + oc;
            #pragma unroll
            for (int j = 0; j < 4; ++j) yp[j] = acc[i][j] + bias[o0 + oc + j];
        }
    }
}

// ---------------------------------------------------------------------------
// oproj: Yf[b][n][c][l] = sum_o A[b][t][o] * W[c][o] + bias[c], t = n*100+l
// A token-major [B,ntok,512]; output written transposed into d_out region.
// ---------------------------------------------------------------------------
__global__ __launch_bounds__(256) void oproj_kernel(
    const float* __restrict__ A, const float* __restrict__ W,
    const float* __restrict__ bias, float* __restrict__ Y, int ntok)
{
    __shared__ float As[32][68];   // [kk][token]
    __shared__ float Ws[32][68];   // [kk][c_local]
    const int t  = threadIdx.x;
    const int t0 = blockIdx.x * 64;
    const int c0 = blockIdx.y * 64;
    const int b  = blockIdx.z;
    const int nN = ntok / 100;
    const int tr = (t >> 4) * 4;
    const int oc = (t & 15) * 4;
    float acc[4][4] = {};
    const int kkA = t & 31;
    const int tb  = t >> 5;        // 0..7

    for (int k0 = 0; k0 < 512; k0 += 32) {
        __syncthreads();
        #pragma unroll
        for (int it = 0; it < 8; ++it) {
            const int tok = tb + it * 8;
            const int tg = t0 + tok;
            As[kkA][tok] = (tg < ntok)
                ? A[((size_t)b * ntok + tg) * 512 + k0 + kkA] : 0.f;
        }
        const float* wp = W + (size_t)c0 * 512 + k0 + kkA;
        #pragma unroll
        for (int it = 0; it < 8; ++it)
            Ws[kkA][tb + it * 8] = wp[(size_t)(tb + it * 8) * 512];
        __syncthreads();
        #pragma unroll
        for (int kk = 0; kk < 32; ++kk) {
            const float4 xv = *(const float4*)&As[kk][tr];
            const float4 wv = *(const float4*)&Ws[kk][oc];
            const float xa[4] = {xv.x, xv.y, xv.z, xv.w};
            const float wa[4] = {wv.x, wv.y, wv.z, wv.w};
            #pragma unroll
            for (int i = 0; i < 4; ++i)
                #pragma unroll
                for (int j = 0; j < 4; ++j)
                    acc[i][j] = fmaf(xa[i], wa[j], acc[i][j]);
        }
    }
    #pragma unroll
    for (int i = 0; i < 4; ++i) {
        const int tg = t0 + tr + i;
        if (tg < ntok) {
            const int n = tg / 100, l = tg % 100;
            #pragma unroll
            for (int j = 0; j < 4; ++j)
                Y[(((size_t)b * nN + n) * 512 + c0 + oc + j) * 100 + l] =
                    acc[i][j] + bias[c0 + oc + j];
        }
    }
}

// ---------------------------------------------------------------------------
// Flash-style attention, per (row-tile of 16, head, batch).
// O[b,r,ho+d] = softmax_k( R[b,r,ho+:]·K[b,k,ho+:] * SCALE ) @ V[b,k,ho+:]
// K/V time-share one LDS buffer (static LDS = 47.9 KB -> 3 blocks/CU).
// ---------------------------------------------------------------------------
__global__ __launch_bounds__(256) void attn_kernel(
    const float* __restrict__ R, const float* __restrict__ K,
    const float* __restrict__ V, float* __restrict__ O,
    int TR, int TK)
{
    __shared__ float Qs[16][132];
    __shared__ float KVs[64][132];
    __shared__ float Ps[16][68];
    __shared__ float red[16][17];
    __shared__ float mrow[16], lrow[16], srow[16];

    const int t  = threadIdx.x;
    const int r0 = blockIdx.x * 16;
    const int ho = blockIdx.y * 128;
    const int b  = blockIdx.z;

    // load Q tile (zero-padded past TR; those rows are computed but not stored)
    #pragma unroll
    for (int i = 0; i < 2; ++i) {
        const int p = t + i * 256;
        const int r = p >> 5;
        const int dq = (p & 31) * 4;
        float4 v = make_float4(0.f, 0.f, 0.f, 0.f);
        if (r0 + r < TR)
            v = *(const float4*)&R[((size_t)b * TR + r0 + r) * 512 + ho + dq];
        *(float4*)&Qs[r][dq] = v;
    }
    if (t < 16) { mrow[t] = -3.0e38f; lrow[t] = 0.f; srow[t] = 0.f; }

    const int rr = t & 15;
    const int dg = t >> 4;         // 0..15
    const int d0 = dg * 8;
    const int ra = t & 7;
    const int kb = t >> 3;         // 0..31
    float acc[8] = {};

    for (int kbase = 0; kbase < TK; kbase += 64) {
        __syncthreads();
        // stage K chunk
        #pragma unroll
        for (int i = 0; i < 8; ++i) {
            const int p = t + i * 256;
            const int kr = p >> 5;
            const int dq = (p & 31) * 4;
            float4 v = make_float4(0.f, 0.f, 0.f, 0.f);
            if (kbase + kr < TK)
                v = *(const float4*)&K[((size_t)b * TK + kbase + kr) * 512 + ho + dq];
            *(float4*)&KVs[kr][dq] = v;
        }
        __syncthreads();
        // logits, 2 rows x 2 cols per thread
        {
            float s00 = 0.f, s01 = 0.f, s10 = 0.f, s11 = 0.f;
            #pragma unroll
            for (int dq = 0; dq < 128; dq += 4) {
                const float4 qa = *(const float4*)&Qs[ra][dq];
                const float4 qb = *(const float4*)&Qs[ra + 8][dq];
                const float4 ka = *(const float4*)&KVs[kb][dq];
                const float4 kc = *(const float4*)&KVs[kb + 32][dq];
                s00 += qa.x*ka.x + qa.y*ka.y + qa.z*ka.z + qa.w*ka.w;
                s01 += qa.x*kc.x + qa.y*kc.y + qa.z*kc.z + qa.w*kc.w;
                s10 += qb.x*ka.x + qb.y*ka.y + qb.z*ka.z + qb.w*ka.w;
                s11 += qb.x*kc.x + qb.y*kc.y + qb.z*kc.z + qb.w*kc.w;
            }
            const bool okA = (kbase + kb      < TK);
            const bool okB = (kbase + kb + 32 < TK);
            Ps[ra][kb]          = okA ? s00 * SCALE_ : -3.0e38f;
            Ps[ra][kb + 32]     = okB ? s01 * SCALE_ : -3.0e38f;
            Ps[ra + 8][kb]      = okA ? s10 * SCALE_ : -3.0e38f;
            Ps[ra + 8][kb + 32] = okB ? s11 * SCALE_ : -3.0e38f;
        }
        __syncthreads();
        // partial row max + stage V chunk (same phase; disjoint LDS)
        {
            float pm = -3.0e38f;
            #pragma unroll
            for (int j = 0; j < 4; ++j) pm = fmaxf(pm, Ps[rr][dg * 4 + j]);
            red[rr][dg] = pm;
        }
        #pragma unroll
        for (int i = 0; i < 8; ++i) {
            const int p = t + i * 256;
            const int kr = p >> 5;
            const int dq = (p & 31) * 4;
            float4 v = make_float4(0.f, 0.f, 0.f, 0.f);
            if (kbase + kr < TK)
                v = *(const float4*)&V[((size_t)b * TK + kbase + kr) * 512 + ho + dq];
            *(float4*)&KVs[kr][dq] = v;
        }
        __syncthreads();
        if (t < 16) {
            float cm = -3.0e38f;
            #pragma unroll
            for (int s = 0; s < 16; ++s) cm = fmaxf(cm, red[t][s]);
            const float mo = mrow[t];
            const float mn = fmaxf(mo, cm);
            srow[t] = __expf(mo - mn);
            mrow[t] = mn;
        }
        __syncthreads();
        // exponentiate + partial sums
        {
            const float mn = mrow[rr];
            float ps = 0.f;
            #pragma unroll
            for (int j = 0; j < 4; ++j) {
                const float v = __expf(Ps[rr][dg * 4 + j] - mn);
                Ps[rr][dg * 4 + j] = v;
                ps += v;
            }
            red[rr][dg] = ps;
        }
        __syncthreads();
        if (t < 16) {
            float cs = 0.f;
            #pragma unroll
            for (int s = 0; s < 16; ++s) cs += red[t][s];
            lrow[t] = lrow[t] * srow[t] + cs;
        }
        __syncthreads();
        // accumulate P @ V
        {
            const float sc = srow[rr];
            #pragma unroll
            for (int j = 0; j < 8; ++j) acc[j] *= sc;
            for (int k = 0; k < 64; ++k) {
                const float pv = Ps[rr][k];
                const float4 v0 = *(const float4*)&KVs[k][d0];
                const float4 v1 = *(const float4*)&KVs[k][d0 + 4];
                acc[0] = fmaf(pv, v0.x, acc[0]);
                acc[1] = fmaf(pv, v0.y, acc[1]);
                acc[2] = fmaf(pv, v0.z, acc[2]);
                acc[3] = fmaf(pv, v0.w, acc[3]);
                acc[4] = fmaf(pv, v1.x, acc[4]);
                acc[5] = fmaf(pv, v1.y, acc[5]);
                acc[6] = fmaf(pv, v1.z, acc[6]);
                acc[7] = fmaf(pv, v1.w, acc[7]);
            }
        }
    }
    __syncthreads();
    if (r0 + rr < TR) {
        const float inv = 1.f / lrow[rr];
        float* op = O + ((size_t)b * TR + r0 + rr) * 512 + ho + d0;
        #pragma unroll
        for (int j = 0; j < 8; ++j) op[j] = acc[j] * inv;
    }
}

// ---------------------------------------------------------------------------
extern "C" void kernel_launch(void* const* d_in, const int* in_sizes, int n_in,
                              void* d_out, int out_size, void* d_ws, size_t ws_size,
                              hipStream_t stream) {
    const float* f1  = (const float*)d_in[0];
    const float* f2  = (const float*)d_in[1];
    const float* Wk1 = (const float*)d_in[2];
    const float* bk1 = (const float*)d_in[3];
    const float* Wv1 = (const float*)d_in[4];
    const float* bv1 = (const float*)d_in[5];
    const float* Wq2 = (const float*)d_in[6];
    const float* bq2 = (const float*)d_in[7];
    // d_in[8..9] = Wk2/bk2: unused by the reference outputs -> skipped.
    const float* Wv2 = (const float*)d_in[10];
    const float* bv2 = (const float*)d_in[11];
    const float* Wo1 = (const float*)d_in[12];
    const float* bo1 = (const float*)d_in[13];
    const float* Wo2 = (const float*)d_in[14];
    const float* bo2 = (const float*)d_in[15];
    float* out = (float*)d_out;

    // workspace layout (fp32), 196,608,000 B total
    float* ws = (float*)d_ws;
    float* K1 = ws;                  // [4][ 500][512]
    float* V1 = K1 + 1024000;        // [4][ 500][512]
    float* Q2 = V1 + 1024000;        // [4][7500][512]
    float* V2 = Q2 + 15360000;       // [4][7500][512]
    float* A1 = V2 + 15360000;       // [4][ 500][512] attn out (support rows)
    float* A2 = A1 + 1024000;        // [4][7500][512] attn out (query rows)

    const dim3 blk(256);

    proj_kernel<<<dim3(8, 8, 4),   blk, 0, stream>>>(f1, Wk1, bk1, K1, 500);
    proj_kernel<<<dim3(8, 8, 4),   blk, 0, stream>>>(f1, Wv1, bv1, V1, 500);
    proj_kernel<<<dim3(118, 8, 4), blk, 0, stream>>>(f2, Wq2, bq2, Q2, 7500);
    proj_kernel<<<dim3(118, 8, 4), blk, 0, stream>>>(f2, Wv2, bv2, V2, 7500);

    // out2 attention: rows = queries (7500), keys = support (500)
    attn_kernel<<<dim3(469, 4, 4), blk, 0, stream>>>(Q2, K1, V1, A2, 7500, 500);
    // out1 attention: rows = support (500), keys = queries (7500)
    attn_kernel<<<dim3(32, 4, 4),  blk, 0, stream>>>(K1, Q2, V2, A1, 500, 7500);

    // o-projections with fused [B,n,L,C] -> [B,n,C,L] transpose at the store
    oproj_kernel<<<dim3(8, 8, 4),   blk, 0, stream>>>(A1, Wo1, bo1, out, 500);
    oproj_kernel<<<dim3(118, 8, 4), blk, 0, stream>>>(A2, Wo2, bo2, out + 1024000, 7500);
}

// Round 2
// 1202.384 us; speedup vs baseline: 2.3902x; 2.3902x over previous
//
#include <hip/hip_runtime.h>
#include <hip/hip_bf16.h>

// MultiHeadCrossAttention: B=4, C=512, HEADS=4, HD=128, L=100
// f1 -> 500 support tokens/batch, f2 -> 7500 query tokens/batch.
// out1: [4,5,512,100], out2: [4,75,512,100] concatenated in d_out.

#define SCALE_ 0.08838834764831845f   // 128^-0.5

using bf16x8 = __attribute__((ext_vector_type(8))) short;
using f32x4  = __attribute__((ext_vector_type(4))) float;

__device__ inline ushort f2bf(float x) {
    union { float f; unsigned u; } v; v.f = x;
    unsigned r = v.u + 0x7fff + ((v.u >> 16) & 1);   // RNE
    return (ushort)(r >> 16);
}

// ---------------------------------------------------------------------------
// proj: Y[t][o] = sum_c X[b][t/100][c][t%100] * W[o][c] + bias[o], bf16 out.
// TRANS=0: Y token-major [B][ntok][512]. TRANS=1: Y d-major [B][512][strideT].
// ---------------------------------------------------------------------------
template<int TRANS>
__global__ __launch_bounds__(256) void proj_kernel(
    const float* __restrict__ X, const float* __restrict__ W,
    const float* __restrict__ bias, ushort* __restrict__ Y,
    int ntok, int strideT)
{
    __shared__ float Xs[32][68];
    __shared__ float Ws[32][68];
    __shared__ ushort Ts[64][72];
    const int t  = threadIdx.x;
    const int t0 = blockIdx.x * 64;
    const int o0 = blockIdx.y * 64;
    const int b  = blockIdx.z;
    const int nN = ntok / 100;
    const int tr = (t >> 4) * 4;
    const int oc = (t & 15) * 4;
    float acc[4][4] = {};

    const int tokA = t & 63;
    const int kkA  = t >> 6;
    const int tgA  = t0 + tokA;
    int nA = 0, lA = 0;
    if (tgA < ntok) { nA = tgA / 100; lA = tgA % 100; }
    const int kkB = t & 31;
    const int obB = t >> 5;

    for (int c0 = 0; c0 < 512; c0 += 32) {
        __syncthreads();
        if (tgA < ntok) {
            const float* xp = X + ((size_t)(b * nN + nA) * 512 + c0) * 100 + lA;
            #pragma unroll
            for (int it = 0; it < 8; ++it)
                Xs[kkA + it * 4][tokA] = xp[(size_t)(kkA + it * 4) * 100];
        } else {
            #pragma unroll
            for (int it = 0; it < 8; ++it) Xs[kkA + it * 4][tokA] = 0.f;
        }
        const float* wp = W + (size_t)o0 * 512 + c0 + kkB;
        #pragma unroll
        for (int it = 0; it < 8; ++it)
            Ws[kkB][obB + it * 8] = wp[(size_t)(obB + it * 8) * 512];
        __syncthreads();
        #pragma unroll
        for (int kk = 0; kk < 32; ++kk) {
            const float4 xv = *(const float4*)&Xs[kk][tr];
            const float4 wv = *(const float4*)&Ws[kk][oc];
            const float xa[4] = {xv.x, xv.y, xv.z, xv.w};
            const float wa[4] = {wv.x, wv.y, wv.z, wv.w};
            #pragma unroll
            for (int i = 0; i < 4; ++i)
                #pragma unroll
                for (int j = 0; j < 4; ++j)
                    acc[i][j] = fmaf(xa[i], wa[j], acc[i][j]);
        }
    }

    if (!TRANS) {
        #pragma unroll
        for (int i = 0; i < 4; ++i) {
            const int tg = t0 + tr + i;
            if (tg < ntok) {
                ushort4 o;
                o.x = f2bf(acc[i][0] + bias[o0 + oc + 0]);
                o.y = f2bf(acc[i][1] + bias[o0 + oc + 1]);
                o.z = f2bf(acc[i][2] + bias[o0 + oc + 2]);
                o.w = f2bf(acc[i][3] + bias[o0 + oc + 3]);
                *(ushort4*)&Y[((size_t)b * ntok + tg) * 512 + o0 + oc] = o;
            }
        }
    } else {
        __syncthreads();
        #pragma unroll
        for (int i = 0; i < 4; ++i)
            #pragma unroll
            for (int j = 0; j < 4; ++j)
                Ts[oc + j][tr + i] = f2bf(acc[i][j] + bias[o0 + oc + j]);
        __syncthreads();
        // write rows of Y[b][o][t]: 16 bf16 per thread, padded stride absorbs edges
        const int ol = t >> 2;
        const int tb2 = (t & 3) * 16;
        ushort* yp = Y + ((size_t)b * 512 + o0 + ol) * strideT + t0 + tb2;
        *(uint4*)yp       = *(uint4*)&Ts[ol][tb2];
        *(uint4*)(yp + 8) = *(uint4*)&Ts[ol][tb2 + 8];
    }
}

// ---------------------------------------------------------------------------
// oproj (fp32): Yf[b][n][c][l] = sum_o A[b][t][o] * W[c][o] + bias[c]
// ---------------------------------------------------------------------------
__global__ __launch_bounds__(256) void oproj_kernel(
    const float* __restrict__ A, const float* __restrict__ W,
    const float* __restrict__ bias, float* __restrict__ Y, int ntok)
{
    __shared__ float As[32][68];
    __shared__ float Ws[32][68];
    const int t  = threadIdx.x;
    const int t0 = blockIdx.x * 64;
    const int c0 = blockIdx.y * 64;
    const int b  = blockIdx.z;
    const int nN = ntok / 100;
    const int tr = (t >> 4) * 4;
    const int oc = (t & 15) * 4;
    float acc[4][4] = {};
    const int kkA = t & 31;
    const int tb  = t >> 5;

    for (int k0 = 0; k0 < 512; k0 += 32) {
        __syncthreads();
        #pragma unroll
        for (int it = 0; it < 8; ++it) {
            const int tok = tb + it * 8;
            const int tg = t0 + tok;
            As[kkA][tok] = (tg < ntok)
                ? A[((size_t)b * ntok + tg) * 512 + k0 + kkA] : 0.f;
        }
        const float* wp = W + (size_t)c0 * 512 + k0 + kkA;
        #pragma unroll
        for (int it = 0; it < 8; ++it)
            Ws[kkA][tb + it * 8] = wp[(size_t)(tb + it * 8) * 512];
        __syncthreads();
        #pragma unroll
        for (int kk = 0; kk < 32; ++kk) {
            const float4 xv = *(const float4*)&As[kk][tr];
            const float4 wv = *(const float4*)&Ws[kk][oc];
            const float xa[4] = {xv.x, xv.y, xv.z, xv.w};
            const float wa[4] = {wv.x, wv.y, wv.z, wv.w};
            #pragma unroll
            for (int i = 0; i < 4; ++i)
                #pragma unroll
                for (int j = 0; j < 4; ++j)
                    acc[i][j] = fmaf(xa[i], wa[j], acc[i][j]);
        }
    }
    #pragma unroll
    for (int i = 0; i < 4; ++i) {
        const int tg = t0 + tr + i;
        if (tg < ntok) {
            const int n = tg / 100, l = tg % 100;
            #pragma unroll
            for (int j = 0; j < 4; ++j)
                Y[(((size_t)b * nN + n) * 512 + c0 + oc + j) * 100 + l] =
                    acc[i][j] + bias[c0 + oc + j];
        }
    }
}

// ---------------------------------------------------------------------------
// MFMA flash attention. Block: 64 rows x head x (b,split). 4 waves, BK=64.
// R:[B][TR][512] bf16 rows; Kt:[B][TK][512] bf16 keys; Vt:[B][512][strideV].
// KSPLIT==1: normalized fp32 out to Aout. Else partial (acc,m,l) to PartO/Pml.
// LDS tiles XOR-swizzled (byte ^= (row&7)<<4) to kill stride-256/128 conflicts.
// ---------------------------------------------------------------------------
template<int KSPLIT>
__global__ __launch_bounds__(256) void attn_mfma_kernel(
    const ushort* __restrict__ R, const ushort* __restrict__ Kt,
    const ushort* __restrict__ Vt, float* __restrict__ Aout,
    float* __restrict__ PartO, float* __restrict__ Pml,
    int TR, int TK, int strideV, int nrb)
{
    __shared__ ushort Qs[64 * 128];
    __shared__ ushort Ks[64 * 128];
    __shared__ ushort Vs[128 * 64];
    __shared__ ushort Ps[64 * 64];

    const int t    = threadIdx.x;
    const int lane = t & 63;
    const int w    = t >> 6;
    const int rb   = blockIdx.x;
    const int h    = blockIdx.y;
    const int b    = blockIdx.z / KSPLIT;
    const int sp   = blockIdx.z % KSPLIT;
    const int r0   = rb * 64;
    const int ho   = h * 128;

    const int klen = (TK + KSPLIT - 1) / KSPLIT;
    const int kbeg = sp * klen;
    int kend = kbeg + klen; if (kend > TK) kend = TK;

    // ---- stage Q tile (swizzled), rows beyond TR zero-filled ----
    {
        const ushort* Rb = R + (size_t)b * TR * 512;
        #pragma unroll
        for (int i = 0; i < 4; ++i) {
            const int p = (t + i * 256) * 16;
            const int row = p >> 8, cb = p & 255;
            uint4 v = make_uint4(0, 0, 0, 0);
            if (r0 + row < TR)
                v = *(const uint4*)((const char*)(Rb + (size_t)(r0 + row) * 512 + ho) + cb);
            *(uint4*)((char*)Qs + row * 256 + (cb ^ ((row & 7) << 4))) = v;
        }
    }
    __syncthreads();

    // ---- hoist Q A-fragments (constant over key chunks) ----
    bf16x8 qa[4];
    {
        const int row = (w << 4) + (lane & 15);
        const int base = row * 256, sw = (row & 7) << 4, g16 = (lane >> 4) * 16;
        #pragma unroll
        for (int s = 0; s < 4; ++s)
            qa[s] = *(const bf16x8*)((const char*)Qs + base + ((s * 64 + g16) ^ sw));
    }

    float m_run[4], l_run[4];
    #pragma unroll
    for (int r = 0; r < 4; ++r) { m_run[r] = -3.0e38f; l_run[r] = 0.f; }
    f32x4 acc[8];
    #pragma unroll
    for (int g = 0; g < 8; ++g) acc[g] = (f32x4){0.f, 0.f, 0.f, 0.f};

    for (int kbase = kbeg; kbase < kend; kbase += 64) {
        __syncthreads();   // previous chunk's K/V reads complete
        // ---- stage K chunk ----
        {
            const ushort* Kb = Kt + (size_t)b * TK * 512;
            #pragma unroll
            for (int i = 0; i < 4; ++i) {
                const int p = (t + i * 256) * 16;
                const int row = p >> 8, cb = p & 255;
                uint4 v = make_uint4(0, 0, 0, 0);
                if (kbase + row < kend)
                    v = *(const uint4*)((const char*)(Kb + (size_t)(kbase + row) * 512 + ho) + cb);
                *(uint4*)((char*)Ks + row * 256 + (cb ^ ((row & 7) << 4))) = v;
            }
        }
        // ---- stage V^T chunk [d][key] ----
        {
            const ushort* Vb = Vt + ((size_t)b * 512 + ho) * strideV;
            #pragma unroll
            for (int i = 0; i < 4; ++i) {
                const int p = (t + i * 256) * 16;
                const int d = p >> 7, cb = p & 127;
                const int k0 = kbase + (cb >> 1);
                const ushort* src = Vb + (size_t)d * strideV + k0;
                uint4 v = make_uint4(0, 0, 0, 0);
                if (k0 + 8 <= kend) {
                    v = *(const uint4*)src;
                } else {
                    union { ushort u[8]; uint4 v4; } tmp;
                    #pragma unroll
                    for (int j = 0; j < 8; ++j)
                        tmp.u[j] = (k0 + j < kend) ? src[j] : (ushort)0;
                    v = tmp.v4;
                }
                *(uint4*)((char*)Vs + d * 128 + (cb ^ ((d & 7) << 4))) = v;
            }
        }
        __syncthreads();

        // ---- QK^T: wave w owns rows [16w,16w+16), 4 col-frags x 4 k-steps ----
        f32x4 sf[4];
        #pragma unroll
        for (int f = 0; f < 4; ++f) {
            f32x4 s = (f32x4){0.f, 0.f, 0.f, 0.f};
            const int kr = f * 16 + (lane & 15);
            const int kb2 = kr * 256, sw = (kr & 7) << 4, g16 = (lane >> 4) * 16;
            #pragma unroll
            for (int s4 = 0; s4 < 4; ++s4) {
                bf16x8 kf = *(const bf16x8*)((const char*)Ks + kb2 + ((s4 * 64 + g16) ^ sw));
                s = __builtin_amdgcn_mfma_f32_16x16x32_bf16(qa[s4], kf, s, 0, 0, 0);
            }
            sf[f] = s;
        }
        // ---- scale + key mask ----
        #pragma unroll
        for (int f = 0; f < 4; ++f) {
            const bool ok = (kbase + f * 16 + (lane & 15)) < kend;
            #pragma unroll
            for (int r = 0; r < 4; ++r)
                sf[f][r] = ok ? sf[f][r] * SCALE_ : -3.0e38f;
        }
        // ---- online softmax (16-lane butterflies; lane owns 4 rows) ----
        float scal[4];
        #pragma unroll
        for (int r = 0; r < 4; ++r) {
            float mx = fmaxf(fmaxf(sf[0][r], sf[1][r]), fmaxf(sf[2][r], sf[3][r]));
            #pragma unroll
            for (int off = 1; off < 16; off <<= 1)
                mx = fmaxf(mx, __shfl_xor(mx, off));
            const float mn = fmaxf(m_run[r], mx);
            scal[r] = __expf(m_run[r] - mn);
            m_run[r] = mn;
        }
        float rsum[4] = {0.f, 0.f, 0.f, 0.f};
        {
            const int rbase = (w << 4) + ((lane >> 4) << 2);
            #pragma unroll
            for (int f = 0; f < 4; ++f) {
                const int colb = (f * 16 + (lane & 15)) * 2;
                #pragma unroll
                for (int r = 0; r < 4; ++r) {
                    const float p = __expf(sf[f][r] - m_run[r]);
                    rsum[r] += p;
                    const int row = rbase + r;
                    *(ushort*)((char*)Ps + row * 128 + (colb ^ ((row & 7) << 4))) = f2bf(p);
                }
            }
        }
        #pragma unroll
        for (int r = 0; r < 4; ++r) {
            float s = rsum[r];
            #pragma unroll
            for (int off = 1; off < 16; off <<= 1) s += __shfl_xor(s, off);
            l_run[r] = l_run[r] * scal[r] + s;
        }
        #pragma unroll
        for (int g = 0; g < 8; ++g)
            #pragma unroll
            for (int r = 0; r < 4; ++r) acc[g][r] *= scal[r];

        // ---- PV: O[16 x 128] += P[16 x 64] * V[64 x 128] ----
        {
            const int ar = (w << 4) + (lane & 15);
            const int ab = ar * 128, asw = (ar & 7) << 4, g16 = (lane >> 4) * 16;
            bf16x8 pa0 = *(const bf16x8*)((const char*)Ps + ab + ((g16) ^ asw));
            bf16x8 pa1 = *(const bf16x8*)((const char*)Ps + ab + ((64 + g16) ^ asw));
            #pragma unroll
            for (int g = 0; g < 8; ++g) {
                const int dr = g * 16 + (lane & 15);
                const int vb = dr * 128, vsw = (dr & 7) << 4;
                bf16x8 v0 = *(const bf16x8*)((const char*)Vs + vb + ((g16) ^ vsw));
                bf16x8 v1 = *(const bf16x8*)((const char*)Vs + vb + ((64 + g16) ^ vsw));
                acc[g] = __builtin_amdgcn_mfma_f32_16x16x32_bf16(pa0, v0, acc[g], 0, 0, 0);
                acc[g] = __builtin_amdgcn_mfma_f32_16x16x32_bf16(pa1, v1, acc[g], 0, 0, 0);
            }
        }
    }

    // ---- epilogue ----
    const int rloc = (w << 4) + ((lane >> 4) << 2);
    if (KSPLIT == 1) {
        #pragma unroll
        for (int r = 0; r < 4; ++r) {
            const int row = r0 + rloc + r;
            if (row < TR) {
                const float inv = 1.f / l_run[r];
                float* Ab = Aout + ((size_t)b * TR + row) * 512 + ho + (lane & 15);
                #pragma unroll
                for (int g = 0; g < 8; ++g) Ab[g * 16] = acc[g][r] * inv;
            }
        }
    } else {
        const size_t tile = (((size_t)b * 4 + h) * nrb + rb) * KSPLIT + sp;
        float* Po = PartO + tile * (64 * 128);
        float* Pm = Pml + tile * 128;
        #pragma unroll
        for (int r = 0; r < 4; ++r) {
            const int row = rloc + r;
            float* pp = Po + row * 128 + (lane & 15);
            #pragma unroll
            for (int g = 0; g < 8; ++g) pp[g * 16] = acc[g][r];
            if ((lane & 15) == 0) { Pm[row] = m_run[r]; Pm[64 + row] = l_run[r]; }
        }
    }
}

// ---------------------------------------------------------------------------
// combine split-K partials: O = sum_i e^{m_i-M} acc_i / sum_i e^{m_i-M} l_i
// ---------------------------------------------------------------------------
#define KSPL 8
__global__ __launch_bounds__(256) void attn_combine_kernel(
    const float* __restrict__ PartO, const float* __restrict__ Pml,
    float* __restrict__ Aout, int TR, int nrb)
{
    const int t = threadIdx.x;
    const int rb = blockIdx.x, h = blockIdx.y, b = blockIdx.z;
    const int row = t >> 2;
    const int dq = (t & 3) * 32;
    const int r0 = rb * 64;
    const size_t tbase = (((size_t)b * 4 + h) * nrb + rb) * KSPL;

    float M = -3.0e38f;
    #pragma unroll
    for (int i = 0; i < KSPL; ++i)
        M = fmaxf(M, Pml[(tbase + i) * 128 + row]);
    float wt[KSPL], L = 0.f;
    #pragma unroll
    for (int i = 0; i < KSPL; ++i) {
        const float wi = __expf(Pml[(tbase + i) * 128 + row] - M);
        wt[i] = wi;
        L += wi * Pml[(tbase + i) * 128 + 64 + row];
    }
    if (r0 + row >= TR) return;
    const float invL = 1.f / L;

    float o[32];
    #pragma unroll
    for (int j = 0; j < 32; ++j) o[j] = 0.f;
    #pragma unroll
    for (int i = 0; i < KSPL; ++i) {
        const float* pp = PartO + (tbase + i) * (64 * 128) + row * 128 + dq;
        #pragma unroll
        for (int j = 0; j < 32; j += 4) {
            const float4 v = *(const float4*)(pp + j);
            o[j] += wt[i] * v.x; o[j+1] += wt[i] * v.y;
            o[j+2] += wt[i] * v.z; o[j+3] += wt[i] * v.w;
        }
    }
    float* Ab = Aout + ((size_t)b * TR + r0 + row) * 512 + h * 128 + dq;
    #pragma unroll
    for (int j = 0; j < 32; j += 4) {
        float4 v;
        v.x = o[j] * invL; v.y = o[j+1] * invL;
        v.z = o[j+2] * invL; v.w = o[j+3] * invL;
        *(float4*)(Ab + j) = v;
    }
}

// ---------------------------------------------------------------------------
extern "C" void kernel_launch(void* const* d_in, const int* in_sizes, int n_in,
                              void* d_out, int out_size, void* d_ws, size_t ws_size,
                              hipStream_t stream) {
    const float* f1  = (const float*)d_in[0];
    const float* f2  = (const float*)d_in[1];
    const float* Wk1 = (const float*)d_in[2];
    const float* bk1 = (const float*)d_in[3];
    const float* Wv1 = (const float*)d_in[4];
    const float* bv1 = (const float*)d_in[5];
    const float* Wq2 = (const float*)d_in[6];
    const float* bq2 = (const float*)d_in[7];
    // d_in[8..9] = Wk2/bk2: unused by the reference outputs.
    const float* Wv2 = (const float*)d_in[10];
    const float* bv2 = (const float*)d_in[11];
    const float* Wo1 = (const float*)d_in[12];
    const float* bo1 = (const float*)d_in[13];
    const float* Wo2 = (const float*)d_in[14];
    const float* bo2 = (const float*)d_in[15];
    float* out = (float*)d_out;

    // ---- workspace layout (165.4 MB) ----
    ushort* K1  = (ushort*)d_ws;          // [4][ 500][512] bf16
    ushort* Q2  = K1 + (size_t)4*500*512;           // [4][7500][512] bf16
    ushort* V1t = Q2 + (size_t)4*7500*512;          // [4][512][ 512] bf16 (d-major, padded)
    ushort* V2t = V1t + (size_t)4*512*512;          // [4][512][7552] bf16 (d-major, padded)
    float* A1    = (float*)(V2t + (size_t)4*512*7552);  // [4][ 500][512] f32
    float* A2    = A1 + (size_t)4*500*512;              // [4][7500][512] f32
    float* PartO = A2 + (size_t)4*7500*512;             // 1024 x [64][128] f32
    float* Pml   = PartO + (size_t)1024*64*128;         // 1024 x [128] f32

    const dim3 blk(256);

    proj_kernel<0><<<dim3(8, 8, 4),   blk, 0, stream>>>(f1, Wk1, bk1, K1, 500, 0);
    proj_kernel<1><<<dim3(8, 8, 4),   blk, 0, stream>>>(f1, Wv1, bv1, V1t, 500, 512);
    proj_kernel<0><<<dim3(118, 8, 4), blk, 0, stream>>>(f2, Wq2, bq2, Q2, 7500, 0);
    proj_kernel<1><<<dim3(118, 8, 4), blk, 0, stream>>>(f2, Wv2, bv2, V2t, 7500, 7552);

    // out2 direction: rows = Q2 (7500), keys = K1/V1 (500)
    attn_mfma_kernel<1><<<dim3(118, 4, 4), blk, 0, stream>>>(
        Q2, K1, V1t, A2, nullptr, nullptr, 7500, 500, 512, 118);
    // out1 direction: rows = K1 (500), keys = Q2/V2 (7500), split-K x8
    attn_mfma_kernel<KSPL><<<dim3(8, 4, 4 * KSPL), blk, 0, stream>>>(
        K1, Q2, V2t, nullptr, PartO, Pml, 500, 7500, 7552, 8);
    attn_combine_kernel<<<dim3(8, 4, 4), blk, 0, stream>>>(PartO, Pml, A1, 500, 8);

    // o-projections (fp32) with fused [B,n,L,C] -> [B,n,C,L] transpose
    oproj_kernel<<<dim3(8, 8, 4),   blk, 0, stream>>>(A1, Wo1, bo1, out, 500);
    oproj_kernel<<<dim3(118, 8, 4), blk, 0, stream>>>(A2, Wo2, bo2, out + (size_t)4*500*512, 7500);
}

// Round 3
// 487.592 us; speedup vs baseline: 5.8941x; 2.4660x over previous
//
#include <hip/hip_runtime.h>
#include <hip/hip_bf16.h>

// MultiHeadCrossAttention: B=4, C=512, HEADS=4, HD=128, L=100
// f1 -> 500 support tokens/batch, f2 -> 7500 query tokens/batch.
// out1: [4,5,512,100], out2: [4,75,512,100] concatenated in d_out.

#define SCALE_ 0.08838834764831845f   // 128^-0.5

using bf16x8 = __attribute__((ext_vector_type(8))) short;
using f32x4  = __attribute__((ext_vector_type(4))) float;

__device__ inline ushort f2bf(float x) {
    union { float f; unsigned u; } v; v.f = x;
    unsigned r = v.u + 0x7fff + ((v.u >> 16) & 1);   // RNE
    return (ushort)(r >> 16);
}

__device__ inline void gll16(const ushort* g, ushort* l) {
    __builtin_amdgcn_global_load_lds(
        (const __attribute__((address_space(1))) void*)g,
        (__attribute__((address_space(3))) void*)l, 16, 0, 0);
}

// ---------------------------------------------------------------------------
// totok: X slab [512][100] f32 (one (b,n)) -> Y tokens [100][512] bf16.
// grid = B*n, block 256.
// ---------------------------------------------------------------------------
__global__ __launch_bounds__(256) void totok_kernel(
    const float* __restrict__ X, ushort* __restrict__ Y)
{
    __shared__ ushort Ts[100 * 136];
    const int t  = threadIdx.x;
    const int bn = blockIdx.x;
    const float* Xb = X + (size_t)bn * 51200;
    ushort* Yb = Y + (size_t)bn * 100 * 512;

    for (int c0 = 0; c0 < 512; c0 += 128) {
        __syncthreads();
        #pragma unroll
        for (int i = 0; i < 50; ++i) {
            const int id = i * 256 + t;
            const int c = id / 100, l = id - c * 100;
            Ts[l * 136 + c] = f2bf(Xb[(size_t)(c0 + c) * 100 + l]);
        }
        __syncthreads();
        #pragma unroll
        for (int i = 0; i < 7; ++i) {
            const int id = i * 256 + t;
            if (id < 1600) {
                const int cg = id & 15, l = id >> 4;
                *(uint4*)(Yb + (size_t)l * 512 + c0 + cg * 8) =
                    *(const uint4*)&Ts[l * 136 + cg * 8];
            }
        }
    }
}

// ---------------------------------------------------------------------------
// weight fp32 -> bf16 (6 x 512x512), grid (256, 6)
// ---------------------------------------------------------------------------
struct WPtrs { const float* p[6]; };
__global__ __launch_bounds__(256) void wconv_kernel(WPtrs wp, ushort* __restrict__ dst)
{
    const int wsel = blockIdx.y;
    const float* src = wp.p[wsel];
    ushort* d = dst + (size_t)wsel * 262144;
    const int idx = (blockIdx.x * 256 + threadIdx.x) * 4;
    const float4 v = *(const float4*)(src + idx);
    ushort4 o;
    o.x = f2bf(v.x); o.y = f2bf(v.y); o.z = f2bf(v.z); o.w = f2bf(v.w);
    *(ushort4*)(d + idx) = o;
}

// ---------------------------------------------------------------------------
// gemm_nt: C[m][n] = sum_k A[m][k]*B[n][k] (+bias), K=512 fixed, lda=ldb=512.
// 128x128 tile, BK=64, 4 waves, global_load_lds staging w/ XOR-preswizzled src.
// EPI 0: bf16 C row-major [Mrows][ldC] (col-overrun allowed into padded ldC).
//        BAXIS 1: bias per col; BAXIS 0: bias per row.
// EPI 2: fp32 final out: C row=c (bias per row), col=token t; writes
//        out + b*sC + (t/100)*51200 + c*100 + (t%100).
// ---------------------------------------------------------------------------
template<int EPI, int BAXIS>
__global__ __launch_bounds__(256) void gemm_nt(
    const ushort* __restrict__ A, size_t sA,
    const ushort* __restrict__ B, size_t sB,
    const float* __restrict__ bias, void* __restrict__ C, size_t sC, int ldC,
    int Mrows, int Ncols)
{
    __shared__ ushort smem[17408];          // 34.8 KB: staging 32KB / epi overlay
    ushort* As = smem;                       // [128][64]
    ushort* Bs = smem + 8192;                // [128][64]

    const int t    = threadIdx.x;
    const int lane = t & 63;
    const int w    = t >> 6;
    const int mw   = (w >> 1) * 64;
    const int nw   = (w & 1) * 64;
    const int m0   = blockIdx.x * 128;
    const int n0   = blockIdx.y * 128;
    const int b    = blockIdx.z;
    const ushort* Ab = A + (size_t)b * sA;
    const ushort* Bb = B + (size_t)b * sB;

    f32x4 acc[4][4];
    #pragma unroll
    for (int i = 0; i < 4; ++i)
        #pragma unroll
        for (int j = 0; j < 4; ++j) acc[i][j] = (f32x4){0.f, 0.f, 0.f, 0.f};

    const int lr = lane >> 3;      // 0..7 row within 8-row group
    const int cb = lane & 7;       // 16B granule within row

    for (int k0 = 0; k0 < 512; k0 += 64) {
        if (k0) __syncthreads();
        #pragma unroll
        for (int i = 0; i < 4; ++i) {
            const int row = w * 32 + i * 8 + lr;
            const int ar = min(m0 + row, Mrows - 1);
            gll16(Ab + (size_t)ar * 512 + k0 + ((cb ^ (row & 7)) * 8),
                  As + (w * 32 + i * 8) * 64);
            const int br = min(n0 + row, Ncols - 1);
            gll16(Bb + (size_t)br * 512 + k0 + ((cb ^ (row & 7)) * 8),
                  Bs + (w * 32 + i * 8) * 64);
        }
        __syncthreads();
        #pragma unroll
        for (int ks = 0; ks < 2; ++ks) {
            bf16x8 af[4], bv[4];
            #pragma unroll
            for (int mf = 0; mf < 4; ++mf) {
                const int row = mw + mf * 16 + (lane & 15);
                af[mf] = *(const bf16x8*)((const char*)As + row * 128 +
                          ((ks * 64 + (lane >> 4) * 16) ^ ((row & 7) << 4)));
            }
            #pragma unroll
            for (int nf = 0; nf < 4; ++nf) {
                const int row = nw + nf * 16 + (lane & 15);
                bv[nf] = *(const bf16x8*)((const char*)Bs + row * 128 +
                          ((ks * 64 + (lane >> 4) * 16) ^ ((row & 7) << 4)));
            }
            #pragma unroll
            for (int mf = 0; mf < 4; ++mf)
                #pragma unroll
                for (int nf = 0; nf < 4; ++nf)
                    acc[mf][nf] = __builtin_amdgcn_mfma_f32_16x16x32_bf16(
                        af[mf], bv[nf], acc[mf][nf], 0, 0, 0);
        }
    }
    __syncthreads();

    if (EPI == 0) {
        // bias values
        float bcol[4];
        if (BAXIS == 1) {
            #pragma unroll
            for (int nf = 0; nf < 4; ++nf)
                bcol[nf] = bias[n0 + nw + nf * 16 + (lane & 15)];
        }
        ushort* Ts = smem;   // [128][136]
        #pragma unroll
        for (int mf = 0; mf < 4; ++mf) {
            #pragma unroll
            for (int r = 0; r < 4; ++r) {
                const int row = mw + mf * 16 + (lane >> 4) * 4 + r;
                const float brow = (BAXIS == 0) ? bias[m0 + row] : 0.f;
                #pragma unroll
                for (int nf = 0; nf < 4; ++nf) {
                    const int col = nw + nf * 16 + (lane & 15);
                    const float v = acc[mf][nf][r] +
                                    ((BAXIS == 1) ? bcol[nf] : brow);
                    Ts[row * 136 + col] = f2bf(v);
                }
            }
        }
        __syncthreads();
        ushort* Cb = (ushort*)C + (size_t)b * sC;
        #pragma unroll
        for (int i = 0; i < 8; ++i) {
            const int id = i * 256 + t;
            const int row = id >> 4, cg = id & 15;
            if (m0 + row < Mrows)
                *(uint4*)(Cb + (size_t)(m0 + row) * ldC + n0 + cg * 8) =
                    *(const uint4*)&Ts[row * 136 + cg * 8];
        }
    } else {
        // EPI 2: fp32 final out with [c][l] scatter
        float* Ts2 = (float*)smem;   // [64][132]
        float* Cb = (float*)C + (size_t)b * sC;
        const int colL = t & 127;
        const int rb2 = t >> 7;
        const int tg = n0 + colL;
        int nIdx = 0, lIdx = 0;
        if (tg < Ncols) { nIdx = tg / 100; lIdx = tg - nIdx * 100; }
        #pragma unroll
        for (int h = 0; h < 2; ++h) {
            __syncthreads();
            if ((mw >> 6) == h) {
                #pragma unroll
                for (int mf = 0; mf < 4; ++mf) {
                    #pragma unroll
                    for (int r = 0; r < 4; ++r) {
                        const int rowl = mf * 16 + (lane >> 4) * 4 + r;
                        const float brow = bias[m0 + h * 64 + rowl];
                        #pragma unroll
                        for (int nf = 0; nf < 4; ++nf) {
                            const int col = nw + nf * 16 + (lane & 15);
                            Ts2[rowl * 132 + col] = acc[mf][nf][r] + brow;
                        }
                    }
                }
            }
            __syncthreads();
            if (tg < Ncols) {
                float* dst = Cb + (size_t)nIdx * 51200 + lIdx;
                #pragma unroll
                for (int i = 0; i < 32; ++i) {
                    const int rowl = i * 2 + rb2;
                    const int c = m0 + h * 64 + rowl;
                    dst[(size_t)c * 100] = Ts2[rowl * 132 + colL];
                }
            }
        }
    }
}

// ---------------------------------------------------------------------------
// MFMA flash attention (unchanged structure; bf16 output now).
// ---------------------------------------------------------------------------
template<int KSPLIT>
__global__ __launch_bounds__(256) void attn_mfma_kernel(
    const ushort* __restrict__ R, const ushort* __restrict__ Kt,
    const ushort* __restrict__ Vt, ushort* __restrict__ Aout,
    float* __restrict__ PartO, float* __restrict__ Pml,
    int TR, int TK, int strideV, int nrb)
{
    __shared__ ushort Qs[64 * 128];
    __shared__ ushort Ks[64 * 128];
    __shared__ ushort Vs[128 * 64];
    __shared__ ushort Ps[64 * 64];

    const int t    = threadIdx.x;
    const int lane = t & 63;
    const int w    = t >> 6;
    const int rb   = blockIdx.x;
    const int h    = blockIdx.y;
    const int b    = blockIdx.z / KSPLIT;
    const int sp   = blockIdx.z % KSPLIT;
    const int r0   = rb * 64;
    const int ho   = h * 128;

    const int klen = (TK + KSPLIT - 1) / KSPLIT;
    const int kbeg = sp * klen;
    int kend = kbeg + klen; if (kend > TK) kend = TK;

    {
        const ushort* Rb = R + (size_t)b * TR * 512;
        #pragma unroll
        for (int i = 0; i < 4; ++i) {
            const int p = (t + i * 256) * 16;
            const int row = p >> 8, cbb = p & 255;
            uint4 v = make_uint4(0, 0, 0, 0);
            if (r0 + row < TR)
                v = *(const uint4*)((const char*)(Rb + (size_t)(r0 + row) * 512 + ho) + cbb);
            *(uint4*)((char*)Qs + row * 256 + (cbb ^ ((row & 7) << 4))) = v;
        }
    }
    __syncthreads();

    bf16x8 qa[4];
    {
        const int row = (w << 4) + (lane & 15);
        const int base = row * 256, sw = (row & 7) << 4, g16 = (lane >> 4) * 16;
        #pragma unroll
        for (int s = 0; s < 4; ++s)
            qa[s] = *(const bf16x8*)((const char*)Qs + base + ((s * 64 + g16) ^ sw));
    }

    float m_run[4], l_run[4];
    #pragma unroll
    for (int r = 0; r < 4; ++r) { m_run[r] = -3.0e38f; l_run[r] = 0.f; }
    f32x4 acc[8];
    #pragma unroll
    for (int g = 0; g < 8; ++g) acc[g] = (f32x4){0.f, 0.f, 0.f, 0.f};

    for (int kbase = kbeg; kbase < kend; kbase += 64) {
        __syncthreads();
        {
            const ushort* Kb = Kt + (size_t)b * TK * 512;
            #pragma unroll
            for (int i = 0; i < 4; ++i) {
                const int p = (t + i * 256) * 16;
                const int row = p >> 8, cbb = p & 255;
                uint4 v = make_uint4(0, 0, 0, 0);
                if (kbase + row < kend)
                    v = *(const uint4*)((const char*)(Kb + (size_t)(kbase + row) * 512 + ho) + cbb);
                *(uint4*)((char*)Ks + row * 256 + (cbb ^ ((row & 7) << 4))) = v;
            }
        }
        {
            const ushort* Vb = Vt + ((size_t)b * 512 + ho) * strideV;
            #pragma unroll
            for (int i = 0; i < 4; ++i) {
                const int p = (t + i * 256) * 16;
                const int d = p >> 7, cbb = p & 127;
                const int k0 = kbase + (cbb >> 1);
                const ushort* src = Vb + (size_t)d * strideV + k0;
                uint4 v = make_uint4(0, 0, 0, 0);
                if (k0 + 8 <= kend) {
                    v = *(const uint4*)src;
                } else {
                    union { ushort u[8]; uint4 v4; } tmp;
                    #pragma unroll
                    for (int j = 0; j < 8; ++j)
                        tmp.u[j] = (k0 + j < kend) ? src[j] : (ushort)0;
                    v = tmp.v4;
                }
                *(uint4*)((char*)Vs + d * 128 + (cbb ^ ((d & 7) << 4))) = v;
            }
        }
        __syncthreads();

        f32x4 sf[4];
        #pragma unroll
        for (int f = 0; f < 4; ++f) {
            f32x4 s = (f32x4){0.f, 0.f, 0.f, 0.f};
            const int kr = f * 16 + (lane & 15);
            const int kb2 = kr * 256, sw = (kr & 7) << 4, g16 = (lane >> 4) * 16;
            #pragma unroll
            for (int s4 = 0; s4 < 4; ++s4) {
                bf16x8 kf = *(const bf16x8*)((const char*)Ks + kb2 + ((s4 * 64 + g16) ^ sw));
                s = __builtin_amdgcn_mfma_f32_16x16x32_bf16(qa[s4], kf, s, 0, 0, 0);
            }
            sf[f] = s;
        }
        #pragma unroll
        for (int f = 0; f < 4; ++f) {
            const bool ok = (kbase + f * 16 + (lane & 15)) < kend;
            #pragma unroll
            for (int r = 0; r < 4; ++r)
                sf[f][r] = ok ? sf[f][r] * SCALE_ : -3.0e38f;
        }
        float scal[4];
        #pragma unroll
        for (int r = 0; r < 4; ++r) {
            float mx = fmaxf(fmaxf(sf[0][r], sf[1][r]), fmaxf(sf[2][r], sf[3][r]));
            #pragma unroll
            for (int off = 1; off < 16; off <<= 1)
                mx = fmaxf(mx, __shfl_xor(mx, off));
            const float mn = fmaxf(m_run[r], mx);
            scal[r] = __expf(m_run[r] - mn);
            m_run[r] = mn;
        }
        float rsum[4] = {0.f, 0.f, 0.f, 0.f};
        {
            const int rbase = (w << 4) + ((lane >> 4) << 2);
            #pragma unroll
            for (int f = 0; f < 4; ++f) {
                const int colb = (f * 16 + (lane & 15)) * 2;
                #pragma unroll
                for (int r = 0; r < 4; ++r) {
                    const float p = __expf(sf[f][r] - m_run[r]);
                    rsum[r] += p;
                    const int row = rbase + r;
                    *(ushort*)((char*)Ps + row * 128 + (colb ^ ((row & 7) << 4))) = f2bf(p);
                }
            }
        }
        #pragma unroll
        for (int r = 0; r < 4; ++r) {
            float s = rsum[r];
            #pragma unroll
            for (int off = 1; off < 16; off <<= 1) s += __shfl_xor(s, off);
            l_run[r] = l_run[r] * scal[r] + s;
        }
        #pragma unroll
        for (int g = 0; g < 8; ++g)
            #pragma unroll
            for (int r = 0; r < 4; ++r) acc[g][r] *= scal[r];

        {
            const int ar = (w << 4) + (lane & 15);
            const int ab = ar * 128, asw = (ar & 7) << 4, g16 = (lane >> 4) * 16;
            bf16x8 pa0 = *(const bf16x8*)((const char*)Ps + ab + ((g16) ^ asw));
            bf16x8 pa1 = *(const bf16x8*)((const char*)Ps + ab + ((64 + g16) ^ asw));
            #pragma unroll
            for (int g = 0; g < 8; ++g) {
                const int dr = g * 16 + (lane & 15);
                const int vb = dr * 128, vsw = (dr & 7) << 4;
                bf16x8 v0 = *(const bf16x8*)((const char*)Vs + vb + ((g16) ^ vsw));
                bf16x8 v1 = *(const bf16x8*)((const char*)Vs + vb + ((64 + g16) ^ vsw));
                acc[g] = __builtin_amdgcn_mfma_f32_16x16x32_bf16(pa0, v0, acc[g], 0, 0, 0);
                acc[g] = __builtin_amdgcn_mfma_f32_16x16x32_bf16(pa1, v1, acc[g], 0, 0, 0);
            }
        }
    }

    const int rloc = (w << 4) + ((lane >> 4) << 2);
    if (KSPLIT == 1) {
        #pragma unroll
        for (int r = 0; r < 4; ++r) {
            const int row = r0 + rloc + r;
            if (row < TR) {
                const float inv = 1.f / l_run[r];
                ushort* Ab2 = Aout + ((size_t)b * TR + row) * 512 + ho + (lane & 15);
                #pragma unroll
                for (int g = 0; g < 8; ++g) Ab2[g * 16] = f2bf(acc[g][r] * inv);
            }
        }
    } else {
        const size_t tile = (((size_t)b * 4 + h) * nrb + rb) * KSPLIT + sp;
        float* Po = PartO + tile * (64 * 128);
        float* Pm = Pml + tile * 128;
        #pragma unroll
        for (int r = 0; r < 4; ++r) {
            const int row = rloc + r;
            float* pp = Po + row * 128 + (lane & 15);
            #pragma unroll
            for (int g = 0; g < 8; ++g) pp[g * 16] = acc[g][r];
            if ((lane & 15) == 0) { Pm[row] = m_run[r]; Pm[64 + row] = l_run[r]; }
        }
    }
}

// ---------------------------------------------------------------------------
#define KSPL 8
__global__ __launch_bounds__(256) void attn_combine_kernel(
    const float* __restrict__ PartO, const float* __restrict__ Pml,
    ushort* __restrict__ Aout, int TR, int nrb)
{
    const int t = threadIdx.x;
    const int rb = blockIdx.x, h = blockIdx.y, b = blockIdx.z;
    const int row = t >> 2;
    const int dq = (t & 3) * 32;
    const int r0 = rb * 64;
    const size_t tbase = (((size_t)b * 4 + h) * nrb + rb) * KSPL;

    float M = -3.0e38f;
    #pragma unroll
    for (int i = 0; i < KSPL; ++i)
        M = fmaxf(M, Pml[(tbase + i) * 128 + row]);
    float wt[KSPL], L = 0.f;
    #pragma unroll
    for (int i = 0; i < KSPL; ++i) {
        const float wi = __expf(Pml[(tbase + i) * 128 + row] - M);
        wt[i] = wi;
        L += wi * Pml[(tbase + i) * 128 + 64 + row];
    }
    if (r0 + row >= TR) return;
    const float invL = 1.f / L;

    float o[32];
    #pragma unroll
    for (int j = 0; j < 32; ++j) o[j] = 0.f;
    #pragma unroll
    for (int i = 0; i < KSPL; ++i) {
        const float* pp = PartO + (tbase + i) * (64 * 128) + row * 128 + dq;
        #pragma unroll
        for (int j = 0; j < 32; j += 4) {
            const float4 v = *(const float4*)(pp + j);
            o[j] += wt[i] * v.x; o[j+1] += wt[i] * v.y;
            o[j+2] += wt[i] * v.z; o[j+3] += wt[i] * v.w;
        }
    }
    ushort* Ab = Aout + ((size_t)b * TR + r0 + row) * 512 + h * 128 + dq;
    #pragma unroll
    for (int j = 0; j < 32; j += 4) {
        ushort4 v;
        v.x = f2bf(o[j] * invL); v.y = f2bf(o[j+1] * invL);
        v.z = f2bf(o[j+2] * invL); v.w = f2bf(o[j+3] * invL);
        *(ushort4*)(Ab + j) = v;
    }
}

// ---------------------------------------------------------------------------
extern "C" void kernel_launch(void* const* d_in, const int* in_sizes, int n_in,
                              void* d_out, int out_size, void* d_ws, size_t ws_size,
                              hipStream_t stream) {
    const float* f1  = (const float*)d_in[0];
    const float* f2  = (const float*)d_in[1];
    const float* Wk1 = (const float*)d_in[2];
    const float* bk1 = (const float*)d_in[3];
    const float* Wv1 = (const float*)d_in[4];
    const float* bv1 = (const float*)d_in[5];
    const float* Wq2 = (const float*)d_in[6];
    const float* bq2 = (const float*)d_in[7];
    // d_in[8..9] = Wk2/bk2: unused by the reference outputs.
    const float* Wv2 = (const float*)d_in[10];
    const float* bv2 = (const float*)d_in[11];
    const float* Wo1 = (const float*)d_in[12];
    const float* bo1 = (const float*)d_in[13];
    const float* Wo2 = (const float*)d_in[14];
    const float* bo2 = (const float*)d_in[15];
    float* out = (float*)d_out;

    // ---- workspace layout (~169 MB) ----
    ushort* f1t = (ushort*)d_ws;                    // [4* 500][512]
    ushort* f2t = f1t + (size_t)1024000;            // [4*7500][512]
    ushort* Wb  = f2t + (size_t)15360000;           // [6][512][512]
    ushort* K1  = Wb  + (size_t)1572864;            // [4* 500][512]
    ushort* Q2  = K1  + (size_t)1024000;            // [4*7500][512]
    ushort* V1t = Q2  + (size_t)15360000;           // [4][512][512]
    ushort* V2t = V1t + (size_t)1048576;            // [4][512][7552]
    ushort* A1  = V2t + (size_t)15466496;           // [4* 500][512]
    ushort* A2  = A1  + (size_t)1024000;            // [4*7500][512]
    float* PartO = (float*)(A2 + (size_t)15360000); // 1024 x [64][128]
    float* Pml   = PartO + (size_t)1024*64*128;     // 1024 x [128]

    const dim3 blk(256);

    // pre-passes
    WPtrs wp; wp.p[0]=Wk1; wp.p[1]=Wv1; wp.p[2]=Wq2; wp.p[3]=Wv2; wp.p[4]=Wo1; wp.p[5]=Wo2;
    wconv_kernel<<<dim3(256, 6), blk, 0, stream>>>(wp, Wb);
    totok_kernel<<<dim3(20),  blk, 0, stream>>>(f1, f1t);
    totok_kernel<<<dim3(300), blk, 0, stream>>>(f2, f2t);

    const ushort* Wk1b = Wb;
    const ushort* Wv1b = Wb + 262144;
    const ushort* Wq2b = Wb + 2*262144;
    const ushort* Wv2b = Wb + 3*262144;
    const ushort* Wo1b = Wb + 4*262144;
    const ushort* Wo2b = Wb + 5*262144;

    // projections (batch-flattened rows where possible)
    gemm_nt<0,1><<<dim3(16, 4, 1),  blk, 0, stream>>>(f1t, 0, Wk1b, 0, bk1, K1, 0, 512, 2000, 512);
    gemm_nt<0,1><<<dim3(235, 4, 1), blk, 0, stream>>>(f2t, 0, Wq2b, 0, bq2, Q2, 0, 512, 30000, 512);
    // V projections, role-swapped -> d-major output
    gemm_nt<0,0><<<dim3(4, 4, 4),  blk, 0, stream>>>(Wv1b, 0, f1t, (size_t)500*512,  bv1, V1t, (size_t)512*512,  512,  512, 500);
    gemm_nt<0,0><<<dim3(4, 59, 4), blk, 0, stream>>>(Wv2b, 0, f2t, (size_t)7500*512, bv2, V2t, (size_t)512*7552, 7552, 512, 7500);

    // attention
    attn_mfma_kernel<1><<<dim3(118, 4, 4), blk, 0, stream>>>(
        Q2, K1, V1t, A2, nullptr, nullptr, 7500, 500, 512, 118);
    attn_mfma_kernel<KSPL><<<dim3(8, 4, 4 * KSPL), blk, 0, stream>>>(
        K1, Q2, V2t, nullptr, PartO, Pml, 500, 7500, 7552, 8);
    attn_combine_kernel<<<dim3(8, 4, 4), blk, 0, stream>>>(PartO, Pml, A1, 500, 8);

    // o-projections (role-swapped; fused [c][l] transpose in epilogue)
    gemm_nt<2,0><<<dim3(4, 4, 4),  blk, 0, stream>>>(Wo1b, 0, A1, (size_t)500*512,  bo1, out, (size_t)5*51200,  0, 512, 500);
    gemm_nt<2,0><<<dim3(4, 59, 4), blk, 0, stream>>>(Wo2b, 0, A2, (size_t)7500*512, bo2, out + (size_t)1024000, (size_t)75*51200, 0, 512, 7500);
}

// Round 4
// 397.965 us; speedup vs baseline: 7.2215x; 1.2252x over previous
//
#include <hip/hip_runtime.h>
#include <hip/hip_bf16.h>

// MultiHeadCrossAttention: B=4, C=512, HEADS=4, HD=128, L=100
// f1 -> 500 support tokens/batch, f2 -> 7500 query tokens/batch.
// out1: [4,5,512,100], out2: [4,75,512,100] concatenated in d_out.

#define SCALE_ 0.08838834764831845f   // 128^-0.5

using bf16x8 = __attribute__((ext_vector_type(8))) short;
using f32x4  = __attribute__((ext_vector_type(4))) float;

__device__ inline ushort f2bf(float x) {
    union { float f; unsigned u; } v; v.f = x;
    unsigned r = v.u + 0x7fff + ((v.u >> 16) & 1);   // RNE
    return (ushort)(r >> 16);
}

__device__ inline void gll16(const ushort* g, ushort* l) {
    __builtin_amdgcn_global_load_lds(
        (const __attribute__((address_space(1))) void*)g,
        (__attribute__((address_space(3))) void*)l, 16, 0, 0);
}

// ---------------------------------------------------------------------------
// totok: X slab [512][100] f32 (one (b,n)) -> Y tokens [100][512] bf16.
// ---------------------------------------------------------------------------
__global__ __launch_bounds__(256) void totok_kernel(
    const float* __restrict__ X, ushort* __restrict__ Y)
{
    __shared__ ushort Ts[100 * 136];
    const int t  = threadIdx.x;
    const int bn = blockIdx.x;
    const float* Xb = X + (size_t)bn * 51200;
    ushort* Yb = Y + (size_t)bn * 100 * 512;

    for (int c0 = 0; c0 < 512; c0 += 128) {
        __syncthreads();
        #pragma unroll
        for (int i = 0; i < 50; ++i) {
            const int id = i * 256 + t;
            const int c = id / 100, l = id - c * 100;
            Ts[l * 136 + c] = f2bf(Xb[(size_t)(c0 + c) * 100 + l]);
        }
        __syncthreads();
        #pragma unroll
        for (int i = 0; i < 7; ++i) {
            const int id = i * 256 + t;
            if (id < 1600) {
                const int cg = id & 15, l = id >> 4;
                *(uint4*)(Yb + (size_t)l * 512 + c0 + cg * 8) =
                    *(const uint4*)&Ts[l * 136 + cg * 8];
            }
        }
    }
}

// ---------------------------------------------------------------------------
// weight fp32 -> bf16 (6 x 512x512), grid (256, 6)
// ---------------------------------------------------------------------------
struct WPtrs { const float* p[6]; };
__global__ __launch_bounds__(256) void wconv_kernel(WPtrs wp, ushort* __restrict__ dst)
{
    const int wsel = blockIdx.y;
    const float* src = wp.p[wsel];
    ushort* d = dst + (size_t)wsel * 262144;
    const int idx = (blockIdx.x * 256 + threadIdx.x) * 4;
    const float4 v = *(const float4*)(src + idx);
    ushort4 o;
    o.x = f2bf(v.x); o.y = f2bf(v.y); o.z = f2bf(v.z); o.w = f2bf(v.w);
    *(ushort4*)(d + idx) = o;
}

// ---------------------------------------------------------------------------
// gemm_nt: C[m][n] = sum_k A[m][k]*B[n][k] (+bias), K=512 fixed, lda=ldb=512.
// 128x128 tile, BK=64, 4 waves, global_load_lds staging w/ XOR-preswizzled src.
// EPI 0: bf16 C row-major [Mrows][ldC]. BAXIS 1: bias per col; 0: per row.
// EPI 2: fp32 final out with [c][l] transpose scatter.
// ---------------------------------------------------------------------------
template<int EPI, int BAXIS>
__global__ __launch_bounds__(256) void gemm_nt(
    const ushort* __restrict__ A, size_t sA,
    const ushort* __restrict__ B, size_t sB,
    const float* __restrict__ bias, void* __restrict__ C, size_t sC, int ldC,
    int Mrows, int Ncols)
{
    __shared__ ushort smem[17408];          // 34.8 KB: staging 32KB / epi overlay
    ushort* As = smem;                       // [128][64]
    ushort* Bs = smem + 8192;                // [128][64]

    const int t    = threadIdx.x;
    const int lane = t & 63;
    const int w    = t >> 6;
    const int mw   = (w >> 1) * 64;
    const int nw   = (w & 1) * 64;
    const int m0   = blockIdx.x * 128;
    const int n0   = blockIdx.y * 128;
    const int b    = blockIdx.z;
    const ushort* Ab = A + (size_t)b * sA;
    const ushort* Bb = B + (size_t)b * sB;

    f32x4 acc[4][4];
    #pragma unroll
    for (int i = 0; i < 4; ++i)
        #pragma unroll
        for (int j = 0; j < 4; ++j) acc[i][j] = (f32x4){0.f, 0.f, 0.f, 0.f};

    const int lr = lane >> 3;      // 0..7 row within 8-row group
    const int cb = lane & 7;       // 16B granule within row

    for (int k0 = 0; k0 < 512; k0 += 64) {
        if (k0) __syncthreads();
        #pragma unroll
        for (int i = 0; i < 4; ++i) {
            const int row = w * 32 + i * 8 + lr;
            const int ar = min(m0 + row, Mrows - 1);
            gll16(Ab + (size_t)ar * 512 + k0 + ((cb ^ (row & 7)) * 8),
                  As + (w * 32 + i * 8) * 64);
            const int br = min(n0 + row, Ncols - 1);
            gll16(Bb + (size_t)br * 512 + k0 + ((cb ^ (row & 7)) * 8),
                  Bs + (w * 32 + i * 8) * 64);
        }
        __syncthreads();
        #pragma unroll
        for (int ks = 0; ks < 2; ++ks) {
            bf16x8 af[4], bv[4];
            #pragma unroll
            for (int mf = 0; mf < 4; ++mf) {
                const int row = mw + mf * 16 + (lane & 15);
                af[mf] = *(const bf16x8*)((const char*)As + row * 128 +
                          ((ks * 64 + (lane >> 4) * 16) ^ ((row & 7) << 4)));
            }
            #pragma unroll
            for (int nf = 0; nf < 4; ++nf) {
                const int row = nw + nf * 16 + (lane & 15);
                bv[nf] = *(const bf16x8*)((const char*)Bs + row * 128 +
                          ((ks * 64 + (lane >> 4) * 16) ^ ((row & 7) << 4)));
            }
            #pragma unroll
            for (int mf = 0; mf < 4; ++mf)
                #pragma unroll
                for (int nf = 0; nf < 4; ++nf)
                    acc[mf][nf] = __builtin_amdgcn_mfma_f32_16x16x32_bf16(
                        af[mf], bv[nf], acc[mf][nf], 0, 0, 0);
        }
    }
    __syncthreads();

    if (EPI == 0) {
        float bcol[4];
        if (BAXIS == 1) {
            #pragma unroll
            for (int nf = 0; nf < 4; ++nf)
                bcol[nf] = bias[n0 + nw + nf * 16 + (lane & 15)];
        }
        ushort* Ts = smem;   // [128][136]
        #pragma unroll
        for (int mf = 0; mf < 4; ++mf) {
            #pragma unroll
            for (int r = 0; r < 4; ++r) {
                const int row = mw + mf * 16 + (lane >> 4) * 4 + r;
                const float brow = (BAXIS == 0) ? bias[m0 + row] : 0.f;
                #pragma unroll
                for (int nf = 0; nf < 4; ++nf) {
                    const int col = nw + nf * 16 + (lane & 15);
                    const float v = acc[mf][nf][r] +
                                    ((BAXIS == 1) ? bcol[nf] : brow);
                    Ts[row * 136 + col] = f2bf(v);
                }
            }
        }
        __syncthreads();
        ushort* Cb = (ushort*)C + (size_t)b * sC;
        #pragma unroll
        for (int i = 0; i < 8; ++i) {
            const int id = i * 256 + t;
            const int row = id >> 4, cg = id & 15;
            if (m0 + row < Mrows)
                *(uint4*)(Cb + (size_t)(m0 + row) * ldC + n0 + cg * 8) =
                    *(const uint4*)&Ts[row * 136 + cg * 8];
        }
    } else {
        // EPI 2: fp32 final out with [c][l] scatter
        float* Ts2 = (float*)smem;   // [64][132]
        float* Cb = (float*)C + (size_t)b * sC;
        const int colL = t & 127;
        const int rb2 = t >> 7;
        const int tg = n0 + colL;
        int nIdx = 0, lIdx = 0;
        if (tg < Ncols) { nIdx = tg / 100; lIdx = tg - nIdx * 100; }
        #pragma unroll
        for (int h = 0; h < 2; ++h) {
            __syncthreads();
            if ((mw >> 6) == h) {
                #pragma unroll
                for (int mf = 0; mf < 4; ++mf) {
                    #pragma unroll
                    for (int r = 0; r < 4; ++r) {
                        const int rowl = mf * 16 + (lane >> 4) * 4 + r;
                        const float brow = bias[m0 + h * 64 + rowl];
                        #pragma unroll
                        for (int nf = 0; nf < 4; ++nf) {
                            const int col = nw + nf * 16 + (lane & 15);
                            Ts2[rowl * 132 + col] = acc[mf][nf][r] + brow;
                        }
                    }
                }
            }
            __syncthreads();
            if (tg < Ncols) {
                float* dst = Cb + (size_t)nIdx * 51200 + lIdx;
                #pragma unroll
                for (int i = 0; i < 32; ++i) {
                    const int rowl = i * 2 + rb2;
                    const int c = m0 + h * 64 + rowl;
                    dst[(size_t)c * 100] = Ts2[rowl * 132 + colL];
                }
            }
        }
    }
}

// ---------------------------------------------------------------------------
// MFMA flash attention. 64 rows x head x (b,split), 4 waves, BK=64.
// Q fragments direct from global (no LDS). K/V staged via global_load_lds
// with source-side XOR preswizzle (linear LDS dest). LDS 40KB -> 4 blocks/CU.
// Out-of-range K/V reads land in adjacent allocated ws (finite) and are
// nullified by the logit mask (exp -> 0).
// ---------------------------------------------------------------------------
template<int KSPLIT>
__global__ __launch_bounds__(256, 4) void attn_mfma_kernel(
    const ushort* __restrict__ R, const ushort* __restrict__ Kt,
    const ushort* __restrict__ Vt, ushort* __restrict__ Aout,
    float* __restrict__ PartO, float* __restrict__ Pml,
    int TR, int TK, int strideV, int nrb)
{
    __shared__ ushort Ks[64 * 128];   // 16 KB, rows 256B, XOR-swizzled
    __shared__ ushort Vs[128 * 64];   // 16 KB, d-rows 128B, XOR-swizzled
    __shared__ ushort Ps[64 * 64];    //  8 KB

    const int t    = threadIdx.x;
    const int lane = t & 63;
    const int w    = t >> 6;
    const int rb   = blockIdx.x;
    const int h    = blockIdx.y;
    const int b    = blockIdx.z / KSPLIT;
    const int sp   = blockIdx.z % KSPLIT;
    const int r0   = rb * 64;
    const int ho   = h * 128;

    const int klen = (TK + KSPLIT - 1) / KSPLIT;
    const int kbeg = sp * klen;
    int kend = kbeg + klen; if (kend > TK) kend = TK;

    // ---- Q fragments direct from global (row-clamped at tail) ----
    bf16x8 qa[4];
    {
        const ushort* Rb = R + (size_t)b * TR * 512;
        const int qrow = min(r0 + (w << 4) + (lane & 15), TR - 1);
        const ushort* qp = Rb + (size_t)qrow * 512 + ho + (lane >> 4) * 8;
        #pragma unroll
        for (int s = 0; s < 4; ++s)
            qa[s] = *(const bf16x8*)(qp + s * 32);
    }

    const ushort* Kb = Kt + (size_t)b * TK * 512;
    const ushort* Vb = Vt + ((size_t)b * 512 + ho) * strideV;

    // per-lane staging offsets (ushort units; XOR preswizzle on source)
    const int krow_i = lane >> 4;            // row within 4-row K granule
    const int kcol   = (lane & 15) * 8;      // 16B col within 256B row
    const int vrow_i = lane >> 3;            // row within 8-row V granule
    const int vcol   = (lane & 7) * 8;       // 16B col within 128B row

    float m_run[4], l_run[4];
    #pragma unroll
    for (int r = 0; r < 4; ++r) { m_run[r] = -3.0e38f; l_run[r] = 0.f; }
    f32x4 acc[8];
    #pragma unroll
    for (int g = 0; g < 8; ++g) acc[g] = (f32x4){0.f, 0.f, 0.f, 0.f};

    for (int kbase = kbeg; kbase < kend; kbase += 64) {
        __syncthreads();   // prior chunk's Ks/Vs reads complete
        // ---- stage K (64x128) and V^T (128x64) via global_load_lds ----
        #pragma unroll
        for (int i = 0; i < 4; ++i) {
            const int kr = w * 16 + i * 4 + krow_i;
            gll16(Kb + (size_t)(kbase + kr) * 512 + ho + (kcol ^ ((kr & 7) << 3)),
                  Ks + (w * 16 + i * 4) * 128);
            const int vd = w * 32 + i * 8 + vrow_i;
            gll16(Vb + (size_t)vd * strideV + kbase + (vcol ^ ((vd & 7) << 3)),
                  Vs + (w * 32 + i * 8) * 64);
        }
        __syncthreads();   // vmcnt drained by compiler before barrier

        // ---- QK^T: wave w owns rows [16w,16w+16), 4 col-frags x 4 k-steps ----
        f32x4 sf[4];
        #pragma unroll
        for (int f = 0; f < 4; ++f) {
            f32x4 s = (f32x4){0.f, 0.f, 0.f, 0.f};
            const int kr = f * 16 + (lane & 15);
            const int kb2 = kr * 256, sw = (kr & 7) << 4, g16 = (lane >> 4) * 16;
            #pragma unroll
            for (int s4 = 0; s4 < 4; ++s4) {
                bf16x8 kf = *(const bf16x8*)((const char*)Ks + kb2 + ((s4 * 64 + g16) ^ sw));
                s = __builtin_amdgcn_mfma_f32_16x16x32_bf16(qa[s4], kf, s, 0, 0, 0);
            }
            sf[f] = s;
        }
        // ---- scale + key mask ----
        #pragma unroll
        for (int f = 0; f < 4; ++f) {
            const bool ok = (kbase + f * 16 + (lane & 15)) < kend;
            #pragma unroll
            for (int r = 0; r < 4; ++r)
                sf[f][r] = ok ? sf[f][r] * SCALE_ : -3.0e38f;
        }
        // ---- online softmax (16-lane butterflies; lane owns 4 rows) ----
        float scal[4];
        #pragma unroll
        for (int r = 0; r < 4; ++r) {
            float mx = fmaxf(fmaxf(sf[0][r], sf[1][r]), fmaxf(sf[2][r], sf[3][r]));
            #pragma unroll
            for (int off = 1; off < 16; off <<= 1)
                mx = fmaxf(mx, __shfl_xor(mx, off));
            const float mn = fmaxf(m_run[r], mx);
            scal[r] = __expf(m_run[r] - mn);
            m_run[r] = mn;
        }
        float rsum[4] = {0.f, 0.f, 0.f, 0.f};
        {
            const int rbase = (w << 4) + ((lane >> 4) << 2);
            #pragma unroll
            for (int f = 0; f < 4; ++f) {
                const int colb = (f * 16 + (lane & 15)) * 2;
                #pragma unroll
                for (int r = 0; r < 4; ++r) {
                    const float p = __expf(sf[f][r] - m_run[r]);
                    rsum[r] += p;
                    const int row = rbase + r;
                    *(ushort*)((char*)Ps + row * 128 + (colb ^ ((row & 7) << 4))) = f2bf(p);
                }
            }
        }
        #pragma unroll
        for (int r = 0; r < 4; ++r) {
            float s = rsum[r];
            #pragma unroll
            for (int off = 1; off < 16; off <<= 1) s += __shfl_xor(s, off);
            l_run[r] = l_run[r] * scal[r] + s;
        }
        #pragma unroll
        for (int g = 0; g < 8; ++g)
            #pragma unroll
            for (int r = 0; r < 4; ++r) acc[g][r] *= scal[r];

        // ---- PV: O[16 x 128] += P[16 x 64] * V[64 x 128] ----
        {
            const int ar = (w << 4) + (lane & 15);
            const int ab = ar * 128, asw = (ar & 7) << 4, g16 = (lane >> 4) * 16;
            bf16x8 pa0 = *(const bf16x8*)((const char*)Ps + ab + ((g16) ^ asw));
            bf16x8 pa1 = *(const bf16x8*)((const char*)Ps + ab + ((64 + g16) ^ asw));
            #pragma unroll
            for (int g = 0; g < 8; ++g) {
                const int dr = g * 16 + (lane & 15);
                const int vb = dr * 128, vsw = (dr & 7) << 4;
                bf16x8 v0 = *(const bf16x8*)((const char*)Vs + vb + ((g16) ^ vsw));
                bf16x8 v1 = *(const bf16x8*)((const char*)Vs + vb + ((64 + g16) ^ vsw));
                acc[g] = __builtin_amdgcn_mfma_f32_16x16x32_bf16(pa0, v0, acc[g], 0, 0, 0);
                acc[g] = __builtin_amdgcn_mfma_f32_16x16x32_bf16(pa1, v1, acc[g], 0, 0, 0);
            }
        }
    }

    // ---- epilogue ----
    const int rloc = (w << 4) + ((lane >> 4) << 2);
    if (KSPLIT == 1) {
        #pragma unroll
        for (int r = 0; r < 4; ++r) {
            const int row = r0 + rloc + r;
            if (row < TR) {
                const float inv = 1.f / l_run[r];
                ushort* Ab2 = Aout + ((size_t)b * TR + row) * 512 + ho + (lane & 15);
                #pragma unroll
                for (int g = 0; g < 8; ++g) Ab2[g * 16] = f2bf(acc[g][r] * inv);
            }
        }
    } else {
        const size_t tile = (((size_t)b * 4 + h) * nrb + rb) * KSPLIT + sp;
        float* Po = PartO + tile * (64 * 128);
        float* Pm = Pml + tile * 128;
        #pragma unroll
        for (int r = 0; r < 4; ++r) {
            const int row = rloc + r;
            float* pp = Po + row * 128 + (lane & 15);
            #pragma unroll
            for (int g = 0; g < 8; ++g) pp[g * 16] = acc[g][r];
            if ((lane & 15) == 0) { Pm[row] = m_run[r]; Pm[64 + row] = l_run[r]; }
        }
    }
}

// ---------------------------------------------------------------------------
#define KSPL 8
__global__ __launch_bounds__(256) void attn_combine_kernel(
    const float* __restrict__ PartO, const float* __restrict__ Pml,
    ushort* __restrict__ Aout, int TR, int nrb)
{
    const int t = threadIdx.x;
    const int rb = blockIdx.x, h = blockIdx.y, b = blockIdx.z;
    const int row = t >> 2;
    const int dq = (t & 3) * 32;
    const int r0 = rb * 64;
    const size_t tbase = (((size_t)b * 4 + h) * nrb + rb) * KSPL;

    float M = -3.0e38f;
    #pragma unroll
    for (int i = 0; i < KSPL; ++i)
        M = fmaxf(M, Pml[(tbase + i) * 128 + row]);
    float wt[KSPL], L = 0.f;
    #pragma unroll
    for (int i = 0; i < KSPL; ++i) {
        const float wi = __expf(Pml[(tbase + i) * 128 + row] - M);
        wt[i] = wi;
        L += wi * Pml[(tbase + i) * 128 + 64 + row];
    }
    if (r0 + row >= TR) return;
    const float invL = 1.f / L;

    float o[32];
    #pragma unroll
    for (int j = 0; j < 32; ++j) o[j] = 0.f;
    #pragma unroll
    for (int i = 0; i < KSPL; ++i) {
        const float* pp = PartO + (tbase + i) * (64 * 128) + row * 128 + dq;
        #pragma unroll
        for (int j = 0; j < 32; j += 4) {
            const float4 v = *(const float4*)(pp + j);
            o[j] += wt[i] * v.x; o[j+1] += wt[i] * v.y;
            o[j+2] += wt[i] * v.z; o[j+3] += wt[i] * v.w;
        }
    }
    ushort* Ab = Aout + ((size_t)b * TR + r0 + row) * 512 + h * 128 + dq;
    #pragma unroll
    for (int j = 0; j < 32; j += 4) {
        ushort4 v;
        v.x = f2bf(o[j] * invL); v.y = f2bf(o[j+1] * invL);
        v.z = f2bf(o[j+2] * invL); v.w = f2bf(o[j+3] * invL);
        *(ushort4*)(Ab + j) = v;
    }
}

// ---------------------------------------------------------------------------
extern "C" void kernel_launch(void* const* d_in, const int* in_sizes, int n_in,
                              void* d_out, int out_size, void* d_ws, size_t ws_size,
                              hipStream_t stream) {
    const float* f1  = (const float*)d_in[0];
    const float* f2  = (const float*)d_in[1];
    const float* Wk1 = (const float*)d_in[2];
    const float* bk1 = (const float*)d_in[3];
    const float* Wv1 = (const float*)d_in[4];
    const float* bv1 = (const float*)d_in[5];
    const float* Wq2 = (const float*)d_in[6];
    const float* bq2 = (const float*)d_in[7];
    // d_in[8..9] = Wk2/bk2: unused by the reference outputs.
    const float* Wv2 = (const float*)d_in[10];
    const float* bv2 = (const float*)d_in[11];
    const float* Wo1 = (const float*)d_in[12];
    const float* bo1 = (const float*)d_in[13];
    const float* Wo2 = (const float*)d_in[14];
    const float* bo2 = (const float*)d_in[15];
    float* out = (float*)d_out;

    // ---- workspace layout (~169 MB) ----
    ushort* f1t = (ushort*)d_ws;                    // [4* 500][512]
    ushort* f2t = f1t + (size_t)1024000;            // [4*7500][512]
    ushort* Wb  = f2t + (size_t)15360000;           // [6][512][512]
    ushort* K1  = Wb  + (size_t)1572864;            // [4* 500][512]
    ushort* Q2  = K1  + (size_t)1024000;            // [4*7500][512]
    ushort* V1t = Q2  + (size_t)15360000;           // [4][512][512]
    ushort* V2t = V1t + (size_t)1048576;            // [4][512][7552]
    ushort* A1  = V2t + (size_t)15466496;           // [4* 500][512]
    ushort* A2  = A1  + (size_t)1024000;            // [4*7500][512]
    float* PartO = (float*)(A2 + (size_t)15360000); // 1024 x [64][128]
    float* Pml   = PartO + (size_t)1024*64*128;     // 1024 x [128]

    const dim3 blk(256);

    // pre-passes
    WPtrs wp; wp.p[0]=Wk1; wp.p[1]=Wv1; wp.p[2]=Wq2; wp.p[3]=Wv2; wp.p[4]=Wo1; wp.p[5]=Wo2;
    wconv_kernel<<<dim3(256, 6), blk, 0, stream>>>(wp, Wb);
    totok_kernel<<<dim3(20),  blk, 0, stream>>>(f1, f1t);
    totok_kernel<<<dim3(300), blk, 0, stream>>>(f2, f2t);

    const ushort* Wk1b = Wb;
    const ushort* Wv1b = Wb + 262144;
    const ushort* Wq2b = Wb + 2*262144;
    const ushort* Wv2b = Wb + 3*262144;
    const ushort* Wo1b = Wb + 4*262144;
    const ushort* Wo2b = Wb + 5*262144;

    // projections (batch-flattened rows where possible)
    gemm_nt<0,1><<<dim3(16, 4, 1),  blk, 0, stream>>>(f1t, 0, Wk1b, 0, bk1, K1, 0, 512, 2000, 512);
    gemm_nt<0,1><<<dim3(235, 4, 1), blk, 0, stream>>>(f2t, 0, Wq2b, 0, bq2, Q2, 0, 512, 30000, 512);
    // V projections, role-swapped -> d-major output
    gemm_nt<0,0><<<dim3(4, 4, 4),  blk, 0, stream>>>(Wv1b, 0, f1t, (size_t)500*512,  bv1, V1t, (size_t)512*512,  512,  512, 500);
    gemm_nt<0,0><<<dim3(4, 59, 4), blk, 0, stream>>>(Wv2b, 0, f2t, (size_t)7500*512, bv2, V2t, (size_t)512*7552, 7552, 512, 7500);

    // attention
    attn_mfma_kernel<1><<<dim3(118, 4, 4), blk, 0, stream>>>(
        Q2, K1, V1t, A2, nullptr, nullptr, 7500, 500, 512, 118);
    attn_mfma_kernel<KSPL><<<dim3(8, 4, 4 * KSPL), blk, 0, stream>>>(
        K1, Q2, V2t, nullptr, PartO, Pml, 500, 7500, 7552, 8);
    attn_combine_kernel<<<dim3(8, 4, 4), blk, 0, stream>>>(PartO, Pml, A1, 500, 8);

    // o-projections (role-swapped; fused [c][l] transpose in epilogue)
    gemm_nt<2,0><<<dim3(4, 4, 4),  blk, 0, stream>>>(Wo1b, 0, A1, (size_t)500*512,  bo1, out, (size_t)5*51200,  0, 512, 500);
    gemm_nt<2,0><<<dim3(4, 59, 4), blk, 0, stream>>>(Wo2b, 0, A2, (size_t)7500*512, bo2, out + (size_t)1024000, (size_t)75*51200, 0, 512, 7500);
}

// Round 5
// 357.586 us; speedup vs baseline: 8.0370x; 1.1129x over previous
//
#include <hip/hip_runtime.h>
#include <hip/hip_bf16.h>

// MultiHeadCrossAttention: B=4, C=512, HEADS=4, HD=128, L=100
// f1 -> 500 support tokens/batch, f2 -> 7500 query tokens/batch.
// out1: [4,5,512,100], out2: [4,75,512,100] concatenated in d_out.

#define SCALE_ 0.08838834764831845f   // 128^-0.5

using bf16x8 = __attribute__((ext_vector_type(8))) short;
using f32x4  = __attribute__((ext_vector_type(4))) float;

__device__ inline ushort f2bf(float x) {
    union { float f; unsigned u; } v; v.f = x;
    unsigned r = v.u + 0x7fff + ((v.u >> 16) & 1);   // RNE
    return (ushort)(r >> 16);
}

__device__ inline void gll16(const ushort* g, ushort* l) {
    __builtin_amdgcn_global_load_lds(
        (const __attribute__((address_space(1))) void*)g,
        (__attribute__((address_space(3))) void*)l, 16, 0, 0);
}

// ---------------------------------------------------------------------------
// totok: X slab [512][100] f32 (one (b,n)) -> Y tokens [100][512] bf16.
// ---------------------------------------------------------------------------
__global__ __launch_bounds__(256) void totok_kernel(
    const float* __restrict__ X, ushort* __restrict__ Y)
{
    __shared__ ushort Ts[100 * 136];
    const int t  = threadIdx.x;
    const int bn = blockIdx.x;
    const float* Xb = X + (size_t)bn * 51200;
    ushort* Yb = Y + (size_t)bn * 100 * 512;

    for (int c0 = 0; c0 < 512; c0 += 128) {
        __syncthreads();
        #pragma unroll
        for (int i = 0; i < 50; ++i) {
            const int id = i * 256 + t;
            const int c = id / 100, l = id - c * 100;
            Ts[l * 136 + c] = f2bf(Xb[(size_t)(c0 + c) * 100 + l]);
        }
        __syncthreads();
        #pragma unroll
        for (int i = 0; i < 7; ++i) {
            const int id = i * 256 + t;
            if (id < 1600) {
                const int cg = id & 15, l = id >> 4;
                *(uint4*)(Yb + (size_t)l * 512 + c0 + cg * 8) =
                    *(const uint4*)&Ts[l * 136 + cg * 8];
            }
        }
    }
}

// ---------------------------------------------------------------------------
// weight fp32 -> bf16 (6 x 512x512), grid (256, 6)
// ---------------------------------------------------------------------------
struct WPtrs { const float* p[6]; };
__global__ __launch_bounds__(256) void wconv_kernel(WPtrs wp, ushort* __restrict__ dst)
{
    const int wsel = blockIdx.y;
    const float* src = wp.p[wsel];
    ushort* d = dst + (size_t)wsel * 262144;
    const int idx = (blockIdx.x * 256 + threadIdx.x) * 4;
    const float4 v = *(const float4*)(src + idx);
    ushort4 o;
    o.x = f2bf(v.x); o.y = f2bf(v.y); o.z = f2bf(v.z); o.w = f2bf(v.w);
    *(ushort4*)(d + idx) = o;
}

// ---------------------------------------------------------------------------
// gemm_nt: C[m][n] = sum_k A[m][k]*B[n][k] (+bias), K=512 fixed, lda=ldb=512.
// 128x128 tile, BK=64, 4 waves, global_load_lds staging w/ XOR-preswizzled src.
// EPI 0: bf16 C row-major [Mrows][ldC]. BAXIS 1: bias per col; 0: per row.
// EPI 2: fp32 final out with [c][l] transpose scatter.
// ---------------------------------------------------------------------------
template<int EPI, int BAXIS>
__global__ __launch_bounds__(256) void gemm_nt(
    const ushort* __restrict__ A, size_t sA,
    const ushort* __restrict__ B, size_t sB,
    const float* __restrict__ bias, void* __restrict__ C, size_t sC, int ldC,
    int Mrows, int Ncols)
{
    __shared__ ushort smem[17408];          // 34.8 KB: staging 32KB / epi overlay
    ushort* As = smem;                       // [128][64]
    ushort* Bs = smem + 8192;                // [128][64]

    const int t    = threadIdx.x;
    const int lane = t & 63;
    const int w    = t >> 6;
    const int mw   = (w >> 1) * 64;
    const int nw   = (w & 1) * 64;
    const int m0   = blockIdx.x * 128;
    const int n0   = blockIdx.y * 128;
    const int b    = blockIdx.z;
    const ushort* Ab = A + (size_t)b * sA;
    const ushort* Bb = B + (size_t)b * sB;

    f32x4 acc[4][4];
    #pragma unroll
    for (int i = 0; i < 4; ++i)
        #pragma unroll
        for (int j = 0; j < 4; ++j) acc[i][j] = (f32x4){0.f, 0.f, 0.f, 0.f};

    const int lr = lane >> 3;      // 0..7 row within 8-row group
    const int cb = lane & 7;       // 16B granule within row

    for (int k0 = 0; k0 < 512; k0 += 64) {
        if (k0) __syncthreads();
        #pragma unroll
        for (int i = 0; i < 4; ++i) {
            const int row = w * 32 + i * 8 + lr;
            const int ar = min(m0 + row, Mrows - 1);
            gll16(Ab + (size_t)ar * 512 + k0 + ((cb ^ (row & 7)) * 8),
                  As + (w * 32 + i * 8) * 64);
            const int br = min(n0 + row, Ncols - 1);
            gll16(Bb + (size_t)br * 512 + k0 + ((cb ^ (row & 7)) * 8),
                  Bs + (w * 32 + i * 8) * 64);
        }
        __syncthreads();
        #pragma unroll
        for (int ks = 0; ks < 2; ++ks) {
            bf16x8 af[4], bv[4];
            #pragma unroll
            for (int mf = 0; mf < 4; ++mf) {
                const int row = mw + mf * 16 + (lane & 15);
                af[mf] = *(const bf16x8*)((const char*)As + row * 128 +
                          ((ks * 64 + (lane >> 4) * 16) ^ ((row & 7) << 4)));
            }
            #pragma unroll
            for (int nf = 0; nf < 4; ++nf) {
                const int row = nw + nf * 16 + (lane & 15);
                bv[nf] = *(const bf16x8*)((const char*)Bs + row * 128 +
                          ((ks * 64 + (lane >> 4) * 16) ^ ((row & 7) << 4)));
            }
            #pragma unroll
            for (int mf = 0; mf < 4; ++mf)
                #pragma unroll
                for (int nf = 0; nf < 4; ++nf)
                    acc[mf][nf] = __builtin_amdgcn_mfma_f32_16x16x32_bf16(
                        af[mf], bv[nf], acc[mf][nf], 0, 0, 0);
        }
    }
    __syncthreads();

    if (EPI == 0) {
        float bcol[4];
        if (BAXIS == 1) {
            #pragma unroll
            for (int nf = 0; nf < 4; ++nf)
                bcol[nf] = bias[n0 + nw + nf * 16 + (lane & 15)];
        }
        ushort* Ts = smem;   // [128][136]
        #pragma unroll
        for (int mf = 0; mf < 4; ++mf) {
            #pragma unroll
            for (int r = 0; r < 4; ++r) {
                const int row = mw + mf * 16 + (lane >> 4) * 4 + r;
                const float brow = (BAXIS == 0) ? bias[m0 + row] : 0.f;
                #pragma unroll
                for (int nf = 0; nf < 4; ++nf) {
                    const int col = nw + nf * 16 + (lane & 15);
                    const float v = acc[mf][nf][r] +
                                    ((BAXIS == 1) ? bcol[nf] : brow);
                    Ts[row * 136 + col] = f2bf(v);
                }
            }
        }
        __syncthreads();
        ushort* Cb = (ushort*)C + (size_t)b * sC;
        #pragma unroll
        for (int i = 0; i < 8; ++i) {
            const int id = i * 256 + t;
            const int row = id >> 4, cg = id & 15;
            if (m0 + row < Mrows)
                *(uint4*)(Cb + (size_t)(m0 + row) * ldC + n0 + cg * 8) =
                    *(const uint4*)&Ts[row * 136 + cg * 8];
        }
    } else {
        // EPI 2: fp32 final out with [c][l] scatter
        float* Ts2 = (float*)smem;   // [64][132]
        float* Cb = (float*)C + (size_t)b * sC;
        const int colL = t & 127;
        const int rb2 = t >> 7;
        const int tg = n0 + colL;
        int nIdx = 0, lIdx = 0;
        if (tg < Ncols) { nIdx = tg / 100; lIdx = tg - nIdx * 100; }
        #pragma unroll
        for (int h = 0; h < 2; ++h) {
            __syncthreads();
            if ((mw >> 6) == h) {
                #pragma unroll
                for (int mf = 0; mf < 4; ++mf) {
                    #pragma unroll
                    for (int r = 0; r < 4; ++r) {
                        const int rowl = mf * 16 + (lane >> 4) * 4 + r;
                        const float brow = bias[m0 + h * 64 + rowl];
                        #pragma unroll
                        for (int nf = 0; nf < 4; ++nf) {
                            const int col = nw + nf * 16 + (lane & 15);
                            Ts2[rowl * 132 + col] = acc[mf][nf][r] + brow;
                        }
                    }
                }
            }
            __syncthreads();
            if (tg < Ncols) {
                float* dst = Cb + (size_t)nIdx * 51200 + lIdx;
                #pragma unroll
                for (int i = 0; i < 32; ++i) {
                    const int rowl = i * 2 + rb2;
                    const int c = m0 + h * 64 + rowl;
                    dst[(size_t)c * 100] = Ts2[rowl * 132 + colL];
                }
            }
        }
    }
}

// ---------------------------------------------------------------------------
// MFMA flash attention. Flat 1D grid with XCD-bijective swizzle (T1):
// each XCD owns a contiguous chunk of work ids, rb fastest -> all row-blocks
// sharing one (h,b[,sp]) key-slice run on the same XCD back-to-back, so K/V
// staging hits that XCD's L2 instead of re-fetching HBM.
// Q fragments direct from global; K/V staged via global_load_lds with
// source-side XOR preswizzle. LDS 40KB -> 4 blocks/CU.
// ---------------------------------------------------------------------------
template<int KSPLIT>
__global__ __launch_bounds__(256, 4) void attn_mfma_kernel(
    const ushort* __restrict__ R, const ushort* __restrict__ Kt,
    const ushort* __restrict__ Vt, ushort* __restrict__ Aout,
    float* __restrict__ PartO, float* __restrict__ Pml,
    int TR, int TK, int strideV, int nrb)
{
    __shared__ ushort Ks[64 * 128];   // 16 KB, rows 256B, XOR-swizzled
    __shared__ ushort Vs[128 * 64];   // 16 KB, d-rows 128B, XOR-swizzled
    __shared__ ushort Ps[64 * 64];    //  8 KB

    const int t    = threadIdx.x;
    const int lane = t & 63;
    const int w    = t >> 6;

    // ---- XCD-bijective block swizzle (m204 formula; exact for any ntot) ----
    const int flat = blockIdx.x;
    const int ntot = gridDim.x;
    const int qq = ntot >> 3, r8 = ntot & 7;
    const int xcd = flat & 7, ii = flat >> 3;
    const int work = (xcd < r8 ? xcd * (qq + 1)
                               : r8 * (qq + 1) + (xcd - r8) * qq) + ii;
    const int rb = work % nrb;
    int rest = work / nrb;
    int sp = 0;
    if (KSPLIT > 1) { sp = rest % KSPLIT; rest /= KSPLIT; }
    const int h = rest & 3;
    const int b = rest >> 2;

    const int r0 = rb * 64;
    const int ho = h * 128;

    const int klen = (TK + KSPLIT - 1) / KSPLIT;
    const int kbeg = sp * klen;
    int kend = kbeg + klen; if (kend > TK) kend = TK;

    // ---- Q fragments direct from global (row-clamped at tail) ----
    bf16x8 qa[4];
    {
        const ushort* Rb = R + (size_t)b * TR * 512;
        const int qrow = min(r0 + (w << 4) + (lane & 15), TR - 1);
        const ushort* qp = Rb + (size_t)qrow * 512 + ho + (lane >> 4) * 8;
        #pragma unroll
        for (int s = 0; s < 4; ++s)
            qa[s] = *(const bf16x8*)(qp + s * 32);
    }

    const ushort* Kb = Kt + (size_t)b * TK * 512;
    const ushort* Vb = Vt + ((size_t)b * 512 + ho) * strideV;

    // per-lane staging offsets (ushort units; XOR preswizzle on source)
    const int krow_i = lane >> 4;            // row within 4-row K granule
    const int kcol   = (lane & 15) * 8;      // 16B col within 256B row
    const int vrow_i = lane >> 3;            // row within 8-row V granule
    const int vcol   = (lane & 7) * 8;       // 16B col within 128B row

    float m_run[4], l_run[4];
    #pragma unroll
    for (int r = 0; r < 4; ++r) { m_run[r] = -3.0e38f; l_run[r] = 0.f; }
    f32x4 acc[8];
    #pragma unroll
    for (int g = 0; g < 8; ++g) acc[g] = (f32x4){0.f, 0.f, 0.f, 0.f};

    for (int kbase = kbeg; kbase < kend; kbase += 64) {
        __syncthreads();   // prior chunk's Ks/Vs reads complete
        // ---- stage K (64x128) and V^T (128x64) via global_load_lds ----
        #pragma unroll
        for (int i = 0; i < 4; ++i) {
            const int kr = w * 16 + i * 4 + krow_i;
            gll16(Kb + (size_t)(kbase + kr) * 512 + ho + (kcol ^ ((kr & 7) << 3)),
                  Ks + (w * 16 + i * 4) * 128);
            const int vd = w * 32 + i * 8 + vrow_i;
            gll16(Vb + (size_t)vd * strideV + kbase + (vcol ^ ((vd & 7) << 3)),
                  Vs + (w * 32 + i * 8) * 64);
        }
        __syncthreads();   // vmcnt drained by compiler before barrier

        // ---- QK^T: wave w owns rows [16w,16w+16), 4 col-frags x 4 k-steps ----
        f32x4 sf[4];
        #pragma unroll
        for (int f = 0; f < 4; ++f) {
            f32x4 s = (f32x4){0.f, 0.f, 0.f, 0.f};
            const int kr = f * 16 + (lane & 15);
            const int kb2 = kr * 256, sw = (kr & 7) << 4, g16 = (lane >> 4) * 16;
            #pragma unroll
            for (int s4 = 0; s4 < 4; ++s4) {
                bf16x8 kf = *(const bf16x8*)((const char*)Ks + kb2 + ((s4 * 64 + g16) ^ sw));
                s = __builtin_amdgcn_mfma_f32_16x16x32_bf16(qa[s4], kf, s, 0, 0, 0);
            }
            sf[f] = s;
        }
        // ---- scale + key mask ----
        #pragma unroll
        for (int f = 0; f < 4; ++f) {
            const bool ok = (kbase + f * 16 + (lane & 15)) < kend;
            #pragma unroll
            for (int r = 0; r < 4; ++r)
                sf[f][r] = ok ? sf[f][r] * SCALE_ : -3.0e38f;
        }
        // ---- online softmax (16-lane butterflies; lane owns 4 rows) ----
        float scal[4];
        #pragma unroll
        for (int r = 0; r < 4; ++r) {
            float mx = fmaxf(fmaxf(sf[0][r], sf[1][r]), fmaxf(sf[2][r], sf[3][r]));
            #pragma unroll
            for (int off = 1; off < 16; off <<= 1)
                mx = fmaxf(mx, __shfl_xor(mx, off));
            const float mn = fmaxf(m_run[r], mx);
            scal[r] = __expf(m_run[r] - mn);
            m_run[r] = mn;
        }
        float rsum[4] = {0.f, 0.f, 0.f, 0.f};
        {
            const int rbase = (w << 4) + ((lane >> 4) << 2);
            #pragma unroll
            for (int f = 0; f < 4; ++f) {
                const int colb = (f * 16 + (lane & 15)) * 2;
                #pragma unroll
                for (int r = 0; r < 4; ++r) {
                    const float p = __expf(sf[f][r] - m_run[r]);
                    rsum[r] += p;
                    const int row = rbase + r;
                    *(ushort*)((char*)Ps + row * 128 + (colb ^ ((row & 7) << 4))) = f2bf(p);
                }
            }
        }
        #pragma unroll
        for (int r = 0; r < 4; ++r) {
            float s = rsum[r];
            #pragma unroll
            for (int off = 1; off < 16; off <<= 1) s += __shfl_xor(s, off);
            l_run[r] = l_run[r] * scal[r] + s;
        }
        #pragma unroll
        for (int g = 0; g < 8; ++g)
            #pragma unroll
            for (int r = 0; r < 4; ++r) acc[g][r] *= scal[r];

        // ---- PV: O[16 x 128] += P[16 x 64] * V[64 x 128] ----
        {
            const int ar = (w << 4) + (lane & 15);
            const int ab = ar * 128, asw = (ar & 7) << 4, g16 = (lane >> 4) * 16;
            bf16x8 pa0 = *(const bf16x8*)((const char*)Ps + ab + ((g16) ^ asw));
            bf16x8 pa1 = *(const bf16x8*)((const char*)Ps + ab + ((64 + g16) ^ asw));
            #pragma unroll
            for (int g = 0; g < 8; ++g) {
                const int dr = g * 16 + (lane & 15);
                const int vb = dr * 128, vsw = (dr & 7) << 4;
                bf16x8 v0 = *(const bf16x8*)((const char*)Vs + vb + ((g16) ^ vsw));
                bf16x8 v1 = *(const bf16x8*)((const char*)Vs + vb + ((64 + g16) ^ vsw));
                acc[g] = __builtin_amdgcn_mfma_f32_16x16x32_bf16(pa0, v0, acc[g], 0, 0, 0);
                acc[g] = __builtin_amdgcn_mfma_f32_16x16x32_bf16(pa1, v1, acc[g], 0, 0, 0);
            }
        }
    }

    // ---- epilogue ----
    const int rloc = (w << 4) + ((lane >> 4) << 2);
    if (KSPLIT == 1) {
        #pragma unroll
        for (int r = 0; r < 4; ++r) {
            const int row = r0 + rloc + r;
            if (row < TR) {
                const float inv = 1.f / l_run[r];
                ushort* Ab2 = Aout + ((size_t)b * TR + row) * 512 + ho + (lane & 15);
                #pragma unroll
                for (int g = 0; g < 8; ++g) Ab2[g * 16] = f2bf(acc[g][r] * inv);
            }
        }
    } else {
        const size_t tile = (((size_t)b * 4 + h) * nrb + rb) * KSPLIT + sp;
        float* Po = PartO + tile * (64 * 128);
        float* Pm = Pml + tile * 128;
        #pragma unroll
        for (int r = 0; r < 4; ++r) {
            const int row = rloc + r;
            float* pp = Po + row * 128 + (lane & 15);
            #pragma unroll
            for (int g = 0; g < 8; ++g) pp[g * 16] = acc[g][r];
            if ((lane & 15) == 0) { Pm[row] = m_run[r]; Pm[64 + row] = l_run[r]; }
        }
    }
}

// ---------------------------------------------------------------------------
#define KSPL 8
__global__ __launch_bounds__(256) void attn_combine_kernel(
    const float* __restrict__ PartO, const float* __restrict__ Pml,
    ushort* __restrict__ Aout, int TR, int nrb)
{
    const int t = threadIdx.x;
    const int rb = blockIdx.x, h = blockIdx.y, b = blockIdx.z;
    const int row = t >> 2;
    const int dq = (t & 3) * 32;
    const int r0 = rb * 64;
    const size_t tbase = (((size_t)b * 4 + h) * nrb + rb) * KSPL;

    float M = -3.0e38f;
    #pragma unroll
    for (int i = 0; i < KSPL; ++i)
        M = fmaxf(M, Pml[(tbase + i) * 128 + row]);
    float wt[KSPL], L = 0.f;
    #pragma unroll
    for (int i = 0; i < KSPL; ++i) {
        const float wi = __expf(Pml[(tbase + i) * 128 + row] - M);
        wt[i] = wi;
        L += wi * Pml[(tbase + i) * 128 + 64 + row];
    }
    if (r0 + row >= TR) return;
    const float invL = 1.f / L;

    float o[32];
    #pragma unroll
    for (int j = 0; j < 32; ++j) o[j] = 0.f;
    #pragma unroll
    for (int i = 0; i < KSPL; ++i) {
        const float* pp = PartO + (tbase + i) * (64 * 128) + row * 128 + dq;
        #pragma unroll
        for (int j = 0; j < 32; j += 4) {
            const float4 v = *(const float4*)(pp + j);
            o[j] += wt[i] * v.x; o[j+1] += wt[i] * v.y;
            o[j+2] += wt[i] * v.z; o[j+3] += wt[i] * v.w;
        }
    }
    ushort* Ab = Aout + ((size_t)b * TR + r0 + row) * 512 + h * 128 + dq;
    #pragma unroll
    for (int j = 0; j < 32; j += 4) {
        ushort4 v;
        v.x = f2bf(o[j] * invL); v.y = f2bf(o[j+1] * invL);
        v.z = f2bf(o[j+2] * invL); v.w = f2bf(o[j+3] * invL);
        *(ushort4*)(Ab + j) = v;
    }
}

// ---------------------------------------------------------------------------
extern "C" void kernel_launch(void* const* d_in, const int* in_sizes, int n_in,
                              void* d_out, int out_size, void* d_ws, size_t ws_size,
                              hipStream_t stream) {
    const float* f1  = (const float*)d_in[0];
    const float* f2  = (const float*)d_in[1];
    const float* Wk1 = (const float*)d_in[2];
    const float* bk1 = (const float*)d_in[3];
    const float* Wv1 = (const float*)d_in[4];
    const float* bv1 = (const float*)d_in[5];
    const float* Wq2 = (const float*)d_in[6];
    const float* bq2 = (const float*)d_in[7];
    // d_in[8..9] = Wk2/bk2: unused by the reference outputs.
    const float* Wv2 = (const float*)d_in[10];
    const float* bv2 = (const float*)d_in[11];
    const float* Wo1 = (const float*)d_in[12];
    const float* bo1 = (const float*)d_in[13];
    const float* Wo2 = (const float*)d_in[14];
    const float* bo2 = (const float*)d_in[15];
    float* out = (float*)d_out;

    // ---- workspace layout (~169 MB) ----
    ushort* f1t = (ushort*)d_ws;                    // [4* 500][512]
    ushort* f2t = f1t + (size_t)1024000;            // [4*7500][512]
    ushort* Wb  = f2t + (size_t)15360000;           // [6][512][512]
    ushort* K1  = Wb  + (size_t)1572864;            // [4* 500][512]
    ushort* Q2  = K1  + (size_t)1024000;            // [4*7500][512]
    ushort* V1t = Q2  + (size_t)15360000;           // [4][512][512]
    ushort* V2t = V1t + (size_t)1048576;            // [4][512][7552]
    ushort* A1  = V2t + (size_t)15466496;           // [4* 500][512]
    ushort* A2  = A1  + (size_t)1024000;            // [4*7500][512]
    float* PartO = (float*)(A2 + (size_t)15360000); // 1024 x [64][128]
    float* Pml   = PartO + (size_t)1024*64*128;     // 1024 x [128]

    const dim3 blk(256);

    // pre-passes
    WPtrs wp; wp.p[0]=Wk1; wp.p[1]=Wv1; wp.p[2]=Wq2; wp.p[3]=Wv2; wp.p[4]=Wo1; wp.p[5]=Wo2;
    wconv_kernel<<<dim3(256, 6), blk, 0, stream>>>(wp, Wb);
    totok_kernel<<<dim3(20),  blk, 0, stream>>>(f1, f1t);
    totok_kernel<<<dim3(300), blk, 0, stream>>>(f2, f2t);

    const ushort* Wk1b = Wb;
    const ushort* Wv1b = Wb + 262144;
    const ushort* Wq2b = Wb + 2*262144;
    const ushort* Wv2b = Wb + 3*262144;
    const ushort* Wo1b = Wb + 4*262144;
    const ushort* Wo2b = Wb + 5*262144;

    // projections (batch-flattened rows where possible)
    gemm_nt<0,1><<<dim3(16, 4, 1),  blk, 0, stream>>>(f1t, 0, Wk1b, 0, bk1, K1, 0, 512, 2000, 512);
    gemm_nt<0,1><<<dim3(235, 4, 1), blk, 0, stream>>>(f2t, 0, Wq2b, 0, bq2, Q2, 0, 512, 30000, 512);
    // V projections, role-swapped -> d-major output
    gemm_nt<0,0><<<dim3(4, 4, 4),  blk, 0, stream>>>(Wv1b, 0, f1t, (size_t)500*512,  bv1, V1t, (size_t)512*512,  512,  512, 500);
    gemm_nt<0,0><<<dim3(4, 59, 4), blk, 0, stream>>>(Wv2b, 0, f2t, (size_t)7500*512, bv2, V2t, (size_t)512*7552, 7552, 512, 7500);

    // attention (flat 1D grids; XCD swizzle inside kernel)
    attn_mfma_kernel<1><<<dim3(118 * 4 * 4), blk, 0, stream>>>(
        Q2, K1, V1t, A2, nullptr, nullptr, 7500, 500, 512, 118);
    attn_mfma_kernel<KSPL><<<dim3(8 * 4 * 4 * KSPL), blk, 0, stream>>>(
        K1, Q2, V2t, nullptr, PartO, Pml, 500, 7500, 7552, 8);
    attn_combine_kernel<<<dim3(8, 4, 4), blk, 0, stream>>>(PartO, Pml, A1, 500, 8);

    // o-projections (role-swapped; fused [c][l] transpose in epilogue)
    gemm_nt<2,0><<<dim3(4, 4, 4),  blk, 0, stream>>>(Wo1b, 0, A1, (size_t)500*512,  bo1, out, (size_t)5*51200,  0, 512, 500);
    gemm_nt<2,0><<<dim3(4, 59, 4), blk, 0, stream>>>(Wo2b, 0, A2, (size_t)7500*512, bo2, out + (size_t)1024000, (size_t)75*51200, 0, 512, 7500);
}

// Round 6
// 317.948 us; speedup vs baseline: 9.0390x; 1.1247x over previous
//
#include <hip/hip_runtime.h>
#include <hip/hip_bf16.h>

// MultiHeadCrossAttention: B=4, C=512, HEADS=4, HD=128, L=100
// f1 -> 500 support tokens/batch, f2 -> 7500 query tokens/batch.
// out1: [4,5,512,100], out2: [4,75,512,100] concatenated in d_out.

#define SCALE_ 0.08838834764831845f              // 128^-0.5
#define QSCL  (0.08838834764831845f * 1.4426950408889634f)   // SCALE * log2(e)

using bf16x8 = __attribute__((ext_vector_type(8))) short;
using f32x4  = __attribute__((ext_vector_type(4))) float;

__device__ inline ushort f2bf(float x) {
    union { float f; unsigned u; } v; v.f = x;
    unsigned r = v.u + 0x7fff + ((v.u >> 16) & 1);   // RNE
    return (ushort)(r >> 16);
}

__device__ inline void gll16(const ushort* g, ushort* l) {
    __builtin_amdgcn_global_load_lds(
        (const __attribute__((address_space(1))) void*)g,
        (__attribute__((address_space(3))) void*)l, 16, 0, 0);
}

// ---------------------------------------------------------------------------
// totok: X slab [512][100] f32 (one (b,n)) -> Y tokens [100][512] bf16.
// ---------------------------------------------------------------------------
__global__ __launch_bounds__(256) void totok_kernel(
    const float* __restrict__ X, ushort* __restrict__ Y)
{
    __shared__ ushort Ts[100 * 136];
    const int t  = threadIdx.x;
    const int bn = blockIdx.x;
    const float* Xb = X + (size_t)bn * 51200;
    ushort* Yb = Y + (size_t)bn * 100 * 512;

    for (int c0 = 0; c0 < 512; c0 += 128) {
        __syncthreads();
        #pragma unroll
        for (int i = 0; i < 50; ++i) {
            const int id = i * 256 + t;
            const int c = id / 100, l = id - c * 100;
            Ts[l * 136 + c] = f2bf(Xb[(size_t)(c0 + c) * 100 + l]);
        }
        __syncthreads();
        #pragma unroll
        for (int i = 0; i < 7; ++i) {
            const int id = i * 256 + t;
            if (id < 1600) {
                const int cg = id & 15, l = id >> 4;
                *(uint4*)(Yb + (size_t)l * 512 + c0 + cg * 8) =
                    *(const uint4*)&Ts[l * 136 + cg * 8];
            }
        }
    }
}

// ---------------------------------------------------------------------------
// weight fp32 -> bf16 (6 x 512x512) with per-weight scale, grid (256, 6)
// ---------------------------------------------------------------------------
struct WPtrs { const float* p[6]; float s[6]; };
__global__ __launch_bounds__(256) void wconv_kernel(WPtrs wp, ushort* __restrict__ dst)
{
    const int wsel = blockIdx.y;
    const float* src = wp.p[wsel];
    const float sc = wp.s[wsel];
    ushort* d = dst + (size_t)wsel * 262144;
    const int idx = (blockIdx.x * 256 + threadIdx.x) * 4;
    const float4 v = *(const float4*)(src + idx);
    ushort4 o;
    o.x = f2bf(v.x * sc); o.y = f2bf(v.y * sc);
    o.z = f2bf(v.z * sc); o.w = f2bf(v.w * sc);
    *(ushort4*)(d + idx) = o;
}

// ---------------------------------------------------------------------------
// gemm_nt: C[m][n] = sum_k A[m][k]*B[n][k] (+bias*bscale), K=512, lda=ldb=512.
// 128x128 tile, BK=64, 4 waves, global_load_lds staging w/ XOR-preswizzled src.
// EPI 0: bf16 C row-major [Mrows][ldC]. BAXIS 1: bias per col; 0: per row.
// EPI 2: fp32 final out with [c][l] transpose scatter.
// ---------------------------------------------------------------------------
template<int EPI, int BAXIS>
__global__ __launch_bounds__(256) void gemm_nt(
    const ushort* __restrict__ A, size_t sA,
    const ushort* __restrict__ B, size_t sB,
    const float* __restrict__ bias, float bscale,
    void* __restrict__ C, size_t sC, int ldC,
    int Mrows, int Ncols)
{
    __shared__ ushort smem[17408];          // 34.8 KB: staging 32KB / epi overlay
    ushort* As = smem;                       // [128][64]
    ushort* Bs = smem + 8192;                // [128][64]

    const int t    = threadIdx.x;
    const int lane = t & 63;
    const int w    = t >> 6;
    const int mw   = (w >> 1) * 64;
    const int nw   = (w & 1) * 64;
    const int m0   = blockIdx.x * 128;
    const int n0   = blockIdx.y * 128;
    const int b    = blockIdx.z;
    const ushort* Ab = A + (size_t)b * sA;
    const ushort* Bb = B + (size_t)b * sB;

    f32x4 acc[4][4];
    #pragma unroll
    for (int i = 0; i < 4; ++i)
        #pragma unroll
        for (int j = 0; j < 4; ++j) acc[i][j] = (f32x4){0.f, 0.f, 0.f, 0.f};

    const int lr = lane >> 3;      // 0..7 row within 8-row group
    const int cb = lane & 7;       // 16B granule within row

    for (int k0 = 0; k0 < 512; k0 += 64) {
        if (k0) __syncthreads();
        #pragma unroll
        for (int i = 0; i < 4; ++i) {
            const int row = w * 32 + i * 8 + lr;
            const int ar = min(m0 + row, Mrows - 1);
            gll16(Ab + (size_t)ar * 512 + k0 + ((cb ^ (row & 7)) * 8),
                  As + (w * 32 + i * 8) * 64);
            const int br = min(n0 + row, Ncols - 1);
            gll16(Bb + (size_t)br * 512 + k0 + ((cb ^ (row & 7)) * 8),
                  Bs + (w * 32 + i * 8) * 64);
        }
        __syncthreads();
        #pragma unroll
        for (int ks = 0; ks < 2; ++ks) {
            bf16x8 af[4], bv[4];
            #pragma unroll
            for (int mf = 0; mf < 4; ++mf) {
                const int row = mw + mf * 16 + (lane & 15);
                af[mf] = *(const bf16x8*)((const char*)As + row * 128 +
                          ((ks * 64 + (lane >> 4) * 16) ^ ((row & 7) << 4)));
            }
            #pragma unroll
            for (int nf = 0; nf < 4; ++nf) {
                const int row = nw + nf * 16 + (lane & 15);
                bv[nf] = *(const bf16x8*)((const char*)Bs + row * 128 +
                          ((ks * 64 + (lane >> 4) * 16) ^ ((row & 7) << 4)));
            }
            #pragma unroll
            for (int mf = 0; mf < 4; ++mf)
                #pragma unroll
                for (int nf = 0; nf < 4; ++nf)
                    acc[mf][nf] = __builtin_amdgcn_mfma_f32_16x16x32_bf16(
                        af[mf], bv[nf], acc[mf][nf], 0, 0, 0);
        }
    }
    __syncthreads();

    if (EPI == 0) {
        float bcol[4];
        if (BAXIS == 1) {
            #pragma unroll
            for (int nf = 0; nf < 4; ++nf)
                bcol[nf] = bias[n0 + nw + nf * 16 + (lane & 15)] * bscale;
        }
        ushort* Ts = smem;   // [128][136]
        #pragma unroll
        for (int mf = 0; mf < 4; ++mf) {
            #pragma unroll
            for (int r = 0; r < 4; ++r) {
                const int row = mw + mf * 16 + (lane >> 4) * 4 + r;
                const float brow = (BAXIS == 0) ? bias[m0 + row] * bscale : 0.f;
                #pragma unroll
                for (int nf = 0; nf < 4; ++nf) {
                    const int col = nw + nf * 16 + (lane & 15);
                    const float v = acc[mf][nf][r] +
                                    ((BAXIS == 1) ? bcol[nf] : brow);
                    Ts[row * 136 + col] = f2bf(v);
                }
            }
        }
        __syncthreads();
        ushort* Cb = (ushort*)C + (size_t)b * sC;
        #pragma unroll
        for (int i = 0; i < 8; ++i) {
            const int id = i * 256 + t;
            const int row = id >> 4, cg = id & 15;
            if (m0 + row < Mrows)
                *(uint4*)(Cb + (size_t)(m0 + row) * ldC + n0 + cg * 8) =
                    *(const uint4*)&Ts[row * 136 + cg * 8];
        }
    } else {
        // EPI 2: fp32 final out with [c][l] scatter
        float* Ts2 = (float*)smem;   // [64][132]
        float* Cb = (float*)C + (size_t)b * sC;
        const int colL = t & 127;
        const int rb2 = t >> 7;
        const int tg = n0 + colL;
        int nIdx = 0, lIdx = 0;
        if (tg < Ncols) { nIdx = tg / 100; lIdx = tg - nIdx * 100; }
        #pragma unroll
        for (int h = 0; h < 2; ++h) {
            __syncthreads();
            if ((mw >> 6) == h) {
                #pragma unroll
                for (int mf = 0; mf < 4; ++mf) {
                    #pragma unroll
                    for (int r = 0; r < 4; ++r) {
                        const int rowl = mf * 16 + (lane >> 4) * 4 + r;
                        const float brow = bias[m0 + h * 64 + rowl];
                        #pragma unroll
                        for (int nf = 0; nf < 4; ++nf) {
                            const int col = nw + nf * 16 + (lane & 15);
                            Ts2[rowl * 132 + col] = acc[mf][nf][r] + brow;
                        }
                    }
                }
            }
            __syncthreads();
            if (tg < Ncols) {
                float* dst = Cb + (size_t)nIdx * 51200 + lIdx;
                #pragma unroll
                for (int i = 0; i < 32; ++i) {
                    const int rowl = i * 2 + rb2;
                    const int c = m0 + h * 64 + rowl;
                    dst[(size_t)c * 100] = Ts2[rowl * 132 + colL];
                }
            }
        }
    }
}

// ---------------------------------------------------------------------------
// MFMA flash attention, swapped-QK^T softmax (T12-adapted), base-2 exp.
// Logits arrive pre-scaled by SCALE*log2e (folded into Q2 projection).
// S^T = mfma(K,Q): lane owns ONE q-row (16 keys in-register) -> in-lane
// max/sum + 2 shfl_xor; P converted via v_cvt_pk_bf16_f32 and redistributed
// to PV A-fragments with ds_bpermute shuffles. No P LDS buffer.
// XCD-bijective block swizzle (T1). LDS 32KB, 4 blocks/CU.
// ---------------------------------------------------------------------------
template<int KSPLIT>
__global__ __launch_bounds__(256, 4) void attn_mfma_kernel(
    const ushort* __restrict__ R, const ushort* __restrict__ Kt,
    const ushort* __restrict__ Vt, ushort* __restrict__ Aout,
    float* __restrict__ PartO, float* __restrict__ Pml,
    int TR, int TK, int strideV, int nrb)
{
    __shared__ ushort Ks[64 * 128];   // 16 KB, rows 256B, XOR-swizzled
    __shared__ ushort Vs[128 * 64];   // 16 KB, d-rows 128B, XOR-swizzled

    const int t    = threadIdx.x;
    const int lane = t & 63;
    const int w    = t >> 6;

    // ---- XCD-bijective block swizzle (m204 formula) ----
    const int flat = blockIdx.x;
    const int ntot = gridDim.x;
    const int qq = ntot >> 3, r8 = ntot & 7;
    const int xcd = flat & 7, ii = flat >> 3;
    const int work = (xcd < r8 ? xcd * (qq + 1)
                               : r8 * (qq + 1) + (xcd - r8) * qq) + ii;
    const int rb = work % nrb;
    int rest = work / nrb;
    int sp = 0;
    if (KSPLIT > 1) { sp = rest % KSPLIT; rest /= KSPLIT; }
    const int h = rest & 3;
    const int b = rest >> 2;

    const int r0 = rb * 64;
    const int ho = h * 128;

    const int klen = (TK + KSPLIT - 1) / KSPLIT;
    const int kbeg = sp * klen;
    int kend = kbeg + klen; if (kend > TK) kend = TK;

    // ---- Q fragments direct from global (row-clamped at tail) ----
    bf16x8 qa[4];
    {
        const ushort* Rb = R + (size_t)b * TR * 512;
        const int qrow = min(r0 + (w << 4) + (lane & 15), TR - 1);
        const ushort* qp = Rb + (size_t)qrow * 512 + ho + (lane >> 4) * 8;
        #pragma unroll
        for (int s = 0; s < 4; ++s)
            qa[s] = *(const bf16x8*)(qp + s * 32);
    }

    const ushort* Kb = Kt + (size_t)b * TK * 512;
    const ushort* Vb = Vt + ((size_t)b * 512 + ho) * strideV;

    // per-lane staging offsets (ushort units; XOR preswizzle on source)
    const int krow_i = lane >> 4;            // row within 4-row K granule
    const int kcol   = (lane & 15) * 8;      // 16B col within 256B row
    const int vrow_i = lane >> 3;            // row within 8-row V granule
    const int vcol   = (lane & 7) * 8;       // 16B col within 128B row

    const int gq = lane >> 4;                // 0..3 lane group

    float m_run = -3.0e38f, l_run = 0.f;     // per-lane: one q-row (base-2)
    f32x4 acc[8];
    #pragma unroll
    for (int g = 0; g < 8; ++g) acc[g] = (f32x4){0.f, 0.f, 0.f, 0.f};

    for (int kbase = kbeg; kbase < kend; kbase += 64) {
        __syncthreads();   // prior chunk's Ks/Vs reads complete
        // ---- stage K (64x128) and V^T (128x64) via global_load_lds ----
        #pragma unroll
        for (int i = 0; i < 4; ++i) {
            const int kr = w * 16 + i * 4 + krow_i;
            gll16(Kb + (size_t)(kbase + kr) * 512 + ho + (kcol ^ ((kr & 7) << 3)),
                  Ks + (w * 16 + i * 4) * 128);
            const int vd = w * 32 + i * 8 + vrow_i;
            gll16(Vb + (size_t)vd * strideV + kbase + (vcol ^ ((vd & 7) << 3)),
                  Vs + (w * 32 + i * 8) * 64);
        }
        __syncthreads();

        // ---- swapped QK^T: sf[f][r] = S[key = f*16+4*gq+r][q = w*16+(lane&15)]
        f32x4 sf[4];
        #pragma unroll
        for (int f = 0; f < 4; ++f) {
            f32x4 s = (f32x4){0.f, 0.f, 0.f, 0.f};
            const int kr = f * 16 + (lane & 15);
            const int kb2 = kr * 256, sw = (kr & 7) << 4, g16 = gq * 16;
            #pragma unroll
            for (int s4 = 0; s4 < 4; ++s4) {
                bf16x8 kf = *(const bf16x8*)((const char*)Ks + kb2 + ((s4 * 64 + g16) ^ sw));
                s = __builtin_amdgcn_mfma_f32_16x16x32_bf16(kf, qa[s4], s, 0, 0, 0);
            }
            sf[f] = s;
        }
        // ---- key mask (partial chunks only) ----
        if (kbase + 64 > kend) {
            #pragma unroll
            for (int f = 0; f < 4; ++f)
                #pragma unroll
                for (int r = 0; r < 4; ++r)
                    if (kbase + f * 16 + gq * 4 + r >= kend) sf[f][r] = -3.0e38f;
        }
        // ---- in-lane row max + cross-group reduce ----
        float mx = sf[0][0];
        #pragma unroll
        for (int f = 0; f < 4; ++f)
            #pragma unroll
            for (int r = 0; r < 4; ++r) mx = fmaxf(mx, sf[f][r]);
        mx = fmaxf(mx, __shfl_xor(mx, 16));
        mx = fmaxf(mx, __shfl_xor(mx, 32));
        // ---- defer-max (T13, base-2 THR=11) ----
        if (__any(mx > m_run + 11.0f)) {
            const float mn = fmaxf(m_run, mx);
            const float sc = __builtin_amdgcn_exp2f(m_run - mn);
            m_run = mn;
            l_run *= sc;
            float scal4[4];
            #pragma unroll
            for (int r = 0; r < 4; ++r)
                scal4[r] = __shfl(sc, (lane & 48) + gq * 4 + r);
            #pragma unroll
            for (int g = 0; g < 8; ++g)
                #pragma unroll
                for (int r = 0; r < 4; ++r) acc[g][r] *= scal4[r];
        }
        // ---- P = exp2(S - m), row sum ----
        float rs = 0.f;
        #pragma unroll
        for (int f = 0; f < 4; ++f)
            #pragma unroll
            for (int r = 0; r < 4; ++r) {
                const float p = __builtin_amdgcn_exp2f(sf[f][r] - m_run);
                sf[f][r] = p;
                rs += p;
            }
        rs += __shfl_xor(rs, 16);
        rs += __shfl_xor(rs, 32);
        l_run += rs;

        // ---- pack P to bf16 pairs: pk[f][h] = keys {16f+4gq+2h, +1} ----
        uint pk[4][2];
        #pragma unroll
        for (int f = 0; f < 4; ++f) {
            const float x0 = sf[f][0], x1 = sf[f][1], x2 = sf[f][2], x3 = sf[f][3];
            asm("v_cvt_pk_bf16_f32 %0, %1, %2" : "=v"(pk[f][0]) : "v"(x0), "v"(x1));
            asm("v_cvt_pk_bf16_f32 %0, %1, %2" : "=v"(pk[f][1]) : "v"(x2), "v"(x3));
        }
        // ---- redistribute to PV A-fragments: pa0 = keys 0-31, pa1 = 32-63 ----
        union { uint u[4]; bf16x8 v; } pa0, pa1;
        #pragma unroll
        for (int u = 0; u < 4; ++u) {
            const int srcl = (lane & 15) + ((lane & 16) << 1) + ((u >> 1) << 4);
            const uint a0 = (uint)__shfl((int)pk[0][u & 1], srcl);
            const uint b0 = (uint)__shfl((int)pk[1][u & 1], srcl);
            const uint a1 = (uint)__shfl((int)pk[2][u & 1], srcl);
            const uint b1 = (uint)__shfl((int)pk[3][u & 1], srcl);
            pa0.u[u] = (lane & 32) ? b0 : a0;
            pa1.u[u] = (lane & 32) ? b1 : a1;
        }

        // ---- PV: O[16 x 128] += P[16 x 64] * V[64 x 128] ----
        {
            const int g16 = gq * 16;
            #pragma unroll
            for (int g = 0; g < 8; ++g) {
                const int dr = g * 16 + (lane & 15);
                const int vb = dr * 128, vsw = (dr & 7) << 4;
                bf16x8 v0 = *(const bf16x8*)((const char*)Vs + vb + ((g16) ^ vsw));
                bf16x8 v1 = *(const bf16x8*)((const char*)Vs + vb + ((64 + g16) ^ vsw));
                acc[g] = __builtin_amdgcn_mfma_f32_16x16x32_bf16(pa0.v, v0, acc[g], 0, 0, 0);
                acc[g] = __builtin_amdgcn_mfma_f32_16x16x32_bf16(pa1.v, v1, acc[g], 0, 0, 0);
            }
        }
    }

    // ---- epilogue (acc rows = q = w*16 + 4*gq + r, cols d = g*16+(lane&15)) ----
    const int rloc = (w << 4) + (gq << 2);
    if (KSPLIT == 1) {
        float linv[4];
        #pragma unroll
        for (int r = 0; r < 4; ++r)
            linv[r] = 1.f / __shfl(l_run, (lane & 48) + gq * 4 + r);
        #pragma unroll
        for (int r = 0; r < 4; ++r) {
            const int row = r0 + rloc + r;
            if (row < TR) {
                ushort* Ab2 = Aout + ((size_t)b * TR + row) * 512 + ho + (lane & 15);
                #pragma unroll
                for (int g = 0; g < 8; ++g) Ab2[g * 16] = f2bf(acc[g][r] * linv[r]);
            }
        }
    } else {
        const size_t tile = (((size_t)b * 4 + h) * nrb + rb) * KSPLIT + sp;
        float* Po = PartO + tile * (64 * 128);
        float* Pm = Pml + tile * 128;
        #pragma unroll
        for (int r = 0; r < 4; ++r) {
            const int row = rloc + r;
            float* pp = Po + row * 128 + (lane & 15);
            #pragma unroll
            for (int g = 0; g < 8; ++g) pp[g * 16] = acc[g][r];
        }
        if (lane < 16) {
            Pm[(w << 4) + lane] = m_run;          // base-2 max
            Pm[64 + (w << 4) + lane] = l_run;
        }
    }
}

// ---------------------------------------------------------------------------
// combine split-K partials (base-2 m): O = sum_i 2^{m_i-M} acc_i / sum ...
// ---------------------------------------------------------------------------
#define KSPL 8
__global__ __launch_bounds__(256) void attn_combine_kernel(
    const float* __restrict__ PartO, const float* __restrict__ Pml,
    ushort* __restrict__ Aout, int TR, int nrb)
{
    const int t = threadIdx.x;
    const int rb = blockIdx.x, h = blockIdx.y, b = blockIdx.z;
    const int row = t >> 2;
    const int dq = (t & 3) * 32;
    const int r0 = rb * 64;
    const size_t tbase = (((size_t)b * 4 + h) * nrb + rb) * KSPL;

    float M = -3.0e38f;
    #pragma unroll
    for (int i = 0; i < KSPL; ++i)
        M = fmaxf(M, Pml[(tbase + i) * 128 + row]);
    float wt[KSPL], L = 0.f;
    #pragma unroll
    for (int i = 0; i < KSPL; ++i) {
        const float wi = __builtin_amdgcn_exp2f(Pml[(tbase + i) * 128 + row] - M);
        wt[i] = wi;
        L += wi * Pml[(tbase + i) * 128 + 64 + row];
    }
    if (r0 + row >= TR) return;
    const float invL = 1.f / L;

    float o[32];
    #pragma unroll
    for (int j = 0; j < 32; ++j) o[j] = 0.f;
    #pragma unroll
    for (int i = 0; i < KSPL; ++i) {
        const float* pp = PartO + (tbase + i) * (64 * 128) + row * 128 + dq;
        #pragma unroll
        for (int j = 0; j < 32; j += 4) {
            const float4 v = *(const float4*)(pp + j);
            o[j] += wt[i] * v.x; o[j+1] += wt[i] * v.y;
            o[j+2] += wt[i] * v.z; o[j+3] += wt[i] * v.w;
        }
    }
    ushort* Ab = Aout + ((size_t)b * TR + r0 + row) * 512 + h * 128 + dq;
    #pragma unroll
    for (int j = 0; j < 32; j += 4) {
        ushort4 v;
        v.x = f2bf(o[j] * invL); v.y = f2bf(o[j+1] * invL);
        v.z = f2bf(o[j+2] * invL); v.w = f2bf(o[j+3] * invL);
        *(ushort4*)(Ab + j) = v;
    }
}

// ---------------------------------------------------------------------------
extern "C" void kernel_launch(void* const* d_in, const int* in_sizes, int n_in,
                              void* d_out, int out_size, void* d_ws, size_t ws_size,
                              hipStream_t stream) {
    const float* f1  = (const float*)d_in[0];
    const float* f2  = (const float*)d_in[1];
    const float* Wk1 = (const float*)d_in[2];
    const float* bk1 = (const float*)d_in[3];
    const float* Wv1 = (const float*)d_in[4];
    const float* bv1 = (const float*)d_in[5];
    const float* Wq2 = (const float*)d_in[6];
    const float* bq2 = (const float*)d_in[7];
    // d_in[8..9] = Wk2/bk2: unused by the reference outputs.
    const float* Wv2 = (const float*)d_in[10];
    const float* bv2 = (const float*)d_in[11];
    const float* Wo1 = (const float*)d_in[12];
    const float* bo1 = (const float*)d_in[13];
    const float* Wo2 = (const float*)d_in[14];
    const float* bo2 = (const float*)d_in[15];
    float* out = (float*)d_out;

    // ---- workspace layout (~169 MB) ----
    ushort* f1t = (ushort*)d_ws;                    // [4* 500][512]
    ushort* f2t = f1t + (size_t)1024000;            // [4*7500][512]
    ushort* Wb  = f2t + (size_t)15360000;           // [6][512][512]
    ushort* K1  = Wb  + (size_t)1572864;            // [4* 500][512]
    ushort* Q2  = K1  + (size_t)1024000;            // [4*7500][512] (pre-scaled)
    ushort* V1t = Q2  + (size_t)15360000;           // [4][512][512]
    ushort* V2t = V1t + (size_t)1048576;            // [4][512][7552]
    ushort* A1  = V2t + (size_t)15466496;           // [4* 500][512]
    ushort* A2  = A1  + (size_t)1024000;            // [4*7500][512]
    float* PartO = (float*)(A2 + (size_t)15360000); // 1024 x [64][128]
    float* Pml   = PartO + (size_t)1024*64*128;     // 1024 x [128]

    const dim3 blk(256);

    // pre-passes (Wq2 pre-scaled by SCALE*log2e -> base-2 softmax downstream)
    WPtrs wp;
    wp.p[0]=Wk1; wp.p[1]=Wv1; wp.p[2]=Wq2; wp.p[3]=Wv2; wp.p[4]=Wo1; wp.p[5]=Wo2;
    wp.s[0]=1.f; wp.s[1]=1.f; wp.s[2]=QSCL; wp.s[3]=1.f; wp.s[4]=1.f; wp.s[5]=1.f;
    wconv_kernel<<<dim3(256, 6), blk, 0, stream>>>(wp, Wb);
    totok_kernel<<<dim3(20),  blk, 0, stream>>>(f1, f1t);
    totok_kernel<<<dim3(300), blk, 0, stream>>>(f2, f2t);

    const ushort* Wk1b = Wb;
    const ushort* Wv1b = Wb + 262144;
    const ushort* Wq2b = Wb + 2*262144;
    const ushort* Wv2b = Wb + 3*262144;
    const ushort* Wo1b = Wb + 4*262144;
    const ushort* Wo2b = Wb + 5*262144;

    // projections
    gemm_nt<0,1><<<dim3(16, 4, 1),  blk, 0, stream>>>(f1t, 0, Wk1b, 0, bk1, 1.f, K1, 0, 512, 2000, 512);
    gemm_nt<0,1><<<dim3(235, 4, 1), blk, 0, stream>>>(f2t, 0, Wq2b, 0, bq2, QSCL, Q2, 0, 512, 30000, 512);
    // V projections, role-swapped -> d-major output
    gemm_nt<0,0><<<dim3(4, 4, 4),  blk, 0, stream>>>(Wv1b, 0, f1t, (size_t)500*512,  bv1, 1.f, V1t, (size_t)512*512,  512,  512, 500);
    gemm_nt<0,0><<<dim3(4, 59, 4), blk, 0, stream>>>(Wv2b, 0, f2t, (size_t)7500*512, bv2, 1.f, V2t, (size_t)512*7552, 7552, 512, 7500);

    // attention (flat 1D grids; XCD swizzle inside kernel)
    attn_mfma_kernel<1><<<dim3(118 * 4 * 4), blk, 0, stream>>>(
        Q2, K1, V1t, A2, nullptr, nullptr, 7500, 500, 512, 118);
    attn_mfma_kernel<KSPL><<<dim3(8 * 4 * 4 * KSPL), blk, 0, stream>>>(
        K1, Q2, V2t, nullptr, PartO, Pml, 500, 7500, 7552, 8);
    attn_combine_kernel<<<dim3(8, 4, 4), blk, 0, stream>>>(PartO, Pml, A1, 500, 8);

    // o-projections (role-swapped; fused [c][l] transpose in epilogue)
    gemm_nt<2,0><<<dim3(4, 4, 4),  blk, 0, stream>>>(Wo1b, 0, A1, (size_t)500*512,  bo1, 1.f, out, (size_t)5*51200,  0, 512, 500);
    gemm_nt<2,0><<<dim3(4, 59, 4), blk, 0, stream>>>(Wo2b, 0, A2, (size_t)7500*512, bo2, 1.f, out + (size_t)1024000, (size_t)75*51200, 0, 512, 7500);
}

// Round 7
// 316.564 us; speedup vs baseline: 9.0785x; 1.0044x over previous
//
#include <hip/hip_runtime.h>
#include <hip/hip_bf16.h>

// MultiHeadCrossAttention: B=4, C=512, HEADS=4, HD=128, L=100
// f1 -> 500 support tokens/batch, f2 -> 7500 query tokens/batch.
// out1: [4,5,512,100], out2: [4,75,512,100] concatenated in d_out.

#define QSCL  (0.08838834764831845f * 1.4426950408889634f)   // SCALE * log2(e)
#define KSPL  8
#define NRB2  118
#define NRB1  8
#define W2CNT (NRB2 * 16)            // 1888 dir-2 works
#define W1CNT (NRB1 * KSPL * 16)     // 1024 dir-1 works

using bf16x8 = __attribute__((ext_vector_type(8))) short;
using f32x4  = __attribute__((ext_vector_type(4))) float;

__device__ inline ushort f2bf(float x) {
    union { float f; unsigned u; } v; v.f = x;
    unsigned r = v.u + 0x7fff + ((v.u >> 16) & 1);   // RNE
    return (ushort)(r >> 16);
}

__device__ inline void gll16(const ushort* g, ushort* l) {
    __builtin_amdgcn_global_load_lds(
        (const __attribute__((address_space(1))) void*)g,
        (__attribute__((address_space(3))) void*)l, 16, 0, 0);
}

// ---------------------------------------------------------------------------
// pre_kernel: blocks [0,1536) = weight fp32->bf16 (x6, pre-scaled);
//             blocks [1536,1556) = totok f1; [1556,1856) = totok f2.
// totok: X slab [512][100] f32 -> Y tokens [100][512] bf16.
// ---------------------------------------------------------------------------
struct PreArgs { const float* w[6]; float s[6]; const float* f1; const float* f2; };

__global__ __launch_bounds__(256) void pre_kernel(
    PreArgs pa, ushort* __restrict__ Wb,
    ushort* __restrict__ f1t, ushort* __restrict__ f2t)
{
    __shared__ ushort Ts[100 * 136];
    const int t   = threadIdx.x;
    const int bid = blockIdx.x;

    if (bid < 1536) {
        const int wsel = bid >> 8;
        const float* src = pa.w[wsel];
        const float sc = pa.s[wsel];
        ushort* d = Wb + (size_t)wsel * 262144;
        const int idx = ((bid & 255) * 256 + t) * 4;
        const float4 v = *(const float4*)(src + idx);
        ushort4 o;
        o.x = f2bf(v.x * sc); o.y = f2bf(v.y * sc);
        o.z = f2bf(v.z * sc); o.w = f2bf(v.w * sc);
        *(ushort4*)(d + idx) = o;
        return;
    }

    const int bn = bid - 1536;
    const float* Xb;
    ushort* Yb;
    if (bn < 20) { Xb = pa.f1 + (size_t)bn * 51200;        Yb = f1t + (size_t)bn * 51200; }
    else         { Xb = pa.f2 + (size_t)(bn - 20) * 51200; Yb = f2t + (size_t)(bn - 20) * 51200; }

    for (int c0 = 0; c0 < 512; c0 += 128) {
        __syncthreads();
        #pragma unroll
        for (int i = 0; i < 50; ++i) {
            const int id = i * 256 + t;
            const int c = id / 100, l = id - c * 100;
            Ts[l * 136 + c] = f2bf(Xb[(size_t)(c0 + c) * 100 + l]);
        }
        __syncthreads();
        #pragma unroll
        for (int i = 0; i < 7; ++i) {
            const int id = i * 256 + t;
            if (id < 1600) {
                const int cg = id & 15, l = id >> 4;
                *(uint4*)(Yb + (size_t)l * 512 + c0 + cg * 8) =
                    *(const uint4*)&Ts[l * 136 + cg * 8];
            }
        }
    }
}

// ---------------------------------------------------------------------------
// gemm_nt two-job dispatch: C[m][n] = sum_k A[m][k]*B[n][k] (+bias*bscale).
// K=512 fixed, lda=ldb=512. 128x128 tile, BK=64, 4 waves, global_load_lds
// staging with XOR-preswizzled source.
// EPI 0: bf16 C row-major [Mrows][ldC]. BAXIS 1: bias per col; 0: per row.
// EPI 2: fp32 final out with [c][l] transpose scatter.
// ---------------------------------------------------------------------------
struct GemmJob {
    const ushort* A; const ushort* B;
    const float* bias; void* C;
    size_t sA, sB, sC;
    float bscale;
    int ldC, Mrows, Ncols, gx, gy, nblk;
};

template<int EPI, int BAXIS>
__global__ __launch_bounds__(256) void gemm_nt(GemmJob j0, GemmJob j1)
{
    __shared__ ushort smem[17408];          // 34.8 KB: staging 32KB / epi overlay
    ushort* As = smem;                       // [128][64]
    ushort* Bs = smem + 8192;                // [128][64]

    const bool second = (int)blockIdx.x >= j0.nblk;
    const GemmJob& j = second ? j1 : j0;
    int id = blockIdx.x - (second ? j0.nblk : 0);

    const int bx = id % j.gx;
    const int rem = id / j.gx;
    const int by = rem % j.gy;
    const int bz = rem / j.gy;

    const int t    = threadIdx.x;
    const int lane = t & 63;
    const int w    = t >> 6;
    const int mw   = (w >> 1) * 64;
    const int nw   = (w & 1) * 64;
    const int m0   = bx * 128;
    const int n0   = by * 128;
    const int Mrows = j.Mrows, Ncols = j.Ncols, ldC = j.ldC;
    const ushort* Ab = j.A + (size_t)bz * j.sA;
    const ushort* Bb = j.B + (size_t)bz * j.sB;
    const float* bias = j.bias;

    f32x4 acc[4][4];
    #pragma unroll
    for (int i = 0; i < 4; ++i)
        #pragma unroll
        for (int jj = 0; jj < 4; ++jj) acc[i][jj] = (f32x4){0.f, 0.f, 0.f, 0.f};

    const int lr = lane >> 3;      // 0..7 row within 8-row group
    const int cb = lane & 7;       // 16B granule within row

    for (int k0 = 0; k0 < 512; k0 += 64) {
        if (k0) __syncthreads();
        #pragma unroll
        for (int i = 0; i < 4; ++i) {
            const int row = w * 32 + i * 8 + lr;
            const int ar = min(m0 + row, Mrows - 1);
            gll16(Ab + (size_t)ar * 512 + k0 + ((cb ^ (row & 7)) * 8),
                  As + (w * 32 + i * 8) * 64);
            const int br = min(n0 + row, Ncols - 1);
            gll16(Bb + (size_t)br * 512 + k0 + ((cb ^ (row & 7)) * 8),
                  Bs + (w * 32 + i * 8) * 64);
        }
        __syncthreads();
        #pragma unroll
        for (int ks = 0; ks < 2; ++ks) {
            bf16x8 af[4], bv[4];
            #pragma unroll
            for (int mf = 0; mf < 4; ++mf) {
                const int row = mw + mf * 16 + (lane & 15);
                af[mf] = *(const bf16x8*)((const char*)As + row * 128 +
                          ((ks * 64 + (lane >> 4) * 16) ^ ((row & 7) << 4)));
            }
            #pragma unroll
            for (int nf = 0; nf < 4; ++nf) {
                const int row = nw + nf * 16 + (lane & 15);
                bv[nf] = *(const bf16x8*)((const char*)Bs + row * 128 +
                          ((ks * 64 + (lane >> 4) * 16) ^ ((row & 7) << 4)));
            }
            #pragma unroll
            for (int mf = 0; mf < 4; ++mf)
                #pragma unroll
                for (int nf = 0; nf < 4; ++nf)
                    acc[mf][nf] = __builtin_amdgcn_mfma_f32_16x16x32_bf16(
                        af[mf], bv[nf], acc[mf][nf], 0, 0, 0);
        }
    }
    __syncthreads();

    if (EPI == 0) {
        float bcol[4];
        if (BAXIS == 1) {
            #pragma unroll
            for (int nf = 0; nf < 4; ++nf)
                bcol[nf] = bias[n0 + nw + nf * 16 + (lane & 15)] * j.bscale;
        }
        ushort* Ts = smem;   // [128][136]
        #pragma unroll
        for (int mf = 0; mf < 4; ++mf) {
            #pragma unroll
            for (int r = 0; r < 4; ++r) {
                const int row = mw + mf * 16 + (lane >> 4) * 4 + r;
                const float brow = (BAXIS == 0) ? bias[m0 + row] * j.bscale : 0.f;
                #pragma unroll
                for (int nf = 0; nf < 4; ++nf) {
                    const int col = nw + nf * 16 + (lane & 15);
                    const float v = acc[mf][nf][r] +
                                    ((BAXIS == 1) ? bcol[nf] : brow);
                    Ts[row * 136 + col] = f2bf(v);
                }
            }
        }
        __syncthreads();
        ushort* Cb = (ushort*)j.C + (size_t)bz * j.sC;
        #pragma unroll
        for (int i = 0; i < 8; ++i) {
            const int id2 = i * 256 + t;
            const int row = id2 >> 4, cg = id2 & 15;
            if (m0 + row < Mrows)
                *(uint4*)(Cb + (size_t)(m0 + row) * ldC + n0 + cg * 8) =
                    *(const uint4*)&Ts[row * 136 + cg * 8];
        }
    } else {
        // EPI 2: fp32 final out with [c][l] scatter
        float* Ts2 = (float*)smem;   // [64][132]
        float* Cb = (float*)j.C + (size_t)bz * j.sC;
        const int colL = t & 127;
        const int rb2 = t >> 7;
        const int tg = n0 + colL;
        int nIdx = 0, lIdx = 0;
        if (tg < Ncols) { nIdx = tg / 100; lIdx = tg - nIdx * 100; }
        #pragma unroll
        for (int h = 0; h < 2; ++h) {
            __syncthreads();
            if ((mw >> 6) == h) {
                #pragma unroll
                for (int mf = 0; mf < 4; ++mf) {
                    #pragma unroll
                    for (int r = 0; r < 4; ++r) {
                        const int rowl = mf * 16 + (lane >> 4) * 4 + r;
                        const float brow = bias[m0 + h * 64 + rowl];
                        #pragma unroll
                        for (int nf = 0; nf < 4; ++nf) {
                            const int col = nw + nf * 16 + (lane & 15);
                            Ts2[rowl * 132 + col] = acc[mf][nf][r] + brow;
                        }
                    }
                }
            }
            __syncthreads();
            if (tg < Ncols) {
                float* dst = Cb + (size_t)nIdx * 51200 + lIdx;
                #pragma unroll
                for (int i = 0; i < 32; ++i) {
                    const int rowl = i * 2 + rb2;
                    const int c = m0 + h * 64 + rowl;
                    dst[(size_t)c * 100] = Ts2[rowl * 132 + colL];
                }
            }
        }
    }
}

// ---------------------------------------------------------------------------
// MFMA flash attention, both directions in ONE dispatch (runtime ksplit).
// Swapped-QK^T in-register softmax (base-2, defer-max), cvt_pk + shfl P
// redistribution, 2-phase staging pipeline:
//   issue V(i) -> QK^T(i)[Ks cur] + softmax -> barrier ->
//   issue K(i+1)[Ks alt] -> PV(i)[Vs] -> barrier.
// K double-buffered (2x16KB) + V single (16KB) = 48KB -> 3 blocks/CU.
// T1 XCD-bijective swizzle over the merged 2912-work grid, rb fastest.
// T5 setprio around MFMA clusters.
// ---------------------------------------------------------------------------
__global__ __launch_bounds__(256, 3) void attn_mfma_kernel(
    const ushort* __restrict__ Q2, const ushort* __restrict__ K1,
    const ushort* __restrict__ V1t, const ushort* __restrict__ V2t,
    ushort* __restrict__ A2, float* __restrict__ PartO, float* __restrict__ Pml)
{
    __shared__ ushort Ks[2 * 64 * 128];   // 32 KB double-buffered, XOR-swizzled
    __shared__ ushort Vs[128 * 64];       // 16 KB, d-rows 128B, XOR-swizzled

    const int t    = threadIdx.x;
    const int lane = t & 63;
    const int w    = t >> 6;

    // ---- XCD-bijective block swizzle (m204; ntot = 2912 = 8*364) ----
    const int flat = blockIdx.x;
    const int work = (flat & 7) * 364 + (flat >> 3);

    // ---- work decode ----
    const bool dir2 = work < W2CNT;
    int rb, h, b, sp = 0;
    if (dir2) {
        rb = work % NRB2;
        const int rest = work / NRB2;
        h = rest & 3; b = rest >> 2;
    } else {
        const int w1 = work - W2CNT;
        rb = w1 % NRB1;
        int rest = w1 / NRB1;
        sp = rest % KSPL; rest /= KSPL;
        h = rest & 3; b = rest >> 2;
    }

    const int TR = dir2 ? 7500 : 500;
    const int TK = dir2 ? 500 : 7500;
    const int strideV = dir2 ? 512 : 7552;
    const ushort* R  = dir2 ? Q2 : K1;
    const ushort* Kt = dir2 ? K1 : Q2;
    const ushort* Vt = dir2 ? V1t : V2t;

    const int r0 = rb * 64;
    const int ho = h * 128;

    int kbeg = 0, kend = TK;
    if (!dir2) {
        kbeg = sp * 938;
        kend = kbeg + 938; if (kend > TK) kend = TK;
    }

    // ---- Q fragments direct from global (row-clamped at tail) ----
    bf16x8 qa[4];
    {
        const ushort* Rb = R + (size_t)b * TR * 512;
        const int qrow = min(r0 + (w << 4) + (lane & 15), TR - 1);
        const ushort* qp = Rb + (size_t)qrow * 512 + ho + (lane >> 4) * 8;
        #pragma unroll
        for (int s = 0; s < 4; ++s)
            qa[s] = *(const bf16x8*)(qp + s * 32);
    }

    const ushort* Kb = Kt + (size_t)b * TK * 512;
    const ushort* Vb = Vt + ((size_t)b * 512 + ho) * strideV;

    // per-lane staging offsets (ushort units; XOR preswizzle on source)
    const int krow_i = lane >> 4;            // row within 4-row K granule
    const int kcol   = (lane & 15) * 8;      // 16B col within 256B row
    const int vrow_i = lane >> 3;            // row within 8-row V granule
    const int vcol   = (lane & 7) * 8;       // 16B col within 128B row
    const int gq     = lane >> 4;            // 0..3 lane group

    float m_run = -3.0e38f, l_run = 0.f;     // per-lane: one q-row (base-2)
    f32x4 acc[8];
    #pragma unroll
    for (int g = 0; g < 8; ++g) acc[g] = (f32x4){0.f, 0.f, 0.f, 0.f};

    // ---- prologue: stage K(kbeg) into Ks buf0 ----
    #pragma unroll
    for (int i = 0; i < 4; ++i) {
        const int kr = w * 16 + i * 4 + krow_i;
        gll16(Kb + (size_t)(kbeg + kr) * 512 + ho + (kcol ^ ((kr & 7) << 3)),
              Ks + (w * 16 + i * 4) * 128);
    }
    __syncthreads();

    int c = 0;
    for (int kbase = kbeg; kbase < kend; kbase += 64, ++c) {
        const ushort* KsC = Ks + (c & 1) * 8192;

        // ---- issue V(kbase) stage (hidden under QK^T + softmax) ----
        #pragma unroll
        for (int i = 0; i < 4; ++i) {
            const int vd = w * 32 + i * 8 + vrow_i;
            gll16(Vb + (size_t)vd * strideV + kbase + (vcol ^ ((vd & 7) << 3)),
                  Vs + (w * 32 + i * 8) * 64);
        }

        // ---- swapped QK^T: sf[f][r] = S[key=f*16+4*gq+r][q=w*16+(lane&15)] ----
        f32x4 sf[4];
        __builtin_amdgcn_s_setprio(1);
        #pragma unroll
        for (int f = 0; f < 4; ++f) {
            f32x4 s = (f32x4){0.f, 0.f, 0.f, 0.f};
            const int kr = f * 16 + (lane & 15);
            const int kb2 = kr * 256, sw = (kr & 7) << 4, g16 = gq * 16;
            #pragma unroll
            for (int s4 = 0; s4 < 4; ++s4) {
                bf16x8 kf = *(const bf16x8*)((const char*)KsC + kb2 + ((s4 * 64 + g16) ^ sw));
                s = __builtin_amdgcn_mfma_f32_16x16x32_bf16(kf, qa[s4], s, 0, 0, 0);
            }
            sf[f] = s;
        }
        __builtin_amdgcn_s_setprio(0);

        // ---- key mask (partial chunks only) ----
        if (kbase + 64 > kend) {
            #pragma unroll
            for (int f = 0; f < 4; ++f)
                #pragma unroll
                for (int r = 0; r < 4; ++r)
                    if (kbase + f * 16 + gq * 4 + r >= kend) sf[f][r] = -3.0e38f;
        }
        // ---- in-lane row max + cross-group reduce ----
        float mx = sf[0][0];
        #pragma unroll
        for (int f = 0; f < 4; ++f)
            #pragma unroll
            for (int r = 0; r < 4; ++r) mx = fmaxf(mx, sf[f][r]);
        mx = fmaxf(mx, __shfl_xor(mx, 16));
        mx = fmaxf(mx, __shfl_xor(mx, 32));
        // ---- defer-max (T13, base-2 THR=11) ----
        if (__any(mx > m_run + 11.0f)) {
            const float mn = fmaxf(m_run, mx);
            const float sc = __builtin_amdgcn_exp2f(m_run - mn);
            m_run = mn;
            l_run *= sc;
            float scal4[4];
            #pragma unroll
            for (int r = 0; r < 4; ++r)
                scal4[r] = __shfl(sc, (lane & 48) + gq * 4 + r);
            #pragma unroll
            for (int g = 0; g < 8; ++g)
                #pragma unroll
                for (int r = 0; r < 4; ++r) acc[g][r] *= scal4[r];
        }
        // ---- P = exp2(S - m), row sum ----
        float rs = 0.f;
        #pragma unroll
        for (int f = 0; f < 4; ++f)
            #pragma unroll
            for (int r = 0; r < 4; ++r) {
                const float p = __builtin_amdgcn_exp2f(sf[f][r] - m_run);
                sf[f][r] = p;
                rs += p;
            }
        rs += __shfl_xor(rs, 16);
        rs += __shfl_xor(rs, 32);
        l_run += rs;

        // ---- pack P to bf16 pairs: pk[f][h2] = keys {16f+4gq+2h2, +1} ----
        uint pk[4][2];
        #pragma unroll
        for (int f = 0; f < 4; ++f) {
            const float x0 = sf[f][0], x1 = sf[f][1], x2 = sf[f][2], x3 = sf[f][3];
            asm("v_cvt_pk_bf16_f32 %0, %1, %2" : "=v"(pk[f][0]) : "v"(x0), "v"(x1));
            asm("v_cvt_pk_bf16_f32 %0, %1, %2" : "=v"(pk[f][1]) : "v"(x2), "v"(x3));
        }
        // ---- redistribute to PV A-fragments: pa0 = keys 0-31, pa1 = 32-63 ----
        union { uint u[4]; bf16x8 v; } pa0, pa1;
        #pragma unroll
        for (int u = 0; u < 4; ++u) {
            const int srcl = (lane & 15) + ((lane & 16) << 1) + ((u >> 1) << 4);
            const uint a0 = (uint)__shfl((int)pk[0][u & 1], srcl);
            const uint b0 = (uint)__shfl((int)pk[1][u & 1], srcl);
            const uint a1 = (uint)__shfl((int)pk[2][u & 1], srcl);
            const uint b1 = (uint)__shfl((int)pk[3][u & 1], srcl);
            pa0.u[u] = (lane & 32) ? b0 : a0;
            pa1.u[u] = (lane & 32) ? b1 : a1;
        }

        __syncthreads();   // V ready; all waves past Ks[cur^1] reads

        // ---- issue K(kbase+64) stage into the other K buffer ----
        if (kbase + 64 < kend) {
            ushort* KsN = Ks + ((c + 1) & 1) * 8192;
            #pragma unroll
            for (int i = 0; i < 4; ++i) {
                const int kr = w * 16 + i * 4 + krow_i;
                gll16(Kb + (size_t)(kbase + 64 + kr) * 512 + ho + (kcol ^ ((kr & 7) << 3)),
                      KsN + (w * 16 + i * 4) * 128);
            }
        }

        // ---- PV: O[16 x 128] += P[16 x 64] * V[64 x 128] ----
        {
            const int g16 = gq * 16;
            __builtin_amdgcn_s_setprio(1);
            #pragma unroll
            for (int g = 0; g < 8; ++g) {
                const int dr = g * 16 + (lane & 15);
                const int vb = dr * 128, vsw = (dr & 7) << 4;
                bf16x8 v0 = *(const bf16x8*)((const char*)Vs + vb + ((g16) ^ vsw));
                bf16x8 v1 = *(const bf16x8*)((const char*)Vs + vb + ((64 + g16) ^ vsw));
                acc[g] = __builtin_amdgcn_mfma_f32_16x16x32_bf16(pa0.v, v0, acc[g], 0, 0, 0);
                acc[g] = __builtin_amdgcn_mfma_f32_16x16x32_bf16(pa1.v, v1, acc[g], 0, 0, 0);
            }
            __builtin_amdgcn_s_setprio(0);
        }
        __syncthreads();   // K(next) ready; Vs reads done before next V stage
    }

    // ---- epilogue (acc rows = q = w*16 + 4*gq + r, cols d = g*16+(lane&15)) ----
    const int rloc = (w << 4) + (gq << 2);
    if (dir2) {
        float linv[4];
        #pragma unroll
        for (int r = 0; r < 4; ++r)
            linv[r] = 1.f / __shfl(l_run, (lane & 48) + gq * 4 + r);
        #pragma unroll
        for (int r = 0; r < 4; ++r) {
            const int row = r0 + rloc + r;
            if (row < TR) {
                ushort* Ab2 = A2 + ((size_t)b * TR + row) * 512 + ho + (lane & 15);
                #pragma unroll
                for (int g = 0; g < 8; ++g) Ab2[g * 16] = f2bf(acc[g][r] * linv[r]);
            }
        }
    } else {
        const size_t tile = (((size_t)b * 4 + h) * NRB1 + rb) * KSPL + sp;
        float* Po = PartO + tile * (64 * 128);
        float* Pm = Pml + tile * 128;
        #pragma unroll
        for (int r = 0; r < 4; ++r) {
            const int row = rloc + r;
            float* pp = Po + row * 128 + (lane & 15);
            #pragma unroll
            for (int g = 0; g < 8; ++g) pp[g * 16] = acc[g][r];
        }
        if (lane < 16) {
            Pm[(w << 4) + lane] = m_run;          // base-2 max
            Pm[64 + (w << 4) + lane] = l_run;
        }
    }
}

// ---------------------------------------------------------------------------
// combine split-K partials (base-2 m): O = sum_i 2^{m_i-M} acc_i / sum ...
// ---------------------------------------------------------------------------
__global__ __launch_bounds__(256) void attn_combine_kernel(
    const float* __restrict__ PartO, const float* __restrict__ Pml,
    ushort* __restrict__ Aout, int TR, int nrb)
{
    const int t = threadIdx.x;
    const int rb = blockIdx.x, h = blockIdx.y, b = blockIdx.z;
    const int row = t >> 2;
    const int dq = (t & 3) * 32;
    const int r0 = rb * 64;
    const size_t tbase = (((size_t)b * 4 + h) * nrb + rb) * KSPL;

    float M = -3.0e38f;
    #pragma unroll
    for (int i = 0; i < KSPL; ++i)
        M = fmaxf(M, Pml[(tbase + i) * 128 + row]);
    float wt[KSPL], L = 0.f;
    #pragma unroll
    for (int i = 0; i < KSPL; ++i) {
        const float wi = __builtin_amdgcn_exp2f(Pml[(tbase + i) * 128 + row] - M);
        wt[i] = wi;
        L += wi * Pml[(tbase + i) * 128 + 64 + row];
    }
    if (r0 + row >= TR) return;
    const float invL = 1.f / L;

    float o[32];
    #pragma unroll
    for (int j = 0; j < 32; ++j) o[j] = 0.f;
    #pragma unroll
    for (int i = 0; i < KSPL; ++i) {
        const float* pp = PartO + (tbase + i) * (64 * 128) + row * 128 + dq;
        #pragma unroll
        for (int j = 0; j < 32; j += 4) {
            const float4 v = *(const float4*)(pp + j);
            o[j] += wt[i] * v.x; o[j+1] += wt[i] * v.y;
            o[j+2] += wt[i] * v.z; o[j+3] += wt[i] * v.w;
        }
    }
    ushort* Ab = Aout + ((size_t)b * TR + r0 + row) * 512 + h * 128 + dq;
    #pragma unroll
    for (int j = 0; j < 32; j += 4) {
        ushort4 v;
        v.x = f2bf(o[j] * invL); v.y = f2bf(o[j+1] * invL);
        v.z = f2bf(o[j+2] * invL); v.w = f2bf(o[j+3] * invL);
        *(ushort4*)(Ab + j) = v;
    }
}

// ---------------------------------------------------------------------------
extern "C" void kernel_launch(void* const* d_in, const int* in_sizes, int n_in,
                              void* d_out, int out_size, void* d_ws, size_t ws_size,
                              hipStream_t stream) {
    const float* f1  = (const float*)d_in[0];
    const float* f2  = (const float*)d_in[1];
    const float* Wk1 = (const float*)d_in[2];
    const float* bk1 = (const float*)d_in[3];
    const float* Wv1 = (const float*)d_in[4];
    const float* bv1 = (const float*)d_in[5];
    const float* Wq2 = (const float*)d_in[6];
    const float* bq2 = (const float*)d_in[7];
    // d_in[8..9] = Wk2/bk2: unused by the reference outputs.
    const float* Wv2 = (const float*)d_in[10];
    const float* bv2 = (const float*)d_in[11];
    const float* Wo1 = (const float*)d_in[12];
    const float* bo1 = (const float*)d_in[13];
    const float* Wo2 = (const float*)d_in[14];
    const float* bo2 = (const float*)d_in[15];
    float* out = (float*)d_out;

    // ---- workspace layout (~169 MB) ----
    ushort* f1t = (ushort*)d_ws;                    // [4* 500][512]
    ushort* f2t = f1t + (size_t)1024000;            // [4*7500][512]
    ushort* Wb  = f2t + (size_t)15360000;           // [6][512][512]
    ushort* K1  = Wb  + (size_t)1572864;            // [4* 500][512]
    ushort* Q2  = K1  + (size_t)1024000;            // [4*7500][512] (pre-scaled)
    ushort* V1t = Q2  + (size_t)15360000;           // [4][512][512]
    ushort* V2t = V1t + (size_t)1048576;            // [4][512][7552]
    ushort* A1  = V2t + (size_t)15466496;           // [4* 500][512]
    ushort* A2  = A1  + (size_t)1024000;            // [4*7500][512]
    float* PartO = (float*)(A2 + (size_t)15360000); // 1024 x [64][128]
    float* Pml   = PartO + (size_t)1024*64*128;     // 1024 x [128]

    const dim3 blk(256);

    const ushort* Wk1b = Wb;
    const ushort* Wv1b = Wb + 262144;
    const ushort* Wq2b = Wb + 2*262144;
    const ushort* Wv2b = Wb + 3*262144;
    const ushort* Wo1b = Wb + 4*262144;
    const ushort* Wo2b = Wb + 5*262144;

    // ---- pre-pass: weights (Wq2 pre-scaled) + both totoks, one dispatch ----
    PreArgs pa;
    pa.w[0]=Wk1; pa.w[1]=Wv1; pa.w[2]=Wq2; pa.w[3]=Wv2; pa.w[4]=Wo1; pa.w[5]=Wo2;
    pa.s[0]=1.f; pa.s[1]=1.f; pa.s[2]=QSCL; pa.s[3]=1.f; pa.s[4]=1.f; pa.s[5]=1.f;
    pa.f1 = f1; pa.f2 = f2;
    pre_kernel<<<dim3(1856), blk, 0, stream>>>(pa, Wb, f1t, f2t);

    // ---- K1 + Q2 projections (token-major bf16), one dispatch ----
    GemmJob jK{f1t, Wk1b, bk1, K1, 0, 0, 0, 1.f, 512, 2000, 512, 16, 4, 64};
    GemmJob jQ{f2t, Wq2b, bq2, Q2, 0, 0, 0, QSCL, 512, 30000, 512, 235, 4, 940};
    gemm_nt<0,1><<<dim3(1004), blk, 0, stream>>>(jK, jQ);

    // ---- V1t + V2t projections (role-swapped, d-major), one dispatch ----
    GemmJob jV1{Wv1b, f1t, bv1, V1t, 0, (size_t)500*512, (size_t)512*512, 1.f,
                512, 512, 500, 4, 4, 64};
    GemmJob jV2{Wv2b, f2t, bv2, V2t, 0, (size_t)7500*512, (size_t)512*7552, 1.f,
                7552, 512, 7500, 4, 59, 944};
    gemm_nt<0,0><<<dim3(1008), blk, 0, stream>>>(jV1, jV2);

    // ---- attention, both directions in one dispatch ----
    attn_mfma_kernel<<<dim3(W2CNT + W1CNT), blk, 0, stream>>>(
        Q2, K1, V1t, V2t, A2, PartO, Pml);
    attn_combine_kernel<<<dim3(8, 4, 4), blk, 0, stream>>>(PartO, Pml, A1, 500, 8);

    // ---- o-projections (fused [c][l] transpose), one dispatch ----
    GemmJob jO1{Wo1b, A1, bo1, out, 0, (size_t)500*512, (size_t)5*51200, 1.f,
                0, 512, 500, 4, 4, 64};
    GemmJob jO2{Wo2b, A2, bo2, out + (size_t)1024000, 0, (size_t)7500*512,
                (size_t)75*51200, 1.f, 0, 512, 7500, 4, 59, 944};
    gemm_nt<2,0><<<dim3(1008), blk, 0, stream>>>(jO1, jO2);
}

// Round 8
// 293.051 us; speedup vs baseline: 9.8069x; 1.0802x over previous
//
#include <hip/hip_runtime.h>
#include <hip/hip_bf16.h>

// MultiHeadCrossAttention: B=4, C=512, HEADS=4, HD=128, L=100
// f1 -> 500 support tokens/batch, f2 -> 7500 query tokens/batch.
// out1: [4,5,512,100], out2: [4,75,512,100] concatenated in d_out.

#define QSCL  (0.08838834764831845f * 1.4426950408889634f)   // SCALE * log2(e)
#define KSPL  8
#define NRB2  118
#define NRB1  8

using bf16x8 = __attribute__((ext_vector_type(8))) short;
using f32x4  = __attribute__((ext_vector_type(4))) float;

__device__ inline ushort f2bf(float x) {
    union { float f; unsigned u; } v; v.f = x;
    unsigned r = v.u + 0x7fff + ((v.u >> 16) & 1);   // RNE
    return (ushort)(r >> 16);
}

__device__ inline void gll16(const ushort* g, ushort* l) {
    __builtin_amdgcn_global_load_lds(
        (const __attribute__((address_space(1))) void*)g,
        (__attribute__((address_space(3))) void*)l, 16, 0, 0);
}

// ---------------------------------------------------------------------------
// pre_kernel: blocks [0,1536) = weight fp32->bf16 (x6, pre-scaled);
//             blocks [1536,1556) = totok f1; [1556,1856) = totok f2.
// ---------------------------------------------------------------------------
struct PreArgs { const float* w[6]; float s[6]; const float* f1; const float* f2; };

__global__ __launch_bounds__(256) void pre_kernel(
    PreArgs pa, ushort* __restrict__ Wb,
    ushort* __restrict__ f1t, ushort* __restrict__ f2t)
{
    __shared__ ushort Ts[100 * 136];
    const int t   = threadIdx.x;
    const int bid = blockIdx.x;

    if (bid < 1536) {
        const int wsel = bid >> 8;
        const float* src = pa.w[wsel];
        const float sc = pa.s[wsel];
        ushort* d = Wb + (size_t)wsel * 262144;
        const int idx = ((bid & 255) * 256 + t) * 4;
        const float4 v = *(const float4*)(src + idx);
        ushort4 o;
        o.x = f2bf(v.x * sc); o.y = f2bf(v.y * sc);
        o.z = f2bf(v.z * sc); o.w = f2bf(v.w * sc);
        *(ushort4*)(d + idx) = o;
        return;
    }

    const int bn = bid - 1536;
    const float* Xb;
    ushort* Yb;
    if (bn < 20) { Xb = pa.f1 + (size_t)bn * 51200;        Yb = f1t + (size_t)bn * 51200; }
    else         { Xb = pa.f2 + (size_t)(bn - 20) * 51200; Yb = f2t + (size_t)(bn - 20) * 51200; }

    for (int c0 = 0; c0 < 512; c0 += 128) {
        __syncthreads();
        #pragma unroll
        for (int i = 0; i < 50; ++i) {
            const int id = i * 256 + t;
            const int c = id / 100, l = id - c * 100;
            Ts[l * 136 + c] = f2bf(Xb[(size_t)(c0 + c) * 100 + l]);
        }
        __syncthreads();
        #pragma unroll
        for (int i = 0; i < 7; ++i) {
            const int id = i * 256 + t;
            if (id < 1600) {
                const int cg = id & 15, l = id >> 4;
                *(uint4*)(Yb + (size_t)l * 512 + c0 + cg * 8) =
                    *(const uint4*)&Ts[l * 136 + cg * 8];
            }
        }
    }
}

// ---------------------------------------------------------------------------
// gemm_nt two-job dispatch: C[m][n] = sum_k A[m][k]*B[n][k] (+bias*bscale).
// K=512 fixed, lda=ldb=512. 128x128 tile, BK=64, 4 waves, global_load_lds
// staging with XOR-preswizzled source.
// EPI 0: bf16 C row-major [Mrows][ldC]. BAXIS 1: bias per col; 0: per row.
// EPI 2: fp32 final out with [c][l] transpose scatter.
// ---------------------------------------------------------------------------
struct GemmJob {
    const ushort* A; const ushort* B;
    const float* bias; void* C;
    size_t sA, sB, sC;
    float bscale;
    int ldC, Mrows, Ncols, gx, gy, nblk;
};

template<int EPI, int BAXIS>
__global__ __launch_bounds__(256) void gemm_nt(GemmJob j0, GemmJob j1)
{
    __shared__ ushort smem[17408];          // 34.8 KB: staging 32KB / epi overlay
    ushort* As = smem;                       // [128][64]
    ushort* Bs = smem + 8192;                // [128][64]

    const bool second = (int)blockIdx.x >= j0.nblk;
    const GemmJob& j = second ? j1 : j0;
    int id = blockIdx.x - (second ? j0.nblk : 0);

    const int bx = id % j.gx;
    const int rem = id / j.gx;
    const int by = rem % j.gy;
    const int bz = rem / j.gy;

    const int t    = threadIdx.x;
    const int lane = t & 63;
    const int w    = t >> 6;
    const int mw   = (w >> 1) * 64;
    const int nw   = (w & 1) * 64;
    const int m0   = bx * 128;
    const int n0   = by * 128;
    const int Mrows = j.Mrows, Ncols = j.Ncols, ldC = j.ldC;
    const ushort* Ab = j.A + (size_t)bz * j.sA;
    const ushort* Bb = j.B + (size_t)bz * j.sB;
    const float* bias = j.bias;

    f32x4 acc[4][4];
    #pragma unroll
    for (int i = 0; i < 4; ++i)
        #pragma unroll
        for (int jj = 0; jj < 4; ++jj) acc[i][jj] = (f32x4){0.f, 0.f, 0.f, 0.f};

    const int lr = lane >> 3;      // 0..7 row within 8-row group
    const int cb = lane & 7;       // 16B granule within row

    for (int k0 = 0; k0 < 512; k0 += 64) {
        if (k0) __syncthreads();
        #pragma unroll
        for (int i = 0; i < 4; ++i) {
            const int row = w * 32 + i * 8 + lr;
            const int ar = min(m0 + row, Mrows - 1);
            gll16(Ab + (size_t)ar * 512 + k0 + ((cb ^ (row & 7)) * 8),
                  As + (w * 32 + i * 8) * 64);
            const int br = min(n0 + row, Ncols - 1);
            gll16(Bb + (size_t)br * 512 + k0 + ((cb ^ (row & 7)) * 8),
                  Bs + (w * 32 + i * 8) * 64);
        }
        __syncthreads();
        #pragma unroll
        for (int ks = 0; ks < 2; ++ks) {
            bf16x8 af[4], bv[4];
            #pragma unroll
            for (int mf = 0; mf < 4; ++mf) {
                const int row = mw + mf * 16 + (lane & 15);
                af[mf] = *(const bf16x8*)((const char*)As + row * 128 +
                          ((ks * 64 + (lane >> 4) * 16) ^ ((row & 7) << 4)));
            }
            #pragma unroll
            for (int nf = 0; nf < 4; ++nf) {
                const int row = nw + nf * 16 + (lane & 15);
                bv[nf] = *(const bf16x8*)((const char*)Bs + row * 128 +
                          ((ks * 64 + (lane >> 4) * 16) ^ ((row & 7) << 4)));
            }
            #pragma unroll
            for (int mf = 0; mf < 4; ++mf)
                #pragma unroll
                for (int nf = 0; nf < 4; ++nf)
                    acc[mf][nf] = __builtin_amdgcn_mfma_f32_16x16x32_bf16(
                        af[mf], bv[nf], acc[mf][nf], 0, 0, 0);
        }
    }
    __syncthreads();

    if (EPI == 0) {
        float bcol[4];
        if (BAXIS == 1) {
            #pragma unroll
            for (int nf = 0; nf < 4; ++nf)
                bcol[nf] = bias[n0 + nw + nf * 16 + (lane & 15)] * j.bscale;
        }
        ushort* Ts = smem;   // [128][136]
        #pragma unroll
        for (int mf = 0; mf < 4; ++mf) {
            #pragma unroll
            for (int r = 0; r < 4; ++r) {
                const int row = mw + mf * 16 + (lane >> 4) * 4 + r;
                const float brow = (BAXIS == 0) ? bias[m0 + row] * j.bscale : 0.f;
                #pragma unroll
                for (int nf = 0; nf < 4; ++nf) {
                    const int col = nw + nf * 16 + (lane & 15);
                    const float v = acc[mf][nf][r] +
                                    ((BAXIS == 1) ? bcol[nf] : brow);
                    Ts[row * 136 + col] = f2bf(v);
                }
            }
        }
        __syncthreads();
        ushort* Cb = (ushort*)j.C + (size_t)bz * j.sC;
        #pragma unroll
        for (int i = 0; i < 8; ++i) {
            const int id2 = i * 256 + t;
            const int row = id2 >> 4, cg = id2 & 15;
            if (m0 + row < Mrows)
                *(uint4*)(Cb + (size_t)(m0 + row) * ldC + n0 + cg * 8) =
                    *(const uint4*)&Ts[row * 136 + cg * 8];
        }
    } else {
        // EPI 2: fp32 final out with [c][l] scatter
        float* Ts2 = (float*)smem;   // [64][132]
        float* Cb = (float*)j.C + (size_t)bz * j.sC;
        const int colL = t & 127;
        const int rb2 = t >> 7;
        const int tg = n0 + colL;
        int nIdx = 0, lIdx = 0;
        if (tg < Ncols) { nIdx = tg / 100; lIdx = tg - nIdx * 100; }
        #pragma unroll
        for (int h = 0; h < 2; ++h) {
            __syncthreads();
            if ((mw >> 6) == h) {
                #pragma unroll
                for (int mf = 0; mf < 4; ++mf) {
                    #pragma unroll
                    for (int r = 0; r < 4; ++r) {
                        const int rowl = mf * 16 + (lane >> 4) * 4 + r;
                        const float brow = bias[m0 + h * 64 + rowl];
                        #pragma unroll
                        for (int nf = 0; nf < 4; ++nf) {
                            const int col = nw + nf * 16 + (lane & 15);
                            Ts2[rowl * 132 + col] = acc[mf][nf][r] + brow;
                        }
                    }
                }
            }
            __syncthreads();
            if (tg < Ncols) {
                float* dst = Cb + (size_t)nIdx * 51200 + lIdx;
                #pragma unroll
                for (int i = 0; i < 32; ++i) {
                    const int rowl = i * 2 + rb2;
                    const int c = m0 + h * 64 + rowl;
                    dst[(size_t)c * 100] = Ts2[rowl * 132 + colL];
                }
            }
        }
    }
}

// ---------------------------------------------------------------------------
// MFMA flash attention, both directions in ONE dispatch.
// Per-XCD balanced work split: each XCD owns 128 dir-1 works (938-key
// split-K slices, longest-first) + 236 dir-2 works (500-key), rb fastest.
// Split-waitcnt pipeline at 32KB LDS (4 blocks/CU):
//   issue K(i)[prev iter] + V(i) -> vmcnt(4)+bar -> QK^T+softmax (V in
//   flight) -> vmcnt(0)+bar -> issue K(i+1) -> PV -> bar.
// vmcnt in-order retirement guarantees the K granule is resident at vmcnt(4).
// ---------------------------------------------------------------------------
__global__ __launch_bounds__(256, 4) void attn_mfma_kernel(
    const ushort* __restrict__ Q2, const ushort* __restrict__ K1,
    const ushort* __restrict__ V1t, const ushort* __restrict__ V2t,
    ushort* __restrict__ A2, float* __restrict__ PartO, float* __restrict__ Pml)
{
    __shared__ ushort Ks[64 * 128];   // 16 KB, rows 256B, XOR-swizzled
    __shared__ ushort Vs[128 * 64];   // 16 KB, d-rows 128B, XOR-swizzled

    const int t    = threadIdx.x;
    const int lane = t & 63;
    const int w    = t >> 6;

    // ---- balanced XCD decode: ii<128 -> dir-1 (long works first) ----
    const int flat = blockIdx.x;
    const int xcd = flat & 7, ii = flat >> 3;       // ii in 0..363
    const bool dir2 = (ii >= 128);
    int rb, h, b, sp = 0;
    if (dir2) {
        const int w2 = xcd * 236 + (ii - 128);      // 0..1887
        rb = w2 % NRB2;
        const int hb = w2 / NRB2;
        h = hb & 3; b = hb >> 2;
    } else {
        const int w1 = xcd * 128 + ii;              // 0..1023
        rb = w1 & 7; sp = (w1 >> 3) & 7;
        const int hb = w1 >> 6;
        h = hb & 3; b = hb >> 2;
    }

    const int TR = dir2 ? 7500 : 500;
    const int TK = dir2 ? 500 : 7500;
    const int strideV = dir2 ? 512 : 7552;
    const ushort* R  = dir2 ? Q2 : K1;
    const ushort* Kt = dir2 ? K1 : Q2;
    const ushort* Vt = dir2 ? V1t : V2t;

    const int r0 = rb * 64;
    const int ho = h * 128;

    int kbeg = 0, kend = TK;
    if (!dir2) {
        kbeg = sp * 938;
        kend = kbeg + 938; if (kend > TK) kend = TK;
    }

    // ---- Q fragments direct from global (row-clamped at tail) ----
    bf16x8 qa[4];
    {
        const ushort* Rb = R + (size_t)b * TR * 512;
        const int qrow = min(r0 + (w << 4) + (lane & 15), TR - 1);
        const ushort* qp = Rb + (size_t)qrow * 512 + ho + (lane >> 4) * 8;
        #pragma unroll
        for (int s = 0; s < 4; ++s)
            qa[s] = *(const bf16x8*)(qp + s * 32);
    }

    const ushort* Kb = Kt + (size_t)b * TK * 512;
    const ushort* Vb = Vt + ((size_t)b * 512 + ho) * strideV;

    // per-lane staging offsets (ushort units; XOR preswizzle on source)
    const int krow_i = lane >> 4;            // row within 4-row K granule
    const int kcol   = (lane & 15) * 8;      // 16B col within 256B row
    const int vrow_i = lane >> 3;            // row within 8-row V granule
    const int vcol   = (lane & 7) * 8;       // 16B col within 128B row
    const int gq     = lane >> 4;            // 0..3 lane group

    float m_run = -3.0e38f, l_run = 0.f;     // per-lane: one q-row (base-2)
    f32x4 acc[8];
    #pragma unroll
    for (int g = 0; g < 8; ++g) acc[g] = (f32x4){0.f, 0.f, 0.f, 0.f};

    // ---- prologue: issue K(kbeg) ----
    #pragma unroll
    for (int i = 0; i < 4; ++i) {
        const int kr = w * 16 + i * 4 + krow_i;
        gll16(Kb + (size_t)(kbeg + kr) * 512 + ho + (kcol ^ ((kr & 7) << 3)),
              Ks + (w * 16 + i * 4) * 128);
    }

    for (int kbase = kbeg; kbase < kend; kbase += 64) {
        // ---- issue V(kbase); outstanding = 4 K + 4 V ----
        #pragma unroll
        for (int i = 0; i < 4; ++i) {
            const int vd = w * 32 + i * 8 + vrow_i;
            gll16(Vb + (size_t)vd * strideV + kbase + (vcol ^ ((vd & 7) << 3)),
                  Vs + (w * 32 + i * 8) * 64);
        }
        // ---- wait K only (in-order retirement); V stays in flight ----
        asm volatile("s_waitcnt vmcnt(4)" ::: "memory");
        __builtin_amdgcn_s_barrier();
        __builtin_amdgcn_sched_barrier(0);

        // ---- swapped QK^T: sf[f][r] = S[key=f*16+4*gq+r][q=w*16+(lane&15)] ----
        f32x4 sf[4];
        __builtin_amdgcn_s_setprio(1);
        #pragma unroll
        for (int f = 0; f < 4; ++f) {
            f32x4 s = (f32x4){0.f, 0.f, 0.f, 0.f};
            const int kr = f * 16 + (lane & 15);
            const int kb2 = kr * 256, sw = (kr & 7) << 4, g16 = gq * 16;
            #pragma unroll
            for (int s4 = 0; s4 < 4; ++s4) {
                bf16x8 kf = *(const bf16x8*)((const char*)Ks + kb2 + ((s4 * 64 + g16) ^ sw));
                s = __builtin_amdgcn_mfma_f32_16x16x32_bf16(kf, qa[s4], s, 0, 0, 0);
            }
            sf[f] = s;
        }
        __builtin_amdgcn_s_setprio(0);

        // ---- key mask (partial chunks only) ----
        if (kbase + 64 > kend) {
            #pragma unroll
            for (int f = 0; f < 4; ++f)
                #pragma unroll
                for (int r = 0; r < 4; ++r)
                    if (kbase + f * 16 + gq * 4 + r >= kend) sf[f][r] = -3.0e38f;
        }
        // ---- in-lane row max + cross-group reduce ----
        float mx = sf[0][0];
        #pragma unroll
        for (int f = 0; f < 4; ++f)
            #pragma unroll
            for (int r = 0; r < 4; ++r) mx = fmaxf(mx, sf[f][r]);
        mx = fmaxf(mx, __shfl_xor(mx, 16));
        mx = fmaxf(mx, __shfl_xor(mx, 32));
        // ---- defer-max (T13, base-2 THR=11) ----
        if (__any(mx > m_run + 11.0f)) {
            const float mn = fmaxf(m_run, mx);
            const float sc = __builtin_amdgcn_exp2f(m_run - mn);
            m_run = mn;
            l_run *= sc;
            float scal4[4];
            #pragma unroll
            for (int r = 0; r < 4; ++r)
                scal4[r] = __shfl(sc, (lane & 48) + gq * 4 + r);
            #pragma unroll
            for (int g = 0; g < 8; ++g)
                #pragma unroll
                for (int r = 0; r < 4; ++r) acc[g][r] *= scal4[r];
        }
        // ---- P = exp2(S - m), row sum ----
        float rs = 0.f;
        #pragma unroll
        for (int f = 0; f < 4; ++f)
            #pragma unroll
            for (int r = 0; r < 4; ++r) {
                const float p = __builtin_amdgcn_exp2f(sf[f][r] - m_run);
                sf[f][r] = p;
                rs += p;
            }
        rs += __shfl_xor(rs, 16);
        rs += __shfl_xor(rs, 32);
        l_run += rs;

        // ---- pack P to bf16 pairs: pk[f][h2] = keys {16f+4gq+2h2, +1} ----
        uint pk[4][2];
        #pragma unroll
        for (int f = 0; f < 4; ++f) {
            const float x0 = sf[f][0], x1 = sf[f][1], x2 = sf[f][2], x3 = sf[f][3];
            asm("v_cvt_pk_bf16_f32 %0, %1, %2" : "=v"(pk[f][0]) : "v"(x0), "v"(x1));
            asm("v_cvt_pk_bf16_f32 %0, %1, %2" : "=v"(pk[f][1]) : "v"(x2), "v"(x3));
        }
        // ---- redistribute to PV A-fragments: pa0 = keys 0-31, pa1 = 32-63 ----
        union { uint u[4]; bf16x8 v; } pa0, pa1;
        #pragma unroll
        for (int u = 0; u < 4; ++u) {
            const int srcl = (lane & 15) + ((lane & 16) << 1) + ((u >> 1) << 4);
            const uint a0 = (uint)__shfl((int)pk[0][u & 1], srcl);
            const uint b0 = (uint)__shfl((int)pk[1][u & 1], srcl);
            const uint a1 = (uint)__shfl((int)pk[2][u & 1], srcl);
            const uint b1 = (uint)__shfl((int)pk[3][u & 1], srcl);
            pa0.u[u] = (lane & 32) ? b0 : a0;
            pa1.u[u] = (lane & 32) ? b1 : a1;
        }

        // ---- wait V; all waves' QK^T reads of Ks done past this barrier ----
        asm volatile("s_waitcnt vmcnt(0)" ::: "memory");
        __builtin_amdgcn_s_barrier();
        __builtin_amdgcn_sched_barrier(0);

        // ---- issue K(kbase+64) into Ks (safe: all Ks reads done); hides
        //      under PV, waited at next iteration's vmcnt(4) ----
        if (kbase + 64 < kend) {
            #pragma unroll
            for (int i = 0; i < 4; ++i) {
                const int kr = w * 16 + i * 4 + krow_i;
                gll16(Kb + (size_t)(kbase + 64 + kr) * 512 + ho + (kcol ^ ((kr & 7) << 3)),
                      Ks + (w * 16 + i * 4) * 128);
            }
        }

        // ---- PV: O[16 x 128] += P[16 x 64] * V[64 x 128] ----
        {
            const int g16 = gq * 16;
            __builtin_amdgcn_s_setprio(1);
            #pragma unroll
            for (int g = 0; g < 8; ++g) {
                const int dr = g * 16 + (lane & 15);
                const int vb = dr * 128, vsw = (dr & 7) << 4;
                bf16x8 v0 = *(const bf16x8*)((const char*)Vs + vb + ((g16) ^ vsw));
                bf16x8 v1 = *(const bf16x8*)((const char*)Vs + vb + ((64 + g16) ^ vsw));
                acc[g] = __builtin_amdgcn_mfma_f32_16x16x32_bf16(pa0.v, v0, acc[g], 0, 0, 0);
                acc[g] = __builtin_amdgcn_mfma_f32_16x16x32_bf16(pa1.v, v1, acc[g], 0, 0, 0);
            }
            __builtin_amdgcn_s_setprio(0);
        }
        // ---- all Vs reads done -> next iteration may restage V ----
        __builtin_amdgcn_s_barrier();
        __builtin_amdgcn_sched_barrier(0);
    }

    // ---- epilogue (acc rows = q = w*16 + 4*gq + r, cols d = g*16+(lane&15)) ----
    const int rloc = (w << 4) + (gq << 2);
    if (dir2) {
        float linv[4];
        #pragma unroll
        for (int r = 0; r < 4; ++r)
            linv[r] = 1.f / __shfl(l_run, (lane & 48) + gq * 4 + r);
        #pragma unroll
        for (int r = 0; r < 4; ++r) {
            const int row = r0 + rloc + r;
            if (row < TR) {
                ushort* Ab2 = A2 + ((size_t)b * TR + row) * 512 + ho + (lane & 15);
                #pragma unroll
                for (int g = 0; g < 8; ++g) Ab2[g * 16] = f2bf(acc[g][r] * linv[r]);
            }
        }
    } else {
        const size_t tile = (((size_t)b * 4 + h) * NRB1 + rb) * KSPL + sp;
        float* Po = PartO + tile * (64 * 128);
        float* Pm = Pml + tile * 128;
        #pragma unroll
        for (int r = 0; r < 4; ++r) {
            const int row = rloc + r;
            float* pp = Po + row * 128 + (lane & 15);
            #pragma unroll
            for (int g = 0; g < 8; ++g) pp[g * 16] = acc[g][r];
        }
        if (lane < 16) {
            Pm[(w << 4) + lane] = m_run;          // base-2 max
            Pm[64 + (w << 4) + lane] = l_run;
        }
    }
}

// ---------------------------------------------------------------------------
// combine split-K partials (base-2 m): O = sum_i 2^{m_i-M} acc_i / sum ...
// ---------------------------------------------------------------------------
__global__ __launch_bounds__(256) void attn_combine_kernel(
    const float* __restrict__ PartO, const float* __restrict__ Pml,
    ushort* __restrict__ Aout, int TR, int nrb)
{
    const int t = threadIdx.x;
    const int rb = blockIdx.x, h = blockIdx.y, b = blockIdx.z;
    const int row = t >> 2;
    const int dq = (t & 3) * 32;
    const int r0 = rb * 64;
    const size_t tbase = (((size_t)b * 4 + h) * nrb + rb) * KSPL;

    float M = -3.0e38f;
    #pragma unroll
    for (int i = 0; i < KSPL; ++i)
        M = fmaxf(M, Pml[(tbase + i) * 128 + row]);
    float wt[KSPL], L = 0.f;
    #pragma unroll
    for (int i = 0; i < KSPL; ++i) {
        const float wi = __builtin_amdgcn_exp2f(Pml[(tbase + i) * 128 + row] - M);
        wt[i] = wi;
        L += wi * Pml[(tbase + i) * 128 + 64 + row];
    }
    if (r0 + row >= TR) return;
    const float invL = 1.f / L;

    float o[32];
    #pragma unroll
    for (int j = 0; j < 32; ++j) o[j] = 0.f;
    #pragma unroll
    for (int i = 0; i < KSPL; ++i) {
        const float* pp = PartO + (tbase + i) * (64 * 128) + row * 128 + dq;
        #pragma unroll
        for (int j = 0; j < 32; j += 4) {
            const float4 v = *(const float4*)(pp + j);
            o[j] += wt[i] * v.x; o[j+1] += wt[i] * v.y;
            o[j+2] += wt[i] * v.z; o[j+3] += wt[i] * v.w;
        }
    }
    ushort* Ab = Aout + ((size_t)b * TR + r0 + row) * 512 + h * 128 + dq;
    #pragma unroll
    for (int j = 0; j < 32; j += 4) {
        ushort4 v;
        v.x = f2bf(o[j] * invL); v.y = f2bf(o[j+1] * invL);
        v.z = f2bf(o[j+2] * invL); v.w = f2bf(o[j+3] * invL);
        *(ushort4*)(Ab + j) = v;
    }
}

// ---------------------------------------------------------------------------
extern "C" void kernel_launch(void* const* d_in, const int* in_sizes, int n_in,
                              void* d_out, int out_size, void* d_ws, size_t ws_size,
                              hipStream_t stream) {
    const float* f1  = (const float*)d_in[0];
    const float* f2  = (const float*)d_in[1];
    const float* Wk1 = (const float*)d_in[2];
    const float* bk1 = (const float*)d_in[3];
    const float* Wv1 = (const float*)d_in[4];
    const float* bv1 = (const float*)d_in[5];
    const float* Wq2 = (const float*)d_in[6];
    const float* bq2 = (const float*)d_in[7];
    // d_in[8..9] = Wk2/bk2: unused by the reference outputs.
    const float* Wv2 = (const float*)d_in[10];
    const float* bv2 = (const float*)d_in[11];
    const float* Wo1 = (const float*)d_in[12];
    const float* bo1 = (const float*)d_in[13];
    const float* Wo2 = (const float*)d_in[14];
    const float* bo2 = (const float*)d_in[15];
    float* out = (float*)d_out;

    // ---- workspace layout (~169 MB) ----
    ushort* f1t = (ushort*)d_ws;                    // [4* 500][512]
    ushort* f2t = f1t + (size_t)1024000;            // [4*7500][512]
    ushort* Wb  = f2t + (size_t)15360000;           // [6][512][512]
    ushort* K1  = Wb  + (size_t)1572864;            // [4* 500][512]
    ushort* Q2  = K1  + (size_t)1024000;            // [4*7500][512] (pre-scaled)
    ushort* V1t = Q2  + (size_t)15360000;           // [4][512][512]
    ushort* V2t = V1t + (size_t)1048576;            // [4][512][7552]
    ushort* A1  = V2t + (size_t)15466496;           // [4* 500][512]
    ushort* A2  = A1  + (size_t)1024000;            // [4*7500][512]
    float* PartO = (float*)(A2 + (size_t)15360000); // 1024 x [64][128]
    float* Pml   = PartO + (size_t)1024*64*128;     // 1024 x [128]

    const dim3 blk(256);

    const ushort* Wk1b = Wb;
    const ushort* Wv1b = Wb + 262144;
    const ushort* Wq2b = Wb + 2*262144;
    const ushort* Wv2b = Wb + 3*262144;
    const ushort* Wo1b = Wb + 4*262144;
    const ushort* Wo2b = Wb + 5*262144;

    // ---- pre-pass: weights (Wq2 pre-scaled) + both totoks, one dispatch ----
    PreArgs pa;
    pa.w[0]=Wk1; pa.w[1]=Wv1; pa.w[2]=Wq2; pa.w[3]=Wv2; pa.w[4]=Wo1; pa.w[5]=Wo2;
    pa.s[0]=1.f; pa.s[1]=1.f; pa.s[2]=QSCL; pa.s[3]=1.f; pa.s[4]=1.f; pa.s[5]=1.f;
    pa.f1 = f1; pa.f2 = f2;
    pre_kernel<<<dim3(1856), blk, 0, stream>>>(pa, Wb, f1t, f2t);

    // ---- K1 + Q2 projections (token-major bf16), one dispatch ----
    GemmJob jK{f1t, Wk1b, bk1, K1, 0, 0, 0, 1.f, 512, 2000, 512, 16, 4, 64};
    GemmJob jQ{f2t, Wq2b, bq2, Q2, 0, 0, 0, QSCL, 512, 30000, 512, 235, 4, 940};
    gemm_nt<0,1><<<dim3(1004), blk, 0, stream>>>(jK, jQ);

    // ---- V1t + V2t projections (role-swapped, d-major), one dispatch ----
    GemmJob jV1{Wv1b, f1t, bv1, V1t, 0, (size_t)500*512, (size_t)512*512, 1.f,
                512, 512, 500, 4, 4, 64};
    GemmJob jV2{Wv2b, f2t, bv2, V2t, 0, (size_t)7500*512, (size_t)512*7552, 1.f,
                7552, 512, 7500, 4, 59, 944};
    gemm_nt<0,0><<<dim3(1008), blk, 0, stream>>>(jV1, jV2);

    // ---- attention, both directions in one dispatch ----
    attn_mfma_kernel<<<dim3(2912), blk, 0, stream>>>(
        Q2, K1, V1t, V2t, A2, PartO, Pml);
    attn_combine_kernel<<<dim3(8, 4, 4), blk, 0, stream>>>(PartO, Pml, A1, 500, 8);

    // ---- o-projections (fused [c][l] transpose), one dispatch ----
    GemmJob jO1{Wo1b, A1, bo1, out, 0, (size_t)500*512, (size_t)5*51200, 1.f,
                0, 512, 500, 4, 4, 64};
    GemmJob jO2{Wo2b, A2, bo2, out + (size_t)1024000, 0, (size_t)7500*512,
                (size_t)75*51200, 1.f, 0, 512, 7500, 4, 59, 944};
    gemm_nt<2,0><<<dim3(1008), blk, 0, stream>>>(jO1, jO2);
}